// Round 6
// baseline (673.279 us; speedup 1.0000x reference)
//
#include <hip/hip_runtime.h>
#include <hip/hip_fp16.h>

#define EPSV 1e-5f
#define HDIM 128
#define BKT_SHIFT 9
#define BKT_SIZE 512
#define CHK 8192

// ================= CSR build: bucketed counting sort =================

__global__ __launch_bounds__(256) void hist_pass(const int* __restrict__ dst,
                                                 int* __restrict__ histG, int E, int NB) {
    __shared__ int h[BKT_SIZE];
    int t = threadIdx.x;
    for (int i = t; i < NB; i += 256) h[i] = 0;
    __syncthreads();
    int base = blockIdx.x * CHK;
    int end = min(base + CHK, E);
    for (int e = base + t; e < end; e += 256) atomicAdd(&h[dst[e] >> BKT_SHIFT], 1);
    __syncthreads();
    for (int i = t; i < NB; i += 256) histG[(size_t)blockIdx.x * NB + i] = h[i];
}

__global__ __launch_bounds__(512) void scan_chunks(int* __restrict__ histG,
                                                   int* __restrict__ tot,
                                                   int NCHUNK, int NB) {
    __shared__ int tmp[512];
    int b = blockIdx.x, t = threadIdx.x;
    int v = (t < NCHUNK) ? histG[(size_t)t * NB + b] : 0;
    tmp[t] = v;
    __syncthreads();
    for (int off = 1; off < 512; off <<= 1) {
        int x = (t >= off) ? tmp[t - off] : 0;
        __syncthreads();
        tmp[t] += x;
        __syncthreads();
    }
    if (t < NCHUNK) histG[(size_t)t * NB + b] = tmp[t] - v;
    if (t == 511) tot[b] = tmp[511];
}

__global__ __launch_bounds__(512) void scan_tot_k(const int* __restrict__ tot,
                                                  int* __restrict__ bucketBase,
                                                  int* __restrict__ rowStart,
                                                  int NB, int N, int E) {
    __shared__ int tmp[512];
    int t = threadIdx.x;
    int v = (t < NB) ? tot[t] : 0;
    tmp[t] = v;
    __syncthreads();
    for (int off = 1; off < 512; off <<= 1) {
        int x = (t >= off) ? tmp[t - off] : 0;
        __syncthreads();
        tmp[t] += x;
        __syncthreads();
    }
    if (t < NB) bucketBase[t] = tmp[t] - v;
    if (t == NB - 1) {
        bucketBase[NB] = tmp[t];
        rowStart[N] = E;
    }
}

__global__ __launch_bounds__(256) void add_base(int* __restrict__ histG,
                                                const int* __restrict__ bucketBase,
                                                int total, int NB) {
    int i = blockIdx.x * 256 + threadIdx.x;
    if (i < total) histG[i] += bucketBase[i % NB];
}

__global__ __launch_bounds__(256) void scatter_bkt(const int* __restrict__ src,
                                                   const int* __restrict__ dst,
                                                   const int* __restrict__ chunkOff,
                                                   unsigned int* __restrict__ EP,
                                                   int E, int NB) {
    __shared__ int cur[BKT_SIZE];
    int t = threadIdx.x, c = blockIdx.x;
    for (int i = t; i < NB; i += 256) cur[i] = chunkOff[(size_t)c * NB + i];
    __syncthreads();
    int base = c * CHK, end = min(base + CHK, E);
    for (int e = base + t; e < end; e += 256) {
        int d = dst[e];
        int b = d >> BKT_SHIFT;
        int pos = atomicAdd(&cur[b], 1);
        EP[pos] = (unsigned int)src[e] | ((unsigned int)(d & (BKT_SIZE - 1)) << 23);
    }
}

__global__ __launch_bounds__(512) void bucket_csr(const unsigned int* __restrict__ EP,
                                                  const int* __restrict__ bucketBase,
                                                  int* __restrict__ rowStart,
                                                  float* __restrict__ dinv,
                                                  int* __restrict__ col, int N) {
    __shared__ int cnt[BKT_SIZE];
    __shared__ int tmp[BKT_SIZE];
    int b = blockIdx.x, t = threadIdx.x;
    int ebase = bucketBase[b], eend = bucketBase[b + 1];
    cnt[t] = 0;
    __syncthreads();
    for (int e = ebase + t; e < eend; e += 512)
        atomicAdd(&cnt[(EP[e] >> 23) & 511], 1);
    __syncthreads();
    int v = cnt[t];
    tmp[t] = v;
    __syncthreads();
    for (int off = 1; off < 512; off <<= 1) {
        int x = (t >= off) ? tmp[t - off] : 0;
        __syncthreads();
        tmp[t] += x;
        __syncthreads();
    }
    int excl = tmp[t] - v;
    int n = (b << BKT_SHIFT) + t;
    if (n < N) {
        rowStart[n] = ebase + excl;
        dinv[n] = rsqrtf((float)v + 1.0f);
    }
    __syncthreads();
    cnt[t] = ebase + excl;
    __syncthreads();
    for (int e = ebase + t; e < eend; e += 512) {
        unsigned int p = EP[e];
        int ld = (p >> 23) & 511;
        int pos = atomicAdd(&cnt[ld], 1);
        col[pos] = (int)(p & 0x7FFFFFu);
    }
}

// ---------------- xs = dinv * x, padded [N][8]; also per-graph node counts ----------------
__global__ __launch_bounds__(256) void prep_xs(const float* __restrict__ x,
                                               const float* __restrict__ dinv,
                                               const int* __restrict__ batch,
                                               float* __restrict__ xs,
                                               float* __restrict__ gcnt, long long total) {
    long long idx = (long long)blockIdx.x * 256 + threadIdx.x;
    if (idx >= total) return;
    int n = (int)(idx >> 3), k = (int)(idx & 7);
    xs[idx] = (k < 7) ? x[(long long)n * 7 + k] * dinv[n] : 0.f;
    if (k == 7) unsafeAtomicAdd(&gcnt[batch[n]], 1.0f);
}

// ---------------- layer-1 aggregation: wave per node, 4 lanes/edge x 16 streams ----------------
__global__ __launch_bounds__(256) void agg7k(const int* __restrict__ col,
                                             const int* __restrict__ rowStart,
                                             const float* __restrict__ xs,
                                             float* __restrict__ agg, int N) {
    int wib = threadIdx.x >> 6, lane = threadIdx.x & 63;
    int stream = lane >> 2;          // 0..15
    int c2 = (lane & 3) * 2;         // channel pair
    int n = blockIdx.x * 4 + wib;
    if (n >= N) return;              // wave-uniform
    float2 acc = make_float2(0.f, 0.f);
    int rs = rowStart[n], re = rowStart[n + 1];
    if (stream == 0) acc = *(const float2*)(xs + (size_t)n * 8 + c2);   // self
    int j = rs + stream;
    for (; j + 16 < re; j += 32) {
        int e0 = col[j], e1 = col[j + 16];
        float2 r0 = *(const float2*)(xs + (size_t)e0 * 8 + c2);
        float2 r1 = *(const float2*)(xs + (size_t)e1 * 8 + c2);
        acc.x += r0.x + r1.x;
        acc.y += r0.y + r1.y;
    }
    for (; j < re; j += 16) {
        float2 r = *(const float2*)(xs + (size_t)col[j] * 8 + c2);
        acc.x += r.x; acc.y += r.y;
    }
#pragma unroll
    for (int off = 4; off <= 32; off <<= 1) {
        acc.x += __shfl_xor(acc.x, off);
        acc.y += __shfl_xor(acc.y, off);
    }
    if (stream == 0) *(float2*)(agg + (size_t)n * 8 + c2) = acc;
}

// ---------------- layer-1 post: A16 = half(dinv*(agg@W1)+b1), accumulate stats ----------------
__global__ __launch_bounds__(512) void l1post(const float* __restrict__ agg,
                                              const float* __restrict__ W1,
                                              const float* __restrict__ b1,
                                              const float* __restrict__ dinv,
                                              const int* __restrict__ batch,
                                              __half* __restrict__ A16,
                                              float* __restrict__ gsum,
                                              float* __restrict__ gsq, int N) {
    __shared__ float w1s[7 * HDIM];
    __shared__ float red_s[4][HDIM], red_q[4][HDIM];
    __shared__ int bsh[4];
    int t = threadIdx.x;
    for (int i = t; i < 7 * HDIM; i += 512) w1s[i] = W1[i];
    int wib = t >> 7, c = t & 127;
    int n = blockIdx.x * 4 + wib;
    __syncthreads();
    bool act = (n < N);
    float v = 0.f;
    int b = -1;
    if (act) {
        b = batch[n];
        const float* ar = agg + (size_t)n * 8;
        float s = 0.f;
#pragma unroll
        for (int k = 0; k < 7; k++) s += ar[k] * w1s[k * HDIM + c];
        v = s * dinv[n] + b1[c];
        A16[(size_t)n * HDIM + c] = __float2half(v);
    }
    if (c == 0) bsh[wib] = act ? b : -1;
    red_s[wib][c] = v;
    red_q[wib][c] = v * v;
    __syncthreads();
    int b0 = bsh[0];
    bool uni = (b0 >= 0) && (bsh[1] == b0) && (bsh[2] == b0) && (bsh[3] == b0);
    if (uni) {
        if (wib == 0) {
            float vs = red_s[0][c] + red_s[1][c] + red_s[2][c] + red_s[3][c];
            float qs = red_q[0][c] + red_q[1][c] + red_q[2][c] + red_q[3][c];
            unsafeAtomicAdd(&gsum[(size_t)b0 * HDIM + c], vs);
            unsafeAtomicAdd(&gsq[(size_t)b0 * HDIM + c], qs);
        }
    } else if (act) {
        unsafeAtomicAdd(&gsum[(size_t)b * HDIM + c], v);
        unsafeAtomicAdd(&gsq[(size_t)b * HDIM + c], v * v);
    }
}

// ---------------- per-(graph,channel): sums -> mean, inv-std ----------------
__global__ __launch_bounds__(256) void gstat(float* __restrict__ gsum,
                                             float* __restrict__ gsq,
                                             const float* __restrict__ gcnt,
                                             const float* __restrict__ alpha, int total) {
    int i = blockIdx.x * 256 + threadIdx.x;
    if (i < total) {
        int g = i >> 7, c = i & 127;
        float cnt = fmaxf(gcnt[g], 1.f);
        float mean = gsum[i] / cnt;
        float m2 = gsq[i] / cnt;
        float a = alpha[c];
        float var = m2 + mean * mean * (a * a - 2.f * a);
        gsum[i] = mean;
        gsq[i] = rsqrtf(fmaxf(var, 0.f) + EPSV);
    }
}

// ---------------- hidden matmul, fp16 in (fused l1 norm+relu), fp16 out ----------------
__global__ __launch_bounds__(256) void mm_h_fused(const __half* __restrict__ A16,
                                                  const float* __restrict__ gmean,
                                                  const float* __restrict__ gistd,
                                                  const float* __restrict__ alpha,
                                                  const float* __restrict__ w,
                                                  const float* __restrict__ bb,
                                                  const int* __restrict__ batch,
                                                  const float* __restrict__ W,
                                                  const float* __restrict__ dinv,
                                                  __half* __restrict__ Q, int N) {
    __shared__ float xs[64][65];
    __shared__ __align__(16) float ws[64][HDIM];
    __shared__ float pA[HDIM], pW[HDIM], pB[HDIM];
    int t = threadIdx.x;
    for (int i = t; i < HDIM; i += 256) { pA[i] = alpha[i]; pW[i] = w[i]; pB[i] = bb[i]; }
    int tx = t & 15;
    int ty = t >> 4;
    int n0 = blockIdx.x * 64;
    float acc[4][8];
#pragma unroll
    for (int i = 0; i < 4; i++)
#pragma unroll
        for (int j = 0; j < 8; j++) acc[i][j] = 0.f;

    for (int s = 0; s < 2; ++s) {
        __syncthreads();
        // stage normed+relu'd X half-tile: 64 nodes x 64 k, 8ch per thread-step
        for (int i = t; i < 64 * 8; i += 256) {
            int nn = i >> 3;
            int kk = (i & 7) * 8;
            int gn = n0 + nn;
            float vv[8];
#pragma unroll
            for (int k = 0; k < 8; k++) vv[k] = 0.f;
            if (gn < N) {
                uint4 u = *(const uint4*)(A16 + (size_t)gn * HDIM + s * 64 + kk);
                int b = batch[gn];
                int c = s * 64 + kk;
                const float* mp = gmean + (size_t)b * HDIM + c;
                const float* ip = gistd + (size_t)b * HDIM + c;
                float2 f0 = __half22float2(*(__half2*)&u.x);
                float2 f1 = __half22float2(*(__half2*)&u.y);
                float2 f2 = __half22float2(*(__half2*)&u.z);
                float2 f3 = __half22float2(*(__half2*)&u.w);
                float f[8] = {f0.x, f0.y, f1.x, f1.y, f2.x, f2.y, f3.x, f3.y};
#pragma unroll
                for (int k = 0; k < 8; k++)
                    vv[k] = fmaxf(pW[c + k] * (f[k] - pA[c + k] * mp[k]) * ip[k] + pB[c + k], 0.f);
            }
#pragma unroll
            for (int k = 0; k < 8; k++) xs[nn][kk + k] = vv[k];
        }
        for (int i = t; i < 64 * 32; i += 256) {
            int kk = i >> 5;
            int c = (i & 31) * 4;
            *(float4*)&ws[kk][c] = *(const float4*)(W + (size_t)(s * 64 + kk) * HDIM + c);
        }
        __syncthreads();
#pragma unroll 8
        for (int kk = 0; kk < 64; ++kk) {
            float xv[4];
#pragma unroll
            for (int i = 0; i < 4; i++) xv[i] = xs[ty * 4 + i][kk];
            float4 w0 = *(const float4*)&ws[kk][tx * 4];
            float4 w1 = *(const float4*)&ws[kk][64 + tx * 4];
#pragma unroll
            for (int i = 0; i < 4; i++) {
                acc[i][0] += xv[i] * w0.x; acc[i][1] += xv[i] * w0.y;
                acc[i][2] += xv[i] * w0.z; acc[i][3] += xv[i] * w0.w;
                acc[i][4] += xv[i] * w1.x; acc[i][5] += xv[i] * w1.y;
                acc[i][6] += xv[i] * w1.z; acc[i][7] += xv[i] * w1.w;
            }
        }
    }
#pragma unroll
    for (int i = 0; i < 4; i++) {
        int gn = n0 + ty * 4 + i;
        if (gn >= N) continue;
        float dv = dinv[gn];
        __half2* q0 = (__half2*)(Q + (size_t)gn * HDIM + tx * 4);
        __half2* q1 = (__half2*)(Q + (size_t)gn * HDIM + 64 + tx * 4);
        q0[0] = __floats2half2_rn(acc[i][0] * dv, acc[i][1] * dv);
        q0[1] = __floats2half2_rn(acc[i][2] * dv, acc[i][3] * dv);
        q1[0] = __floats2half2_rn(acc[i][4] * dv, acc[i][5] * dv);
        q1[1] = __floats2half2_rn(acc[i][6] * dv, acc[i][7] * dv);
    }
}

// ---------------- unpack-add 8 fp16 channels ----------------
__device__ __forceinline__ void addu4(float* __restrict__ acc, uint4 u) {
    float2 f0 = __half22float2(*(__half2*)&u.x);
    float2 f1 = __half22float2(*(__half2*)&u.y);
    float2 f2 = __half22float2(*(__half2*)&u.z);
    float2 f3 = __half22float2(*(__half2*)&u.w);
    acc[0] += f0.x; acc[1] += f0.y; acc[2] += f1.x; acc[3] += f1.y;
    acc[4] += f2.x; acc[5] += f2.y; acc[6] += f3.x; acc[7] += f3.y;
}

// ---------------- layer-2 CSR gather: 16 lanes/edge x 4 streams, uint4 loads ----------------
__global__ __launch_bounds__(256) void node_agg2(const int* __restrict__ col,
                                                 const int* __restrict__ rowStart,
                                                 const __half* __restrict__ Q,
                                                 const float* __restrict__ dinv,
                                                 const float* __restrict__ bias,
                                                 const int* __restrict__ batch,
                                                 __half* __restrict__ A2,
                                                 float* __restrict__ gsum,
                                                 float* __restrict__ gsq, int N) {
    __shared__ __align__(16) float sv[4][HDIM];
    __shared__ __align__(16) float sq[4][HDIM];
    __shared__ int bsh[4];
    int wib = threadIdx.x >> 6;
    int lane = threadIdx.x & 63;
    int stream = lane >> 4;          // 0..3
    int c8 = (lane & 15) * 8;        // 8 channels per lane
    int n = blockIdx.x * 4 + wib;
    bool active = (n < N);
    float acc[8];
#pragma unroll
    for (int k = 0; k < 8; k++) acc[k] = 0.f;
    int b = -1;
    if (active) {
        b = batch[n];
        int rs = rowStart[n], re = rowStart[n + 1];
        if (stream == 0) addu4(acc, *(const uint4*)(Q + (size_t)n * HDIM + c8));  // self
        int j = rs + stream;
        for (; j + 12 < re; j += 16) {
            int e0 = col[j], e1 = col[j + 4], e2 = col[j + 8], e3 = col[j + 12];
            uint4 u0 = *(const uint4*)(Q + (size_t)e0 * HDIM + c8);
            uint4 u1 = *(const uint4*)(Q + (size_t)e1 * HDIM + c8);
            uint4 u2 = *(const uint4*)(Q + (size_t)e2 * HDIM + c8);
            uint4 u3 = *(const uint4*)(Q + (size_t)e3 * HDIM + c8);
            addu4(acc, u0); addu4(acc, u1); addu4(acc, u2); addu4(acc, u3);
        }
        for (; j < re; j += 4)
            addu4(acc, *(const uint4*)(Q + (size_t)col[j] * HDIM + c8));
    }
    // combine 4 edge streams
#pragma unroll
    for (int k = 0; k < 8; k++) {
        acc[k] += __shfl_xor(acc[k], 16);
        acc[k] += __shfl_xor(acc[k], 32);
    }
    if (lane == 0) bsh[wib] = active ? b : -1;
    if (stream == 0) {
        float dv = active ? dinv[n] : 0.f;
#pragma unroll
        for (int k = 0; k < 8; k++) {
            acc[k] = active ? (acc[k] * dv + bias[c8 + k]) : 0.f;
            sv[wib][c8 + k] = acc[k];
            sq[wib][c8 + k] = acc[k] * acc[k];
        }
        if (active) {
            __half2 h0 = __floats2half2_rn(acc[0], acc[1]);
            __half2 h1 = __floats2half2_rn(acc[2], acc[3]);
            __half2 h2 = __floats2half2_rn(acc[4], acc[5]);
            __half2 h3 = __floats2half2_rn(acc[6], acc[7]);
            uint4 u;
            u.x = *(unsigned int*)&h0; u.y = *(unsigned int*)&h1;
            u.z = *(unsigned int*)&h2; u.w = *(unsigned int*)&h3;
            *(uint4*)(A2 + (size_t)n * HDIM + c8) = u;
        }
    }
    __syncthreads();
    int b0 = bsh[0];
    bool uni = (b0 >= 0) && (bsh[1] == b0) && (bsh[2] == b0) && (bsh[3] == b0);
    if (uni) {
        if (wib == 0 && stream == 0) {
#pragma unroll
            for (int k = 0; k < 8; k++) {
                int c = c8 + k;
                unsafeAtomicAdd(&gsum[(size_t)b0 * HDIM + c],
                                sv[0][c] + sv[1][c] + sv[2][c] + sv[3][c]);
                unsafeAtomicAdd(&gsq[(size_t)b0 * HDIM + c],
                                sq[0][c] + sq[1][c] + sq[2][c] + sq[3][c]);
            }
        }
    } else if (active && stream == 0) {
#pragma unroll
        for (int k = 0; k < 8; k++) {
            int c = c8 + k;
            unsafeAtomicAdd(&gsum[(size_t)b * HDIM + c], acc[k]);
            unsafeAtomicAdd(&gsq[(size_t)b * HDIM + c], acc[k] * acc[k]);
        }
    }
}

// ---------------- layer-2 normalize+relu fused with pool atomics (wave per node) ----------------
__global__ __launch_bounds__(256) void node_norm_pool(const __half* __restrict__ A2,
                                                      const float* __restrict__ gmean,
                                                      const float* __restrict__ gistd,
                                                      const float* __restrict__ alpha,
                                                      const float* __restrict__ w,
                                                      const float* __restrict__ bb,
                                                      const int* __restrict__ batch,
                                                      float* __restrict__ gpool, int N) {
    __shared__ float sv[4][HDIM];
    __shared__ int bsh[4];
    int wib = threadIdx.x >> 6, lane = threadIdx.x & 63;
    int c = lane * 2;
    int n = blockIdx.x * 4 + wib;
    bool active = (n < N);
    float2 y = make_float2(0.f, 0.f);
    int b = -1;
    if (active) {
        b = batch[n];
        float2 v = __half22float2(*(const __half2*)(A2 + (size_t)n * HDIM + c));
        float2 m = *(const float2*)(gmean + (size_t)b * HDIM + c);
        float2 is = *(const float2*)(gistd + (size_t)b * HDIM + c);
        y.x = fmaxf(w[c] * (v.x - alpha[c] * m.x) * is.x + bb[c], 0.f);
        y.y = fmaxf(w[c + 1] * (v.y - alpha[c + 1] * m.y) * is.y + bb[c + 1], 0.f);
    }
    if (lane == 0) bsh[wib] = active ? b : -1;
    sv[wib][c] = y.x; sv[wib][c + 1] = y.y;
    __syncthreads();
    int b0 = bsh[0];
    bool uni = (b0 >= 0) && (bsh[1] == b0) && (bsh[2] == b0) && (bsh[3] == b0);
    if (uni) {
        if (wib == 0) {
            float vx = sv[0][c] + sv[1][c] + sv[2][c] + sv[3][c];
            float vy = sv[0][c + 1] + sv[1][c + 1] + sv[2][c + 1] + sv[3][c + 1];
            unsafeAtomicAdd(&gpool[(size_t)b0 * HDIM + c], vx);
            unsafeAtomicAdd(&gpool[(size_t)b0 * HDIM + c + 1], vy);
        }
    } else if (active) {
        unsafeAtomicAdd(&gpool[(size_t)b * HDIM + c], y.x);
        unsafeAtomicAdd(&gpool[(size_t)b * HDIM + c + 1], y.y);
    }
}

// ---------------- head ----------------
__global__ __launch_bounds__(128) void head(const float* __restrict__ gpool,
                                            const float* __restrict__ gcnt,
                                            const float* __restrict__ H1,
                                            const float* __restrict__ hb1,
                                            const float* __restrict__ H2,
                                            const float* __restrict__ hb2,
                                            float* __restrict__ out, int G) {
    __shared__ float gv[HDIM];
    __shared__ float tv[HDIM];
    __shared__ float r0[HDIM], r1[HDIM];
    int g = blockIdx.x;
    int c = threadIdx.x;
    float cnt = fmaxf(gcnt[g], 1.0f);
    gv[c] = gpool[(long long)g * HDIM + c] / cnt;
    __syncthreads();
    float s = hb1[c];
    for (int k = 0; k < HDIM; k++) s += gv[k] * H1[k * HDIM + c];
    tv[c] = fmaxf(s, 0.f);
    __syncthreads();
    r0[c] = tv[c] * H2[c * 2 + 0];
    r1[c] = tv[c] * H2[c * 2 + 1];
    __syncthreads();
    for (int off = 64; off > 0; off >>= 1) {
        if (c < off) { r0[c] += r0[c + off]; r1[c] += r1[c + off]; }
        __syncthreads();
    }
    if (c == 0) {
        out[(long long)g * 2 + 0] = r0[0] + hb2[0];
        out[(long long)g * 2 + 1] = r1[0] + hb2[1];
    }
}

extern "C" void kernel_launch(void* const* d_in, const int* in_sizes, int n_in,
                              void* d_out, int out_size, void* d_ws, size_t ws_size,
                              hipStream_t stream) {
    const float* x    = (const float*)d_in[0];
    const int*   ei   = (const int*)d_in[1];
    const int*   batch= (const int*)d_in[2];
    const float* W1   = (const float*)d_in[4];
    const float* b1   = (const float*)d_in[5];
    const float* gn1w = (const float*)d_in[6];
    const float* gn1b = (const float*)d_in[7];
    const float* gn1a = (const float*)d_in[8];
    const float* W2   = (const float*)d_in[9];
    const float* b2   = (const float*)d_in[10];
    const float* gn2w = (const float*)d_in[11];
    const float* gn2b = (const float*)d_in[12];
    const float* gn2a = (const float*)d_in[13];
    const float* H1   = (const float*)d_in[14];
    const float* hb1  = (const float*)d_in[15];
    const float* H2   = (const float*)d_in[16];
    const float* hb2  = (const float*)d_in[17];

    int N = in_sizes[0] / 7;
    int E = in_sizes[1] / 2;
    int G = out_size / 2;
    const int* srcI = ei;
    const int* dstI = ei + E;

    int NB = (N + BKT_SIZE - 1) >> BKT_SHIFT;
    int NCHUNK = (E + CHK - 1) / CHK;

    // workspace layout
    __half* A16   = (__half*)d_ws;                   // N*128 half (layer1 pre-norm)
    __half* A2    = A16;                             // alias: layer2 pre-norm (A16 dead by then)
    __half* Q16   = A16 + (size_t)N * HDIM;          // N*128 half
    float*  xs    = (float*)(Q16 + (size_t)N * HDIM);// N*8
    float*  agg   = xs + (size_t)N * 8;              // N*8
    float*  gsum1 = agg + (size_t)N * 8;             // G*128
    float*  gsq1  = gsum1 + (size_t)G * HDIM;        // G*128
    float*  gsum2 = gsq1 + (size_t)G * HDIM;         // G*128
    float*  gsq2  = gsum2 + (size_t)G * HDIM;        // G*128
    float*  gpool = gsq2 + (size_t)G * HDIM;         // G*128
    float*  gcnt  = gpool + (size_t)G * HDIM;        // G
    float*  dinv  = gcnt + G;                        // N
    int* rowStart = (int*)(dinv + N);                // N+2
    unsigned int* EP = (unsigned int*)(rowStart + N + 2); // E
    int* col      = (int*)(EP + E);                  // E
    int* histG    = col + E;                         // NCHUNK*NB
    int* tot      = histG + (size_t)NCHUNK * NB;     // NB+2
    int* bucketBase = tot + NB + 2;                  // NB+2

    int gridNW = (N + 3) / 4;
    int gridGH = (G * HDIM + 255) / 256;
    int gridMM = (N + 63) / 64;

    // single upfront memset: gsum1,gsq1,gsum2,gsq2,gpool,gcnt
    hipMemsetAsync(gsum1, 0, ((size_t)G * HDIM * 5 + G) * 4, stream);

    // ---- CSR build ----
    hist_pass<<<NCHUNK, 256, 0, stream>>>(dstI, histG, E, NB);
    scan_chunks<<<NB, 512, 0, stream>>>(histG, tot, NCHUNK, NB);
    scan_tot_k<<<1, 512, 0, stream>>>(tot, bucketBase, rowStart, NB, N, E);
    add_base<<<((NCHUNK * NB) + 255) / 256, 256, 0, stream>>>(histG, bucketBase, NCHUNK * NB, NB);
    scatter_bkt<<<NCHUNK, 256, 0, stream>>>(srcI, dstI, histG, EP, E, NB);
    bucket_csr<<<NB, 512, 0, stream>>>(EP, bucketBase, rowStart, dinv, col, N);

    // ---- block 1 (rank-7 aggregation) ----
    long long nx8 = (long long)N * 8;
    prep_xs<<<(int)((nx8 + 255) / 256), 256, 0, stream>>>(x, dinv, batch, xs, gcnt, nx8);
    agg7k<<<gridNW, 256, 0, stream>>>(col, rowStart, xs, agg, N);
    l1post<<<gridNW, 512, 0, stream>>>(agg, W1, b1, dinv, batch, A16, gsum1, gsq1, N);
    gstat<<<gridGH, 256, 0, stream>>>(gsum1, gsq1, gcnt, gn1a, G * HDIM);

    // ---- mm_h with fused layer-1 norm+relu, fp16 in/out ----
    mm_h_fused<<<gridMM, 256, 0, stream>>>(A16, gsum1, gsq1, gn1a, gn1w, gn1b, batch,
                                           W2, dinv, Q16, N);

    // ---- block 2 (fp16 gather, 4 edge streams x 16 lanes) ----
    node_agg2<<<gridNW, 256, 0, stream>>>(col, rowStart, Q16, dinv, b2, batch, A2,
                                          gsum2, gsq2, N);
    gstat<<<gridGH, 256, 0, stream>>>(gsum2, gsq2, gcnt, gn2a, G * HDIM);

    // ---- layer-2 norm + relu + pool fused ----
    node_norm_pool<<<gridNW, 256, 0, stream>>>(A2, gsum2, gsq2, gn2a, gn2w, gn2b, batch, gpool, N);

    // ---- head ----
    head<<<G, 128, 0, stream>>>(gpool, gcnt, H1, hb1, H2, hb2, (float*)d_out, G);
}

// Round 7
// 538.400 us; speedup vs baseline: 1.2505x; 1.2505x over previous
//
#include <hip/hip_runtime.h>
#include <hip/hip_fp16.h>

#define EPSV 1e-5f
#define HDIM 128
#define BKT_SHIFT 9
#define BKT_SIZE 512
#define CHK 8192

// ================= CSR build: bucketed counting sort =================

__global__ __launch_bounds__(256) void hist_pass(const int* __restrict__ dst,
                                                 int* __restrict__ histG, int E, int NB) {
    __shared__ int h[BKT_SIZE];
    int t = threadIdx.x;
    for (int i = t; i < NB; i += 256) h[i] = 0;
    __syncthreads();
    int base = blockIdx.x * CHK;
    int end = min(base + CHK, E);
    for (int e = base + t; e < end; e += 256) atomicAdd(&h[dst[e] >> BKT_SHIFT], 1);
    __syncthreads();
    for (int i = t; i < NB; i += 256) histG[(size_t)blockIdx.x * NB + i] = h[i];
}

__global__ __launch_bounds__(512) void scan_chunks(int* __restrict__ histG,
                                                   int* __restrict__ tot,
                                                   int NCHUNK, int NB) {
    __shared__ int tmp[512];
    int b = blockIdx.x, t = threadIdx.x;
    int v = (t < NCHUNK) ? histG[(size_t)t * NB + b] : 0;
    tmp[t] = v;
    __syncthreads();
    for (int off = 1; off < 512; off <<= 1) {
        int x = (t >= off) ? tmp[t - off] : 0;
        __syncthreads();
        tmp[t] += x;
        __syncthreads();
    }
    if (t < NCHUNK) histG[(size_t)t * NB + b] = tmp[t] - v;
    if (t == 511) tot[b] = tmp[511];
}

__global__ __launch_bounds__(512) void scan_tot_k(const int* __restrict__ tot,
                                                  int* __restrict__ bucketBase,
                                                  int* __restrict__ rowStart,
                                                  int NB, int N, int E) {
    __shared__ int tmp[512];
    int t = threadIdx.x;
    int v = (t < NB) ? tot[t] : 0;
    tmp[t] = v;
    __syncthreads();
    for (int off = 1; off < 512; off <<= 1) {
        int x = (t >= off) ? tmp[t - off] : 0;
        __syncthreads();
        tmp[t] += x;
        __syncthreads();
    }
    if (t < NB) bucketBase[t] = tmp[t] - v;
    if (t == NB - 1) {
        bucketBase[NB] = tmp[t];
        rowStart[N] = E;
    }
}

__global__ __launch_bounds__(256) void add_base(int* __restrict__ histG,
                                                const int* __restrict__ bucketBase,
                                                int total, int NB) {
    int i = blockIdx.x * 256 + threadIdx.x;
    if (i < total) histG[i] += bucketBase[i % NB];
}

__global__ __launch_bounds__(256) void scatter_bkt(const int* __restrict__ src,
                                                   const int* __restrict__ dst,
                                                   const int* __restrict__ chunkOff,
                                                   unsigned int* __restrict__ EP,
                                                   int E, int NB) {
    __shared__ int cur[BKT_SIZE];
    int t = threadIdx.x, c = blockIdx.x;
    for (int i = t; i < NB; i += 256) cur[i] = chunkOff[(size_t)c * NB + i];
    __syncthreads();
    int base = c * CHK, end = min(base + CHK, E);
    for (int e = base + t; e < end; e += 256) {
        int d = dst[e];
        int b = d >> BKT_SHIFT;
        int pos = atomicAdd(&cur[b], 1);
        EP[pos] = (unsigned int)src[e] | ((unsigned int)(d & (BKT_SIZE - 1)) << 23);
    }
}

__global__ __launch_bounds__(512) void bucket_csr(const unsigned int* __restrict__ EP,
                                                  const int* __restrict__ bucketBase,
                                                  int* __restrict__ rowStart,
                                                  float* __restrict__ dinv,
                                                  int* __restrict__ col, int N) {
    __shared__ int cnt[BKT_SIZE];
    __shared__ int tmp[BKT_SIZE];
    int b = blockIdx.x, t = threadIdx.x;
    int ebase = bucketBase[b], eend = bucketBase[b + 1];
    cnt[t] = 0;
    __syncthreads();
    for (int e = ebase + t; e < eend; e += 512)
        atomicAdd(&cnt[(EP[e] >> 23) & 511], 1);
    __syncthreads();
    int v = cnt[t];
    tmp[t] = v;
    __syncthreads();
    for (int off = 1; off < 512; off <<= 1) {
        int x = (t >= off) ? tmp[t - off] : 0;
        __syncthreads();
        tmp[t] += x;
        __syncthreads();
    }
    int excl = tmp[t] - v;
    int n = (b << BKT_SHIFT) + t;
    if (n < N) {
        rowStart[n] = ebase + excl;
        dinv[n] = rsqrtf((float)v + 1.0f);
    }
    __syncthreads();
    cnt[t] = ebase + excl;
    __syncthreads();
    for (int e = ebase + t; e < eend; e += 512) {
        unsigned int p = EP[e];
        int ld = (p >> 23) & 511;
        int pos = atomicAdd(&cnt[ld], 1);
        col[pos] = (int)(p & 0x7FFFFFu);
    }
}

// ---------------- xs = dinv * x, padded [N][8]; also per-graph node counts ----------------
__global__ __launch_bounds__(256) void prep_xs(const float* __restrict__ x,
                                               const float* __restrict__ dinv,
                                               const int* __restrict__ batch,
                                               float* __restrict__ xs,
                                               float* __restrict__ gcnt, long long total) {
    long long idx = (long long)blockIdx.x * 256 + threadIdx.x;
    if (idx >= total) return;
    int n = (int)(idx >> 3), k = (int)(idx & 7);
    xs[idx] = (k < 7) ? x[(long long)n * 7 + k] * dinv[n] : 0.f;
    if (k == 7) unsafeAtomicAdd(&gcnt[batch[n]], 1.0f);
}

// ---------------- layer-1 aggregation: wave per node, 4 lanes/edge x 16 streams ----------------
__global__ __launch_bounds__(256) void agg7k(const int* __restrict__ col,
                                             const int* __restrict__ rowStart,
                                             const float* __restrict__ xs,
                                             float* __restrict__ agg, int N) {
    int wib = threadIdx.x >> 6, lane = threadIdx.x & 63;
    int stream = lane >> 2;          // 0..15
    int c2 = (lane & 3) * 2;         // channel pair
    int n = blockIdx.x * 4 + wib;
    if (n >= N) return;              // wave-uniform
    float2 acc = make_float2(0.f, 0.f);
    int rs = rowStart[n], re = rowStart[n + 1];
    if (stream == 0) acc = *(const float2*)(xs + (size_t)n * 8 + c2);   // self
    int j = rs + stream;
    for (; j + 16 < re; j += 32) {
        int e0 = col[j], e1 = col[j + 16];
        float2 r0 = *(const float2*)(xs + (size_t)e0 * 8 + c2);
        float2 r1 = *(const float2*)(xs + (size_t)e1 * 8 + c2);
        acc.x += r0.x + r1.x;
        acc.y += r0.y + r1.y;
    }
    for (; j < re; j += 16) {
        float2 r = *(const float2*)(xs + (size_t)col[j] * 8 + c2);
        acc.x += r.x; acc.y += r.y;
    }
#pragma unroll
    for (int off = 4; off <= 32; off <<= 1) {
        acc.x += __shfl_xor(acc.x, off);
        acc.y += __shfl_xor(acc.y, off);
    }
    if (stream == 0) *(float2*)(agg + (size_t)n * 8 + c2) = acc;
}

// ---------------- layer-1 post: A16 = half(dinv*(agg@W1)+b1), accumulate stats ----------------
__global__ __launch_bounds__(512) void l1post(const float* __restrict__ agg,
                                              const float* __restrict__ W1,
                                              const float* __restrict__ b1,
                                              const float* __restrict__ dinv,
                                              const int* __restrict__ batch,
                                              __half* __restrict__ A16,
                                              float* __restrict__ gsum,
                                              float* __restrict__ gsq, int N) {
    __shared__ float w1s[7 * HDIM];
    __shared__ float red_s[4][HDIM], red_q[4][HDIM];
    __shared__ int bsh[4];
    int t = threadIdx.x;
    for (int i = t; i < 7 * HDIM; i += 512) w1s[i] = W1[i];
    int wib = t >> 7, c = t & 127;
    int n = blockIdx.x * 4 + wib;
    __syncthreads();
    bool act = (n < N);
    float v = 0.f;
    int b = -1;
    if (act) {
        b = batch[n];
        const float* ar = agg + (size_t)n * 8;
        float s = 0.f;
#pragma unroll
        for (int k = 0; k < 7; k++) s += ar[k] * w1s[k * HDIM + c];
        v = s * dinv[n] + b1[c];
        A16[(size_t)n * HDIM + c] = __float2half(v);
    }
    if (c == 0) bsh[wib] = act ? b : -1;
    red_s[wib][c] = v;
    red_q[wib][c] = v * v;
    __syncthreads();
    int b0 = bsh[0];
    bool uni = (b0 >= 0) && (bsh[1] == b0) && (bsh[2] == b0) && (bsh[3] == b0);
    if (uni) {
        if (wib == 0) {
            float vs = red_s[0][c] + red_s[1][c] + red_s[2][c] + red_s[3][c];
            float qs = red_q[0][c] + red_q[1][c] + red_q[2][c] + red_q[3][c];
            unsafeAtomicAdd(&gsum[(size_t)b0 * HDIM + c], vs);
            unsafeAtomicAdd(&gsq[(size_t)b0 * HDIM + c], qs);
        }
    } else if (act) {
        unsafeAtomicAdd(&gsum[(size_t)b * HDIM + c], v);
        unsafeAtomicAdd(&gsq[(size_t)b * HDIM + c], v * v);
    }
}

// ---------------- per-(graph,channel): sums -> mean, inv-std ----------------
__global__ __launch_bounds__(256) void gstat(float* __restrict__ gsum,
                                             float* __restrict__ gsq,
                                             const float* __restrict__ gcnt,
                                             const float* __restrict__ alpha, int total) {
    int i = blockIdx.x * 256 + threadIdx.x;
    if (i < total) {
        int g = i >> 7, c = i & 127;
        float cnt = fmaxf(gcnt[g], 1.f);
        float mean = gsum[i] / cnt;
        float m2 = gsq[i] / cnt;
        float a = alpha[c];
        float var = m2 + mean * mean * (a * a - 2.f * a);
        gsum[i] = mean;
        gsq[i] = rsqrtf(fmaxf(var, 0.f) + EPSV);
    }
}

// ---------------- hidden matmul, fp16 in (fused l1 norm+relu), fp16 out ----------------
__global__ __launch_bounds__(256) void mm_h_fused(const __half* __restrict__ A16,
                                                  const float* __restrict__ gmean,
                                                  const float* __restrict__ gistd,
                                                  const float* __restrict__ alpha,
                                                  const float* __restrict__ w,
                                                  const float* __restrict__ bb,
                                                  const int* __restrict__ batch,
                                                  const float* __restrict__ W,
                                                  const float* __restrict__ dinv,
                                                  __half* __restrict__ Q, int N) {
    __shared__ float xs[64][65];
    __shared__ __align__(16) float ws[64][HDIM];
    __shared__ float pA[HDIM], pW[HDIM], pB[HDIM];
    int t = threadIdx.x;
    for (int i = t; i < HDIM; i += 256) { pA[i] = alpha[i]; pW[i] = w[i]; pB[i] = bb[i]; }
    int tx = t & 15;
    int ty = t >> 4;
    int n0 = blockIdx.x * 64;
    float acc[4][8];
#pragma unroll
    for (int i = 0; i < 4; i++)
#pragma unroll
        for (int j = 0; j < 8; j++) acc[i][j] = 0.f;

    for (int s = 0; s < 2; ++s) {
        __syncthreads();
        for (int i = t; i < 64 * 8; i += 256) {
            int nn = i >> 3;
            int kk = (i & 7) * 8;
            int gn = n0 + nn;
            float vv[8];
#pragma unroll
            for (int k = 0; k < 8; k++) vv[k] = 0.f;
            if (gn < N) {
                uint4 u = *(const uint4*)(A16 + (size_t)gn * HDIM + s * 64 + kk);
                int b = batch[gn];
                int c = s * 64 + kk;
                const float* mp = gmean + (size_t)b * HDIM + c;
                const float* ip = gistd + (size_t)b * HDIM + c;
                float2 f0 = __half22float2(*(__half2*)&u.x);
                float2 f1 = __half22float2(*(__half2*)&u.y);
                float2 f2 = __half22float2(*(__half2*)&u.z);
                float2 f3 = __half22float2(*(__half2*)&u.w);
                float f[8] = {f0.x, f0.y, f1.x, f1.y, f2.x, f2.y, f3.x, f3.y};
#pragma unroll
                for (int k = 0; k < 8; k++)
                    vv[k] = fmaxf(pW[c + k] * (f[k] - pA[c + k] * mp[k]) * ip[k] + pB[c + k], 0.f);
            }
#pragma unroll
            for (int k = 0; k < 8; k++) xs[nn][kk + k] = vv[k];
        }
        for (int i = t; i < 64 * 32; i += 256) {
            int kk = i >> 5;
            int c = (i & 31) * 4;
            *(float4*)&ws[kk][c] = *(const float4*)(W + (size_t)(s * 64 + kk) * HDIM + c);
        }
        __syncthreads();
#pragma unroll 8
        for (int kk = 0; kk < 64; ++kk) {
            float xv[4];
#pragma unroll
            for (int i = 0; i < 4; i++) xv[i] = xs[ty * 4 + i][kk];
            float4 w0 = *(const float4*)&ws[kk][tx * 4];
            float4 w1 = *(const float4*)&ws[kk][64 + tx * 4];
#pragma unroll
            for (int i = 0; i < 4; i++) {
                acc[i][0] += xv[i] * w0.x; acc[i][1] += xv[i] * w0.y;
                acc[i][2] += xv[i] * w0.z; acc[i][3] += xv[i] * w0.w;
                acc[i][4] += xv[i] * w1.x; acc[i][5] += xv[i] * w1.y;
                acc[i][6] += xv[i] * w1.z; acc[i][7] += xv[i] * w1.w;
            }
        }
    }
#pragma unroll
    for (int i = 0; i < 4; i++) {
        int gn = n0 + ty * 4 + i;
        if (gn >= N) continue;
        float dv = dinv[gn];
        __half2* q0 = (__half2*)(Q + (size_t)gn * HDIM + tx * 4);
        __half2* q1 = (__half2*)(Q + (size_t)gn * HDIM + 64 + tx * 4);
        q0[0] = __floats2half2_rn(acc[i][0] * dv, acc[i][1] * dv);
        q0[1] = __floats2half2_rn(acc[i][2] * dv, acc[i][3] * dv);
        q1[0] = __floats2half2_rn(acc[i][4] * dv, acc[i][5] * dv);
        q1[1] = __floats2half2_rn(acc[i][6] * dv, acc[i][7] * dv);
    }
}

// ---------------- fp16 row load: 4 channels (8B) ----------------
__device__ __forceinline__ float4 qrow4(const __half* __restrict__ Q, int e, int c4) {
    uint2 u = *(const uint2*)(Q + (size_t)e * HDIM + c4);
    float2 f0 = __half22float2(*(__half2*)&u.x);
    float2 f1 = __half22float2(*(__half2*)&u.y);
    return make_float4(f0.x, f0.y, f1.x, f1.y);
}

// ---------------- layer-2 CSR gather: half-wave per edge stream, 4ch/lane, deep unroll ----------------
__global__ __launch_bounds__(256) void node_agg2(const int* __restrict__ col,
                                                 const int* __restrict__ rowStart,
                                                 const __half* __restrict__ Q,
                                                 const float* __restrict__ dinv,
                                                 const float* __restrict__ bias,
                                                 const int* __restrict__ batch,
                                                 __half* __restrict__ A2,
                                                 float* __restrict__ gsum,
                                                 float* __restrict__ gsq, int N) {
    __shared__ __align__(16) float sv[4][HDIM];
    __shared__ __align__(16) float sq[4][HDIM];
    __shared__ int bsh[4];
    int wib = threadIdx.x >> 6;
    int lane = threadIdx.x & 63;
    int half = lane >> 5;
    int l = lane & 31;
    int c4 = l * 4;
    int n = blockIdx.x * 4 + wib;
    bool active = (n < N);
    float4 acc = make_float4(0.f, 0.f, 0.f, 0.f);
    int b = -1;
    if (active) {
        b = batch[n];
        int rs = rowStart[n], re = rowStart[n + 1];
        if (half == 0) acc = qrow4(Q, n, c4);          // self term
        int j = rs + half;
        // 8 edges per stream per iteration (16 per wave)
        for (; j + 14 < re; j += 16) {
            int e0 = col[j],      e1 = col[j + 2],  e2 = col[j + 4],  e3 = col[j + 6];
            int e4 = col[j + 8],  e5 = col[j + 10], e6 = col[j + 12], e7 = col[j + 14];
            float4 r0 = qrow4(Q, e0, c4);
            float4 r1 = qrow4(Q, e1, c4);
            float4 r2 = qrow4(Q, e2, c4);
            float4 r3 = qrow4(Q, e3, c4);
            float4 r4 = qrow4(Q, e4, c4);
            float4 r5 = qrow4(Q, e5, c4);
            float4 r6 = qrow4(Q, e6, c4);
            float4 r7 = qrow4(Q, e7, c4);
            acc.x += ((r0.x + r1.x) + (r2.x + r3.x)) + ((r4.x + r5.x) + (r6.x + r7.x));
            acc.y += ((r0.y + r1.y) + (r2.y + r3.y)) + ((r4.y + r5.y) + (r6.y + r7.y));
            acc.z += ((r0.z + r1.z) + (r2.z + r3.z)) + ((r4.z + r5.z) + (r6.z + r7.z));
            acc.w += ((r0.w + r1.w) + (r2.w + r3.w)) + ((r4.w + r5.w) + (r6.w + r7.w));
        }
        for (; j + 6 < re; j += 8) {
            int e0 = col[j], e1 = col[j + 2], e2 = col[j + 4], e3 = col[j + 6];
            float4 r0 = qrow4(Q, e0, c4);
            float4 r1 = qrow4(Q, e1, c4);
            float4 r2 = qrow4(Q, e2, c4);
            float4 r3 = qrow4(Q, e3, c4);
            acc.x += (r0.x + r1.x) + (r2.x + r3.x);
            acc.y += (r0.y + r1.y) + (r2.y + r3.y);
            acc.z += (r0.z + r1.z) + (r2.z + r3.z);
            acc.w += (r0.w + r1.w) + (r2.w + r3.w);
        }
        for (; j < re; j += 2) {
            float4 r = qrow4(Q, col[j], c4);
            acc.x += r.x; acc.y += r.y; acc.z += r.z; acc.w += r.w;
        }
        // combine even/odd edge streams
        acc.x += __shfl_xor(acc.x, 32);
        acc.y += __shfl_xor(acc.y, 32);
        acc.z += __shfl_xor(acc.z, 32);
        acc.w += __shfl_xor(acc.w, 32);
        float dv = dinv[n];
        acc.x = acc.x * dv + bias[c4];
        acc.y = acc.y * dv + bias[c4 + 1];
        acc.z = acc.z * dv + bias[c4 + 2];
        acc.w = acc.w * dv + bias[c4 + 3];
        if (half == 0) {
            __half2 o0 = __floats2half2_rn(acc.x, acc.y);
            __half2 o1 = __floats2half2_rn(acc.z, acc.w);
            uint2 u;
            u.x = *(unsigned int*)&o0;
            u.y = *(unsigned int*)&o1;
            *(uint2*)(A2 + (size_t)n * HDIM + c4) = u;
        }
    }
    if (lane == 0) bsh[wib] = active ? b : -1;
    if (half == 0) {
        float4 z = active ? acc : make_float4(0.f, 0.f, 0.f, 0.f);
        *(float4*)&sv[wib][c4] = z;
        *(float4*)&sq[wib][c4] = make_float4(z.x * z.x, z.y * z.y, z.z * z.z, z.w * z.w);
    }
    __syncthreads();
    int b0 = bsh[0];
    bool uni = (b0 >= 0) && (bsh[1] == b0) && (bsh[2] == b0) && (bsh[3] == b0);
    if (uni) {
        if (wib == 0 && half == 0) {
#pragma unroll
            for (int k = 0; k < 4; k++) {
                int c = c4 + k;
                float vs = sv[0][c] + sv[1][c] + sv[2][c] + sv[3][c];
                float qs = sq[0][c] + sq[1][c] + sq[2][c] + sq[3][c];
                unsafeAtomicAdd(&gsum[(size_t)b0 * HDIM + c], vs);
                unsafeAtomicAdd(&gsq[(size_t)b0 * HDIM + c], qs);
            }
        }
    } else if (active && half == 0) {
        float va[4] = {acc.x, acc.y, acc.z, acc.w};
#pragma unroll
        for (int k = 0; k < 4; k++) {
            int c = c4 + k;
            unsafeAtomicAdd(&gsum[(size_t)b * HDIM + c], va[k]);
            unsafeAtomicAdd(&gsq[(size_t)b * HDIM + c], va[k] * va[k]);
        }
    }
}

// ---------------- layer-2 normalize+relu fused with pool atomics (wave per node) ----------------
__global__ __launch_bounds__(256) void node_norm_pool(const __half* __restrict__ A2,
                                                      const float* __restrict__ gmean,
                                                      const float* __restrict__ gistd,
                                                      const float* __restrict__ alpha,
                                                      const float* __restrict__ w,
                                                      const float* __restrict__ bb,
                                                      const int* __restrict__ batch,
                                                      float* __restrict__ gpool, int N) {
    __shared__ float sv[4][HDIM];
    __shared__ int bsh[4];
    int wib = threadIdx.x >> 6, lane = threadIdx.x & 63;
    int c = lane * 2;
    int n = blockIdx.x * 4 + wib;
    bool active = (n < N);
    float2 y = make_float2(0.f, 0.f);
    int b = -1;
    if (active) {
        b = batch[n];
        float2 v = __half22float2(*(const __half2*)(A2 + (size_t)n * HDIM + c));
        float2 m = *(const float2*)(gmean + (size_t)b * HDIM + c);
        float2 is = *(const float2*)(gistd + (size_t)b * HDIM + c);
        y.x = fmaxf(w[c] * (v.x - alpha[c] * m.x) * is.x + bb[c], 0.f);
        y.y = fmaxf(w[c + 1] * (v.y - alpha[c + 1] * m.y) * is.y + bb[c + 1], 0.f);
    }
    if (lane == 0) bsh[wib] = active ? b : -1;
    sv[wib][c] = y.x; sv[wib][c + 1] = y.y;
    __syncthreads();
    int b0 = bsh[0];
    bool uni = (b0 >= 0) && (bsh[1] == b0) && (bsh[2] == b0) && (bsh[3] == b0);
    if (uni) {
        if (wib == 0) {
            float vx = sv[0][c] + sv[1][c] + sv[2][c] + sv[3][c];
            float vy = sv[0][c + 1] + sv[1][c + 1] + sv[2][c + 1] + sv[3][c + 1];
            unsafeAtomicAdd(&gpool[(size_t)b0 * HDIM + c], vx);
            unsafeAtomicAdd(&gpool[(size_t)b0 * HDIM + c + 1], vy);
        }
    } else if (active) {
        unsafeAtomicAdd(&gpool[(size_t)b * HDIM + c], y.x);
        unsafeAtomicAdd(&gpool[(size_t)b * HDIM + c + 1], y.y);
    }
}

// ---------------- head ----------------
__global__ __launch_bounds__(128) void head(const float* __restrict__ gpool,
                                            const float* __restrict__ gcnt,
                                            const float* __restrict__ H1,
                                            const float* __restrict__ hb1,
                                            const float* __restrict__ H2,
                                            const float* __restrict__ hb2,
                                            float* __restrict__ out, int G) {
    __shared__ float gv[HDIM];
    __shared__ float tv[HDIM];
    __shared__ float r0[HDIM], r1[HDIM];
    int g = blockIdx.x;
    int c = threadIdx.x;
    float cnt = fmaxf(gcnt[g], 1.0f);
    gv[c] = gpool[(long long)g * HDIM + c] / cnt;
    __syncthreads();
    float s = hb1[c];
    for (int k = 0; k < HDIM; k++) s += gv[k] * H1[k * HDIM + c];
    tv[c] = fmaxf(s, 0.f);
    __syncthreads();
    r0[c] = tv[c] * H2[c * 2 + 0];
    r1[c] = tv[c] * H2[c * 2 + 1];
    __syncthreads();
    for (int off = 64; off > 0; off >>= 1) {
        if (c < off) { r0[c] += r0[c + off]; r1[c] += r1[c + off]; }
        __syncthreads();
    }
    if (c == 0) {
        out[(long long)g * 2 + 0] = r0[0] + hb2[0];
        out[(long long)g * 2 + 1] = r1[0] + hb2[1];
    }
}

extern "C" void kernel_launch(void* const* d_in, const int* in_sizes, int n_in,
                              void* d_out, int out_size, void* d_ws, size_t ws_size,
                              hipStream_t stream) {
    const float* x    = (const float*)d_in[0];
    const int*   ei   = (const int*)d_in[1];
    const int*   batch= (const int*)d_in[2];
    const float* W1   = (const float*)d_in[4];
    const float* b1   = (const float*)d_in[5];
    const float* gn1w = (const float*)d_in[6];
    const float* gn1b = (const float*)d_in[7];
    const float* gn1a = (const float*)d_in[8];
    const float* W2   = (const float*)d_in[9];
    const float* b2   = (const float*)d_in[10];
    const float* gn2w = (const float*)d_in[11];
    const float* gn2b = (const float*)d_in[12];
    const float* gn2a = (const float*)d_in[13];
    const float* H1   = (const float*)d_in[14];
    const float* hb1  = (const float*)d_in[15];
    const float* H2   = (const float*)d_in[16];
    const float* hb2  = (const float*)d_in[17];

    int N = in_sizes[0] / 7;
    int E = in_sizes[1] / 2;
    int G = out_size / 2;
    const int* srcI = ei;
    const int* dstI = ei + E;

    int NB = (N + BKT_SIZE - 1) >> BKT_SHIFT;
    int NCHUNK = (E + CHK - 1) / CHK;

    // workspace layout
    __half* A16   = (__half*)d_ws;                   // N*128 half (layer1 pre-norm)
    __half* A2    = A16;                             // alias: layer2 pre-norm (A16 dead by then)
    __half* Q16   = A16 + (size_t)N * HDIM;          // N*128 half
    float*  xs    = (float*)(Q16 + (size_t)N * HDIM);// N*8
    float*  agg   = xs + (size_t)N * 8;              // N*8
    float*  gsum1 = agg + (size_t)N * 8;             // G*128
    float*  gsq1  = gsum1 + (size_t)G * HDIM;        // G*128
    float*  gsum2 = gsq1 + (size_t)G * HDIM;         // G*128
    float*  gsq2  = gsum2 + (size_t)G * HDIM;        // G*128
    float*  gpool = gsq2 + (size_t)G * HDIM;         // G*128
    float*  gcnt  = gpool + (size_t)G * HDIM;        // G
    float*  dinv  = gcnt + G;                        // N
    int* rowStart = (int*)(dinv + N);                // N+2
    unsigned int* EP = (unsigned int*)(rowStart + N + 2); // E
    int* col      = (int*)(EP + E);                  // E
    int* histG    = col + E;                         // NCHUNK*NB
    int* tot      = histG + (size_t)NCHUNK * NB;     // NB+2
    int* bucketBase = tot + NB + 2;                  // NB+2

    int gridNW = (N + 3) / 4;
    int gridGH = (G * HDIM + 255) / 256;
    int gridMM = (N + 63) / 64;

    // single upfront memset: gsum1,gsq1,gsum2,gsq2,gpool,gcnt
    hipMemsetAsync(gsum1, 0, ((size_t)G * HDIM * 5 + G) * 4, stream);

    // ---- CSR build ----
    hist_pass<<<NCHUNK, 256, 0, stream>>>(dstI, histG, E, NB);
    scan_chunks<<<NB, 512, 0, stream>>>(histG, tot, NCHUNK, NB);
    scan_tot_k<<<1, 512, 0, stream>>>(tot, bucketBase, rowStart, NB, N, E);
    add_base<<<((NCHUNK * NB) + 255) / 256, 256, 0, stream>>>(histG, bucketBase, NCHUNK * NB, NB);
    scatter_bkt<<<NCHUNK, 256, 0, stream>>>(srcI, dstI, histG, EP, E, NB);
    bucket_csr<<<NB, 512, 0, stream>>>(EP, bucketBase, rowStart, dinv, col, N);

    // ---- block 1 (rank-7 aggregation) ----
    long long nx8 = (long long)N * 8;
    prep_xs<<<(int)((nx8 + 255) / 256), 256, 0, stream>>>(x, dinv, batch, xs, gcnt, nx8);
    agg7k<<<gridNW, 256, 0, stream>>>(col, rowStart, xs, agg, N);
    l1post<<<gridNW, 512, 0, stream>>>(agg, W1, b1, dinv, batch, A16, gsum1, gsq1, N);
    gstat<<<gridGH, 256, 0, stream>>>(gsum1, gsq1, gcnt, gn1a, G * HDIM);

    // ---- mm_h with fused layer-1 norm+relu, fp16 in/out ----
    mm_h_fused<<<gridMM, 256, 0, stream>>>(A16, gsum1, gsq1, gn1a, gn1w, gn1b, batch,
                                           W2, dinv, Q16, N);

    // ---- block 2 (fp16 gather, 2 half-wave edge streams, deep unroll) ----
    node_agg2<<<gridNW, 256, 0, stream>>>(col, rowStart, Q16, dinv, b2, batch, A2,
                                          gsum2, gsq2, N);
    gstat<<<gridGH, 256, 0, stream>>>(gsum2, gsq2, gcnt, gn2a, G * HDIM);

    // ---- layer-2 norm + relu + pool fused ----
    node_norm_pool<<<gridNW, 256, 0, stream>>>(A2, gsum2, gsq2, gn2a, gn2w, gn2b, batch, gpool, N);

    // ---- head ----
    head<<<G, 128, 0, stream>>>(gpool, gcnt, H1, hb1, H2, hb2, (float*)d_out, G);
}

// Round 8
// 503.720 us; speedup vs baseline: 1.3366x; 1.0688x over previous
//
#include <hip/hip_runtime.h>
#include <hip/hip_fp16.h>

#define EPSV 1e-5f
#define HDIM 128
#define BKT_SHIFT 9
#define BKT_SIZE 512
#define CHK 8192

typedef _Float16 f16x8 __attribute__((ext_vector_type(8)));
typedef float f32x4 __attribute__((ext_vector_type(4)));

// ================= CSR build: bucketed counting sort =================

__global__ __launch_bounds__(256) void hist_pass(const int* __restrict__ dst,
                                                 int* __restrict__ histG, int E, int NB) {
    __shared__ int h[BKT_SIZE];
    int t = threadIdx.x;
    for (int i = t; i < NB; i += 256) h[i] = 0;
    __syncthreads();
    int base = blockIdx.x * CHK;
    int end = min(base + CHK, E);
    for (int e = base + t; e < end; e += 256) atomicAdd(&h[dst[e] >> BKT_SHIFT], 1);
    __syncthreads();
    for (int i = t; i < NB; i += 256) histG[(size_t)blockIdx.x * NB + i] = h[i];
}

__global__ __launch_bounds__(512) void scan_chunks(int* __restrict__ histG,
                                                   int* __restrict__ tot,
                                                   int NCHUNK, int NB) {
    __shared__ int tmp[512];
    int b = blockIdx.x, t = threadIdx.x;
    int v = (t < NCHUNK) ? histG[(size_t)t * NB + b] : 0;
    tmp[t] = v;
    __syncthreads();
    for (int off = 1; off < 512; off <<= 1) {
        int x = (t >= off) ? tmp[t - off] : 0;
        __syncthreads();
        tmp[t] += x;
        __syncthreads();
    }
    if (t < NCHUNK) histG[(size_t)t * NB + b] = tmp[t] - v;
    if (t == 511) tot[b] = tmp[511];
}

__global__ __launch_bounds__(512) void scan_tot_k(const int* __restrict__ tot,
                                                  int* __restrict__ bucketBase,
                                                  int* __restrict__ rowStart,
                                                  int NB, int N, int E) {
    __shared__ int tmp[512];
    int t = threadIdx.x;
    int v = (t < NB) ? tot[t] : 0;
    tmp[t] = v;
    __syncthreads();
    for (int off = 1; off < 512; off <<= 1) {
        int x = (t >= off) ? tmp[t - off] : 0;
        __syncthreads();
        tmp[t] += x;
        __syncthreads();
    }
    if (t < NB) bucketBase[t] = tmp[t] - v;
    if (t == NB - 1) {
        bucketBase[NB] = tmp[t];
        rowStart[N] = E;
    }
}

__global__ __launch_bounds__(256) void add_base(int* __restrict__ histG,
                                                const int* __restrict__ bucketBase,
                                                int total, int NB) {
    int i = blockIdx.x * 256 + threadIdx.x;
    if (i < total) histG[i] += bucketBase[i % NB];
}

__global__ __launch_bounds__(256) void scatter_bkt(const int* __restrict__ src,
                                                   const int* __restrict__ dst,
                                                   const int* __restrict__ chunkOff,
                                                   unsigned int* __restrict__ EP,
                                                   int E, int NB) {
    __shared__ int cur[BKT_SIZE];
    int t = threadIdx.x, c = blockIdx.x;
    for (int i = t; i < NB; i += 256) cur[i] = chunkOff[(size_t)c * NB + i];
    __syncthreads();
    int base = c * CHK, end = min(base + CHK, E);
    for (int e = base + t; e < end; e += 256) {
        int d = dst[e];
        int b = d >> BKT_SHIFT;
        int pos = atomicAdd(&cur[b], 1);
        EP[pos] = (unsigned int)src[e] | ((unsigned int)(d & (BKT_SIZE - 1)) << 23);
    }
}

__global__ __launch_bounds__(512) void bucket_csr(const unsigned int* __restrict__ EP,
                                                  const int* __restrict__ bucketBase,
                                                  int* __restrict__ rowStart,
                                                  float* __restrict__ dinv,
                                                  int* __restrict__ col, int N) {
    __shared__ int cnt[BKT_SIZE];
    __shared__ int tmp[BKT_SIZE];
    int b = blockIdx.x, t = threadIdx.x;
    int ebase = bucketBase[b], eend = bucketBase[b + 1];
    cnt[t] = 0;
    __syncthreads();
    for (int e = ebase + t; e < eend; e += 512)
        atomicAdd(&cnt[(EP[e] >> 23) & 511], 1);
    __syncthreads();
    int v = cnt[t];
    tmp[t] = v;
    __syncthreads();
    for (int off = 1; off < 512; off <<= 1) {
        int x = (t >= off) ? tmp[t - off] : 0;
        __syncthreads();
        tmp[t] += x;
        __syncthreads();
    }
    int excl = tmp[t] - v;
    int n = (b << BKT_SHIFT) + t;
    if (n < N) {
        rowStart[n] = ebase + excl;
        dinv[n] = rsqrtf((float)v + 1.0f);
    }
    __syncthreads();
    cnt[t] = ebase + excl;
    __syncthreads();
    for (int e = ebase + t; e < eend; e += 512) {
        unsigned int p = EP[e];
        int ld = (p >> 23) & 511;
        int pos = atomicAdd(&cnt[ld], 1);
        col[pos] = (int)(p & 0x7FFFFFu);
    }
}

// ---------------- W2^T in fp16 (once) ----------------
__global__ __launch_bounds__(256) void prep_w2t(const float* __restrict__ W2,
                                                __half* __restrict__ W2t) {
    int i = blockIdx.x * 256 + threadIdx.x;   // i over 128*128
    if (i < HDIM * HDIM) {
        int c = i >> 7, k = i & 127;
        W2t[c * HDIM + k] = __float2half(W2[k * HDIM + c]);
    }
}

// ---------------- xs = dinv * x, padded [N][8]; also per-graph node counts ----------------
__global__ __launch_bounds__(256) void prep_xs(const float* __restrict__ x,
                                               const float* __restrict__ dinv,
                                               const int* __restrict__ batch,
                                               float* __restrict__ xs,
                                               float* __restrict__ gcnt, long long total) {
    long long idx = (long long)blockIdx.x * 256 + threadIdx.x;
    if (idx >= total) return;
    int n = (int)(idx >> 3), k = (int)(idx & 7);
    xs[idx] = (k < 7) ? x[(long long)n * 7 + k] * dinv[n] : 0.f;
    if (k == 7) unsafeAtomicAdd(&gcnt[batch[n]], 1.0f);
}

// ---------------- layer-1 aggregation: wave per node, 4 lanes/edge x 16 streams ----------------
__global__ __launch_bounds__(256) void agg7k(const int* __restrict__ col,
                                             const int* __restrict__ rowStart,
                                             const float* __restrict__ xs,
                                             float* __restrict__ agg, int N) {
    int wib = threadIdx.x >> 6, lane = threadIdx.x & 63;
    int stream = lane >> 2;          // 0..15
    int c2 = (lane & 3) * 2;         // channel pair
    int n = blockIdx.x * 4 + wib;
    if (n >= N) return;              // wave-uniform
    float2 acc = make_float2(0.f, 0.f);
    int rs = rowStart[n], re = rowStart[n + 1];
    if (stream == 0) acc = *(const float2*)(xs + (size_t)n * 8 + c2);   // self
    int j = rs + stream;
    for (; j + 16 < re; j += 32) {
        int e0 = col[j], e1 = col[j + 16];
        float2 r0 = *(const float2*)(xs + (size_t)e0 * 8 + c2);
        float2 r1 = *(const float2*)(xs + (size_t)e1 * 8 + c2);
        acc.x += r0.x + r1.x;
        acc.y += r0.y + r1.y;
    }
    for (; j < re; j += 16) {
        float2 r = *(const float2*)(xs + (size_t)col[j] * 8 + c2);
        acc.x += r.x; acc.y += r.y;
    }
#pragma unroll
    for (int off = 4; off <= 32; off <<= 1) {
        acc.x += __shfl_xor(acc.x, off);
        acc.y += __shfl_xor(acc.y, off);
    }
    if (stream == 0) *(float2*)(agg + (size_t)n * 8 + c2) = acc;
}

// ---------------- layer-1 post: A16 = half(dinv*(agg@W1)+b1), accumulate stats ----------------
__global__ __launch_bounds__(512) void l1post(const float* __restrict__ agg,
                                              const float* __restrict__ W1,
                                              const float* __restrict__ b1,
                                              const float* __restrict__ dinv,
                                              const int* __restrict__ batch,
                                              __half* __restrict__ A16,
                                              float* __restrict__ gsum,
                                              float* __restrict__ gsq, int N) {
    __shared__ float w1s[7 * HDIM];
    __shared__ float red_s[4][HDIM], red_q[4][HDIM];
    __shared__ int bsh[4];
    int t = threadIdx.x;
    for (int i = t; i < 7 * HDIM; i += 512) w1s[i] = W1[i];
    int wib = t >> 7, c = t & 127;
    int n = blockIdx.x * 4 + wib;
    __syncthreads();
    bool act = (n < N);
    float v = 0.f;
    int b = -1;
    if (act) {
        b = batch[n];
        const float* ar = agg + (size_t)n * 8;
        float s = 0.f;
#pragma unroll
        for (int k = 0; k < 7; k++) s += ar[k] * w1s[k * HDIM + c];
        v = s * dinv[n] + b1[c];
        A16[(size_t)n * HDIM + c] = __float2half(v);
    }
    if (c == 0) bsh[wib] = act ? b : -1;
    red_s[wib][c] = v;
    red_q[wib][c] = v * v;
    __syncthreads();
    int b0 = bsh[0];
    bool uni = (b0 >= 0) && (bsh[1] == b0) && (bsh[2] == b0) && (bsh[3] == b0);
    if (uni) {
        if (wib == 0) {
            float vs = red_s[0][c] + red_s[1][c] + red_s[2][c] + red_s[3][c];
            float qs = red_q[0][c] + red_q[1][c] + red_q[2][c] + red_q[3][c];
            unsafeAtomicAdd(&gsum[(size_t)b0 * HDIM + c], vs);
            unsafeAtomicAdd(&gsq[(size_t)b0 * HDIM + c], qs);
        }
    } else if (act) {
        unsafeAtomicAdd(&gsum[(size_t)b * HDIM + c], v);
        unsafeAtomicAdd(&gsq[(size_t)b * HDIM + c], v * v);
    }
}

// ---------------- per-(graph,channel): sums -> mean, inv-std ----------------
__global__ __launch_bounds__(256) void gstat(float* __restrict__ gsum,
                                             float* __restrict__ gsq,
                                             const float* __restrict__ gcnt,
                                             const float* __restrict__ alpha, int total) {
    int i = blockIdx.x * 256 + threadIdx.x;
    if (i < total) {
        int g = i >> 7, c = i & 127;
        float cnt = fmaxf(gcnt[g], 1.f);
        float mean = gsum[i] / cnt;
        float m2 = gsq[i] / cnt;
        float a = alpha[c];
        float var = m2 + mean * mean * (a * a - 2.f * a);
        gsum[i] = mean;
        gsq[i] = rsqrtf(fmaxf(var, 0.f) + EPSV);
    }
}

// ---------------- hidden matmul via MFMA: Q = half(dinv * (relu(norm(A16)) @ W2)) ----------------
// block: 256 threads = 4 waves; tile 64 nodes x 128 ch; K = 128 in 4 steps of 32.
__global__ __launch_bounds__(256) void mm_h_mfma(const __half* __restrict__ A16,
                                                 const float* __restrict__ gmean,
                                                 const float* __restrict__ gistd,
                                                 const float* __restrict__ alpha,
                                                 const float* __restrict__ w,
                                                 const float* __restrict__ bb,
                                                 const int* __restrict__ batch,
                                                 const __half* __restrict__ W2t,
                                                 const float* __restrict__ dinv,
                                                 __half* __restrict__ Q, int N) {
    __shared__ _Float16 XS[64][136];    // padded: row stride 272B -> ~2-way bank aliasing (free)
    __shared__ _Float16 WT[HDIM][136];  // W2^T: [col][k]
    __shared__ float pA[HDIM], pW[HDIM], pB[HDIM];
    int t = threadIdx.x;
    for (int i = t; i < HDIM; i += 256) { pA[i] = alpha[i]; pW[i] = w[i]; pB[i] = bb[i]; }
    int n0 = blockIdx.x * 64;

    // stage W2t: 128 rows x 128 halves, uint4 = 8 halves
    for (int i = t; i < HDIM * 16; i += 256) {
        int row = i >> 4;
        int kk = (i & 15) * 8;
        *(uint4*)&WT[row][kk] = *(const uint4*)(W2t + (size_t)row * HDIM + kk);
    }
    __syncthreads();  // pA/pW/pB ready before XS staging uses them

    // stage XS with fused layer-1 norm + relu
    for (int i = t; i < 64 * 16; i += 256) {
        int nn = i >> 4;
        int kk = (i & 15) * 8;
        int gn = n0 + nn;
        __half hv[8];
#pragma unroll
        for (int k = 0; k < 8; k++) hv[k] = __float2half(0.f);
        if (gn < N) {
            uint4 u = *(const uint4*)(A16 + (size_t)gn * HDIM + kk);
            int b = batch[gn];
            const float* mp = gmean + (size_t)b * HDIM + kk;
            const float* ip = gistd + (size_t)b * HDIM + kk;
            float2 f0 = __half22float2(*(__half2*)&u.x);
            float2 f1 = __half22float2(*(__half2*)&u.y);
            float2 f2 = __half22float2(*(__half2*)&u.z);
            float2 f3 = __half22float2(*(__half2*)&u.w);
            float f[8] = {f0.x, f0.y, f1.x, f1.y, f2.x, f2.y, f3.x, f3.y};
#pragma unroll
            for (int k = 0; k < 8; k++) {
                int c = kk + k;
                hv[k] = __float2half(fmaxf(pW[c] * (f[k] - pA[c] * mp[k]) * ip[k] + pB[c], 0.f));
            }
        }
        *(uint4*)&XS[nn][kk] = *(uint4*)hv;
    }
    __syncthreads();

    int wid = t >> 6, lane = t & 63;
    int m0 = wid * 16;                 // wave's 16 rows
    int rlane = lane & 15;
    int kgrp = lane >> 4;              // 0..3
    f32x4 acc[8];
#pragma unroll
    for (int ct = 0; ct < 8; ct++) acc[ct] = (f32x4){0.f, 0.f, 0.f, 0.f};

#pragma unroll
    for (int kt = 0; kt < 4; ++kt) {
        int kbase = kt * 32 + kgrp * 8;
        f16x8 a = *(const f16x8*)&XS[m0 + rlane][kbase];
#pragma unroll
        for (int ct = 0; ct < 8; ++ct) {
            f16x8 bfr = *(const f16x8*)&WT[ct * 16 + rlane][kbase];
            acc[ct] = __builtin_amdgcn_mfma_f32_16x16x32_f16(a, bfr, acc[ct], 0, 0, 0);
        }
    }

    // epilogue: C layout col=lane&15, row=(lane>>4)*4+r
    int rgrp = lane >> 4;
    float dv[4];
    int gnr[4];
#pragma unroll
    for (int r = 0; r < 4; r++) {
        gnr[r] = n0 + m0 + rgrp * 4 + r;
        dv[r] = (gnr[r] < N) ? dinv[gnr[r]] : 0.f;
    }
#pragma unroll
    for (int ct = 0; ct < 8; ++ct) {
#pragma unroll
        for (int r = 0; r < 4; ++r) {
            if (gnr[r] < N)
                Q[(size_t)gnr[r] * HDIM + ct * 16 + rlane] = __float2half(acc[ct][r] * dv[r]);
        }
    }
}

// ---------------- fp16 row load: 4 channels (8B) ----------------
__device__ __forceinline__ float4 qrow4(const __half* __restrict__ Q, int e, int c4) {
    uint2 u = *(const uint2*)(Q + (size_t)e * HDIM + c4);
    float2 f0 = __half22float2(*(__half2*)&u.x);
    float2 f1 = __half22float2(*(__half2*)&u.y);
    return make_float4(f0.x, f0.y, f1.x, f1.y);
}

// ---------------- layer-2 CSR gather: half-wave per edge stream, 4ch/lane, deep unroll ----------------
__global__ __launch_bounds__(256) void node_agg2(const int* __restrict__ col,
                                                 const int* __restrict__ rowStart,
                                                 const __half* __restrict__ Q,
                                                 const float* __restrict__ dinv,
                                                 const float* __restrict__ bias,
                                                 const int* __restrict__ batch,
                                                 __half* __restrict__ A2,
                                                 float* __restrict__ gsum,
                                                 float* __restrict__ gsq, int N) {
    __shared__ __align__(16) float sv[4][HDIM];
    __shared__ __align__(16) float sq[4][HDIM];
    __shared__ int bsh[4];
    int wib = threadIdx.x >> 6;
    int lane = threadIdx.x & 63;
    int half = lane >> 5;
    int l = lane & 31;
    int c4 = l * 4;
    int n = blockIdx.x * 4 + wib;
    bool active = (n < N);
    float4 acc = make_float4(0.f, 0.f, 0.f, 0.f);
    int b = -1;
    if (active) {
        b = batch[n];
        int rs = rowStart[n], re = rowStart[n + 1];
        if (half == 0) acc = qrow4(Q, n, c4);          // self term
        int j = rs + half;
        for (; j + 14 < re; j += 16) {
            int e0 = col[j],      e1 = col[j + 2],  e2 = col[j + 4],  e3 = col[j + 6];
            int e4 = col[j + 8],  e5 = col[j + 10], e6 = col[j + 12], e7 = col[j + 14];
            float4 r0 = qrow4(Q, e0, c4);
            float4 r1 = qrow4(Q, e1, c4);
            float4 r2 = qrow4(Q, e2, c4);
            float4 r3 = qrow4(Q, e3, c4);
            float4 r4 = qrow4(Q, e4, c4);
            float4 r5 = qrow4(Q, e5, c4);
            float4 r6 = qrow4(Q, e6, c4);
            float4 r7 = qrow4(Q, e7, c4);
            acc.x += ((r0.x + r1.x) + (r2.x + r3.x)) + ((r4.x + r5.x) + (r6.x + r7.x));
            acc.y += ((r0.y + r1.y) + (r2.y + r3.y)) + ((r4.y + r5.y) + (r6.y + r7.y));
            acc.z += ((r0.z + r1.z) + (r2.z + r3.z)) + ((r4.z + r5.z) + (r6.z + r7.z));
            acc.w += ((r0.w + r1.w) + (r2.w + r3.w)) + ((r4.w + r5.w) + (r6.w + r7.w));
        }
        for (; j + 6 < re; j += 8) {
            int e0 = col[j], e1 = col[j + 2], e2 = col[j + 4], e3 = col[j + 6];
            float4 r0 = qrow4(Q, e0, c4);
            float4 r1 = qrow4(Q, e1, c4);
            float4 r2 = qrow4(Q, e2, c4);
            float4 r3 = qrow4(Q, e3, c4);
            acc.x += (r0.x + r1.x) + (r2.x + r3.x);
            acc.y += (r0.y + r1.y) + (r2.y + r3.y);
            acc.z += (r0.z + r1.z) + (r2.z + r3.z);
            acc.w += (r0.w + r1.w) + (r2.w + r3.w);
        }
        for (; j < re; j += 2) {
            float4 r = qrow4(Q, col[j], c4);
            acc.x += r.x; acc.y += r.y; acc.z += r.z; acc.w += r.w;
        }
        acc.x += __shfl_xor(acc.x, 32);
        acc.y += __shfl_xor(acc.y, 32);
        acc.z += __shfl_xor(acc.z, 32);
        acc.w += __shfl_xor(acc.w, 32);
        float dv = dinv[n];
        acc.x = acc.x * dv + bias[c4];
        acc.y = acc.y * dv + bias[c4 + 1];
        acc.z = acc.z * dv + bias[c4 + 2];
        acc.w = acc.w * dv + bias[c4 + 3];
        if (half == 0) {
            __half2 o0 = __floats2half2_rn(acc.x, acc.y);
            __half2 o1 = __floats2half2_rn(acc.z, acc.w);
            uint2 u;
            u.x = *(unsigned int*)&o0;
            u.y = *(unsigned int*)&o1;
            *(uint2*)(A2 + (size_t)n * HDIM + c4) = u;
        }
    }
    if (lane == 0) bsh[wib] = active ? b : -1;
    if (half == 0) {
        float4 z = active ? acc : make_float4(0.f, 0.f, 0.f, 0.f);
        *(float4*)&sv[wib][c4] = z;
        *(float4*)&sq[wib][c4] = make_float4(z.x * z.x, z.y * z.y, z.z * z.z, z.w * z.w);
    }
    __syncthreads();
    int b0 = bsh[0];
    bool uni = (b0 >= 0) && (bsh[1] == b0) && (bsh[2] == b0) && (bsh[3] == b0);
    if (uni) {
        if (wib == 0 && half == 0) {
#pragma unroll
            for (int k = 0; k < 4; k++) {
                int c = c4 + k;
                float vs = sv[0][c] + sv[1][c] + sv[2][c] + sv[3][c];
                float qs = sq[0][c] + sq[1][c] + sq[2][c] + sq[3][c];
                unsafeAtomicAdd(&gsum[(size_t)b0 * HDIM + c], vs);
                unsafeAtomicAdd(&gsq[(size_t)b0 * HDIM + c], qs);
            }
        }
    } else if (active && half == 0) {
        float va[4] = {acc.x, acc.y, acc.z, acc.w};
#pragma unroll
        for (int k = 0; k < 4; k++) {
            int c = c4 + k;
            unsafeAtomicAdd(&gsum[(size_t)b * HDIM + c], va[k]);
            unsafeAtomicAdd(&gsq[(size_t)b * HDIM + c], va[k] * va[k]);
        }
    }
}

// ---------------- layer-2 normalize+relu fused with pool atomics (wave per node) ----------------
__global__ __launch_bounds__(256) void node_norm_pool(const __half* __restrict__ A2,
                                                      const float* __restrict__ gmean,
                                                      const float* __restrict__ gistd,
                                                      const float* __restrict__ alpha,
                                                      const float* __restrict__ w,
                                                      const float* __restrict__ bb,
                                                      const int* __restrict__ batch,
                                                      float* __restrict__ gpool, int N) {
    __shared__ float sv[4][HDIM];
    __shared__ int bsh[4];
    int wib = threadIdx.x >> 6, lane = threadIdx.x & 63;
    int c = lane * 2;
    int n = blockIdx.x * 4 + wib;
    bool active = (n < N);
    float2 y = make_float2(0.f, 0.f);
    int b = -1;
    if (active) {
        b = batch[n];
        float2 v = __half22float2(*(const __half2*)(A2 + (size_t)n * HDIM + c));
        float2 m = *(const float2*)(gmean + (size_t)b * HDIM + c);
        float2 is = *(const float2*)(gistd + (size_t)b * HDIM + c);
        y.x = fmaxf(w[c] * (v.x - alpha[c] * m.x) * is.x + bb[c], 0.f);
        y.y = fmaxf(w[c + 1] * (v.y - alpha[c + 1] * m.y) * is.y + bb[c + 1], 0.f);
    }
    if (lane == 0) bsh[wib] = active ? b : -1;
    sv[wib][c] = y.x; sv[wib][c + 1] = y.y;
    __syncthreads();
    int b0 = bsh[0];
    bool uni = (b0 >= 0) && (bsh[1] == b0) && (bsh[2] == b0) && (bsh[3] == b0);
    if (uni) {
        if (wib == 0) {
            float vx = sv[0][c] + sv[1][c] + sv[2][c] + sv[3][c];
            float vy = sv[0][c + 1] + sv[1][c + 1] + sv[2][c + 1] + sv[3][c + 1];
            unsafeAtomicAdd(&gpool[(size_t)b0 * HDIM + c], vx);
            unsafeAtomicAdd(&gpool[(size_t)b0 * HDIM + c + 1], vy);
        }
    } else if (active) {
        unsafeAtomicAdd(&gpool[(size_t)b * HDIM + c], y.x);
        unsafeAtomicAdd(&gpool[(size_t)b * HDIM + c + 1], y.y);
    }
}

// ---------------- head ----------------
__global__ __launch_bounds__(128) void head(const float* __restrict__ gpool,
                                            const float* __restrict__ gcnt,
                                            const float* __restrict__ H1,
                                            const float* __restrict__ hb1,
                                            const float* __restrict__ H2,
                                            const float* __restrict__ hb2,
                                            float* __restrict__ out, int G) {
    __shared__ float gv[HDIM];
    __shared__ float tv[HDIM];
    __shared__ float r0[HDIM], r1[HDIM];
    int g = blockIdx.x;
    int c = threadIdx.x;
    float cnt = fmaxf(gcnt[g], 1.0f);
    gv[c] = gpool[(long long)g * HDIM + c] / cnt;
    __syncthreads();
    float s = hb1[c];
    for (int k = 0; k < HDIM; k++) s += gv[k] * H1[k * HDIM + c];
    tv[c] = fmaxf(s, 0.f);
    __syncthreads();
    r0[c] = tv[c] * H2[c * 2 + 0];
    r1[c] = tv[c] * H2[c * 2 + 1];
    __syncthreads();
    for (int off = 64; off > 0; off >>= 1) {
        if (c < off) { r0[c] += r0[c + off]; r1[c] += r1[c + off]; }
        __syncthreads();
    }
    if (c == 0) {
        out[(long long)g * 2 + 0] = r0[0] + hb2[0];
        out[(long long)g * 2 + 1] = r1[0] + hb2[1];
    }
}

extern "C" void kernel_launch(void* const* d_in, const int* in_sizes, int n_in,
                              void* d_out, int out_size, void* d_ws, size_t ws_size,
                              hipStream_t stream) {
    const float* x    = (const float*)d_in[0];
    const int*   ei   = (const int*)d_in[1];
    const int*   batch= (const int*)d_in[2];
    const float* W1   = (const float*)d_in[4];
    const float* b1   = (const float*)d_in[5];
    const float* gn1w = (const float*)d_in[6];
    const float* gn1b = (const float*)d_in[7];
    const float* gn1a = (const float*)d_in[8];
    const float* W2   = (const float*)d_in[9];
    const float* b2   = (const float*)d_in[10];
    const float* gn2w = (const float*)d_in[11];
    const float* gn2b = (const float*)d_in[12];
    const float* gn2a = (const float*)d_in[13];
    const float* H1   = (const float*)d_in[14];
    const float* hb1  = (const float*)d_in[15];
    const float* H2   = (const float*)d_in[16];
    const float* hb2  = (const float*)d_in[17];

    int N = in_sizes[0] / 7;
    int E = in_sizes[1] / 2;
    int G = out_size / 2;
    const int* srcI = ei;
    const int* dstI = ei + E;

    int NB = (N + BKT_SIZE - 1) >> BKT_SHIFT;
    int NCHUNK = (E + CHK - 1) / CHK;

    // workspace layout
    __half* A16   = (__half*)d_ws;                   // N*128 half (layer1 pre-norm)
    __half* A2    = A16;                             // alias: layer2 pre-norm (A16 dead by then)
    __half* Q16   = A16 + (size_t)N * HDIM;          // N*128 half
    float*  xs    = (float*)(Q16 + (size_t)N * HDIM);// N*8
    float*  agg   = xs + (size_t)N * 8;              // N*8
    float*  gsum1 = agg + (size_t)N * 8;             // G*128
    float*  gsq1  = gsum1 + (size_t)G * HDIM;        // G*128
    float*  gsum2 = gsq1 + (size_t)G * HDIM;         // G*128
    float*  gsq2  = gsum2 + (size_t)G * HDIM;        // G*128
    float*  gpool = gsq2 + (size_t)G * HDIM;         // G*128
    float*  gcnt  = gpool + (size_t)G * HDIM;        // G
    float*  dinv  = gcnt + G;                        // N
    int* rowStart = (int*)(dinv + N);                // N+2
    unsigned int* EP = (unsigned int*)(rowStart + N + 2); // E
    int* col      = (int*)(EP + E);                  // E
    int* histG    = col + E;                         // NCHUNK*NB
    int* tot      = histG + (size_t)NCHUNK * NB;     // NB+2
    int* bucketBase = tot + NB + 2;                  // NB+2
    __half* W2t   = (__half*)(bucketBase + NB + 2);  // 128*128 half

    int gridNW = (N + 3) / 4;
    int gridGH = (G * HDIM + 255) / 256;
    int gridMM = (N + 63) / 64;

    // single upfront memset: gsum1,gsq1,gsum2,gsq2,gpool,gcnt
    hipMemsetAsync(gsum1, 0, ((size_t)G * HDIM * 5 + G) * 4, stream);

    // ---- CSR build ----
    hist_pass<<<NCHUNK, 256, 0, stream>>>(dstI, histG, E, NB);
    scan_chunks<<<NB, 512, 0, stream>>>(histG, tot, NCHUNK, NB);
    scan_tot_k<<<1, 512, 0, stream>>>(tot, bucketBase, rowStart, NB, N, E);
    add_base<<<((NCHUNK * NB) + 255) / 256, 256, 0, stream>>>(histG, bucketBase, NCHUNK * NB, NB);
    scatter_bkt<<<NCHUNK, 256, 0, stream>>>(srcI, dstI, histG, EP, E, NB);
    bucket_csr<<<NB, 512, 0, stream>>>(EP, bucketBase, rowStart, dinv, col, N);

    // ---- W2^T fp16 (once) ----
    prep_w2t<<<(HDIM * HDIM + 255) / 256, 256, 0, stream>>>(W2, W2t);

    // ---- block 1 (rank-7 aggregation) ----
    long long nx8 = (long long)N * 8;
    prep_xs<<<(int)((nx8 + 255) / 256), 256, 0, stream>>>(x, dinv, batch, xs, gcnt, nx8);
    agg7k<<<gridNW, 256, 0, stream>>>(col, rowStart, xs, agg, N);
    l1post<<<gridNW, 512, 0, stream>>>(agg, W1, b1, dinv, batch, A16, gsum1, gsq1, N);
    gstat<<<gridGH, 256, 0, stream>>>(gsum1, gsq1, gcnt, gn1a, G * HDIM);

    // ---- hidden matmul via MFMA, fused layer-1 norm+relu, fp16 in/out ----
    mm_h_mfma<<<gridMM, 256, 0, stream>>>(A16, gsum1, gsq1, gn1a, gn1w, gn1b, batch,
                                          W2t, dinv, Q16, N);

    // ---- block 2 (fp16 gather, 2 half-wave edge streams, deep unroll) ----
    node_agg2<<<gridNW, 256, 0, stream>>>(col, rowStart, Q16, dinv, b2, batch, A2,
                                          gsum2, gsq2, N);
    gstat<<<gridGH, 256, 0, stream>>>(gsum2, gsq2, gcnt, gn2a, G * HDIM);

    // ---- layer-2 norm + relu + pool fused ----
    node_norm_pool<<<gridNW, 256, 0, stream>>>(A2, gsum2, gsq2, gn2a, gn2w, gn2b, batch, gpool, N);

    // ---- head ----
    head<<<G, 128, 0, stream>>>(gpool, gcnt, H1, hb1, H2, hb2, (float*)d_out, G);
}

// Round 9
// 472.401 us; speedup vs baseline: 1.4252x; 1.0663x over previous
//
#include <hip/hip_runtime.h>
#include <hip/hip_fp16.h>

#define EPSV 1e-5f
#define HDIM 128
#define BKT_SHIFT 9
#define BKT_SIZE 512
#define CHK 8192

typedef _Float16 f16x8 __attribute__((ext_vector_type(8)));
typedef float f32x4 __attribute__((ext_vector_type(4)));

// ================= CSR build: bucketed counting sort =================

__global__ __launch_bounds__(256) void hist_pass(const int* __restrict__ dst,
                                                 int* __restrict__ histG, int E, int NB) {
    __shared__ int h[BKT_SIZE];
    int t = threadIdx.x;
    for (int i = t; i < NB; i += 256) h[i] = 0;
    __syncthreads();
    int base = blockIdx.x * CHK;
    int end = min(base + CHK, E);
    for (int e = base + t; e < end; e += 256) atomicAdd(&h[dst[e] >> BKT_SHIFT], 1);
    __syncthreads();
    for (int i = t; i < NB; i += 256) histG[(size_t)blockIdx.x * NB + i] = h[i];
}

__global__ __launch_bounds__(512) void scan_chunks(int* __restrict__ histG,
                                                   int* __restrict__ tot,
                                                   int NCHUNK, int NB) {
    __shared__ int tmp[512];
    int b = blockIdx.x, t = threadIdx.x;
    int v = (t < NCHUNK) ? histG[(size_t)t * NB + b] : 0;
    tmp[t] = v;
    __syncthreads();
    for (int off = 1; off < 512; off <<= 1) {
        int x = (t >= off) ? tmp[t - off] : 0;
        __syncthreads();
        tmp[t] += x;
        __syncthreads();
    }
    if (t < NCHUNK) histG[(size_t)t * NB + b] = tmp[t] - v;
    if (t == 511) tot[b] = tmp[511];
}

__global__ __launch_bounds__(512) void scan_tot_k(const int* __restrict__ tot,
                                                  int* __restrict__ bucketBase,
                                                  int* __restrict__ rowStart,
                                                  int NB, int N, int E) {
    __shared__ int tmp[512];
    int t = threadIdx.x;
    int v = (t < NB) ? tot[t] : 0;
    tmp[t] = v;
    __syncthreads();
    for (int off = 1; off < 512; off <<= 1) {
        int x = (t >= off) ? tmp[t - off] : 0;
        __syncthreads();
        tmp[t] += x;
        __syncthreads();
    }
    if (t < NB) bucketBase[t] = tmp[t] - v;
    if (t == NB - 1) {
        bucketBase[NB] = tmp[t];
        rowStart[N] = E;
    }
}

__global__ __launch_bounds__(256) void add_base(int* __restrict__ histG,
                                                const int* __restrict__ bucketBase,
                                                int total, int NB) {
    int i = blockIdx.x * 256 + threadIdx.x;
    if (i < total) histG[i] += bucketBase[i % NB];
}

__global__ __launch_bounds__(256) void scatter_bkt(const int* __restrict__ src,
                                                   const int* __restrict__ dst,
                                                   const int* __restrict__ chunkOff,
                                                   unsigned int* __restrict__ EP,
                                                   int E, int NB) {
    __shared__ int cur[BKT_SIZE];
    int t = threadIdx.x, c = blockIdx.x;
    for (int i = t; i < NB; i += 256) cur[i] = chunkOff[(size_t)c * NB + i];
    __syncthreads();
    int base = c * CHK, end = min(base + CHK, E);
    for (int e = base + t; e < end; e += 256) {
        int d = dst[e];
        int b = d >> BKT_SHIFT;
        int pos = atomicAdd(&cur[b], 1);
        EP[pos] = (unsigned int)src[e] | ((unsigned int)(d & (BKT_SIZE - 1)) << 23);
    }
}

__global__ __launch_bounds__(512) void bucket_csr(const unsigned int* __restrict__ EP,
                                                  const int* __restrict__ bucketBase,
                                                  int* __restrict__ rowStart,
                                                  float* __restrict__ dinv,
                                                  int* __restrict__ col, int N) {
    __shared__ int cnt[BKT_SIZE];
    __shared__ int tmp[BKT_SIZE];
    int b = blockIdx.x, t = threadIdx.x;
    int ebase = bucketBase[b], eend = bucketBase[b + 1];
    cnt[t] = 0;
    __syncthreads();
    for (int e = ebase + t; e < eend; e += 512)
        atomicAdd(&cnt[(EP[e] >> 23) & 511], 1);
    __syncthreads();
    int v = cnt[t];
    tmp[t] = v;
    __syncthreads();
    for (int off = 1; off < 512; off <<= 1) {
        int x = (t >= off) ? tmp[t - off] : 0;
        __syncthreads();
        tmp[t] += x;
        __syncthreads();
    }
    int excl = tmp[t] - v;
    int n = (b << BKT_SHIFT) + t;
    if (n < N) {
        rowStart[n] = ebase + excl;
        dinv[n] = rsqrtf((float)v + 1.0f);
    }
    __syncthreads();
    cnt[t] = ebase + excl;
    __syncthreads();
    for (int e = ebase + t; e < eend; e += 512) {
        unsigned int p = EP[e];
        int ld = (p >> 23) & 511;
        int pos = atomicAdd(&cnt[ld], 1);
        col[pos] = (int)(p & 0x7FFFFFu);
    }
}

// ---------------- W2^T in fp16 (once) ----------------
__global__ __launch_bounds__(256) void prep_w2t(const float* __restrict__ W2,
                                                __half* __restrict__ W2t) {
    int i = blockIdx.x * 256 + threadIdx.x;
    if (i < HDIM * HDIM) {
        int c = i >> 7, k = i & 127;
        W2t[c * HDIM + k] = __float2half(W2[k * HDIM + c]);
    }
}

// ---------------- xs = dinv * x, padded [N][8]; also per-graph node counts ----------------
__global__ __launch_bounds__(256) void prep_xs(const float* __restrict__ x,
                                               const float* __restrict__ dinv,
                                               const int* __restrict__ batch,
                                               float* __restrict__ xs,
                                               float* __restrict__ gcnt, long long total) {
    long long idx = (long long)blockIdx.x * 256 + threadIdx.x;
    if (idx >= total) return;
    int n = (int)(idx >> 3), k = (int)(idx & 7);
    xs[idx] = (k < 7) ? x[(long long)n * 7 + k] * dinv[n] : 0.f;
    if (k == 7) unsafeAtomicAdd(&gcnt[batch[n]], 1.0f);
}

// ---------------- layer-1 aggregation: wave per node, 4 lanes/edge x 16 streams ----------------
__global__ __launch_bounds__(256) void agg7k(const int* __restrict__ col,
                                             const int* __restrict__ rowStart,
                                             const float* __restrict__ xs,
                                             float* __restrict__ agg, int N) {
    int wib = threadIdx.x >> 6, lane = threadIdx.x & 63;
    int stream = lane >> 2;
    int c2 = (lane & 3) * 2;
    int n = blockIdx.x * 4 + wib;
    if (n >= N) return;
    float2 acc = make_float2(0.f, 0.f);
    int rs = rowStart[n], re = rowStart[n + 1];
    if (stream == 0) acc = *(const float2*)(xs + (size_t)n * 8 + c2);
    int j = rs + stream;
    for (; j + 16 < re; j += 32) {
        int e0 = col[j], e1 = col[j + 16];
        float2 r0 = *(const float2*)(xs + (size_t)e0 * 8 + c2);
        float2 r1 = *(const float2*)(xs + (size_t)e1 * 8 + c2);
        acc.x += r0.x + r1.x;
        acc.y += r0.y + r1.y;
    }
    for (; j < re; j += 16) {
        float2 r = *(const float2*)(xs + (size_t)col[j] * 8 + c2);
        acc.x += r.x; acc.y += r.y;
    }
#pragma unroll
    for (int off = 4; off <= 32; off <<= 1) {
        acc.x += __shfl_xor(acc.x, off);
        acc.y += __shfl_xor(acc.y, off);
    }
    if (stream == 0) *(float2*)(agg + (size_t)n * 8 + c2) = acc;
}

// ---------------- layer-1 post: A16 = half(dinv*(agg@W1)+b1) (no stats) ----------------
__global__ __launch_bounds__(512) void l1post(const float* __restrict__ agg,
                                              const float* __restrict__ W1,
                                              const float* __restrict__ b1,
                                              const float* __restrict__ dinv,
                                              __half* __restrict__ A16, int N) {
    __shared__ float w1s[7 * HDIM];
    int t = threadIdx.x;
    for (int i = t; i < 7 * HDIM; i += 512) w1s[i] = W1[i];
    int wib = t >> 7, c = t & 127;
    int n = blockIdx.x * 4 + wib;
    __syncthreads();
    if (n < N) {
        const float* ar = agg + (size_t)n * 8;
        float s = 0.f;
#pragma unroll
        for (int k = 0; k < 7; k++) s += ar[k] * w1s[k * HDIM + c];
        A16[(size_t)n * HDIM + c] = __float2half(s * dinv[n] + b1[c]);
    }
}

// ---------------- coalesced GraphNorm stats over fp16 matrix, batch-run flush ----------------
__global__ __launch_bounds__(256) void stats2(const __half* __restrict__ X,
                                              const int* __restrict__ batch,
                                              float* __restrict__ gsum,
                                              float* __restrict__ gsq, int N) {
    int t = threadIdx.x;
    int c = t & 127;
    int half_ = t >> 7;
    int n0 = blockIdx.x * 32;
    float s = 0.f, q = 0.f;
    int cur = -1;
    for (int i = half_; i < 32; i += 2) {
        int n = n0 + i;
        if (n >= N) break;
        int b = batch[n];
        if (b != cur) {
            if (cur >= 0) {
                unsafeAtomicAdd(&gsum[(size_t)cur * HDIM + c], s);
                unsafeAtomicAdd(&gsq[(size_t)cur * HDIM + c], q);
            }
            cur = b; s = 0.f; q = 0.f;
        }
        float v = __half2float(X[(size_t)n * HDIM + c]);
        s += v; q += v * v;
    }
    if (cur >= 0) {
        unsafeAtomicAdd(&gsum[(size_t)cur * HDIM + c], s);
        unsafeAtomicAdd(&gsq[(size_t)cur * HDIM + c], q);
    }
}

// ---------------- per-(graph,channel): sums -> mean, inv-std ----------------
__global__ __launch_bounds__(256) void gstat(float* __restrict__ gsum,
                                             float* __restrict__ gsq,
                                             const float* __restrict__ gcnt,
                                             const float* __restrict__ alpha, int total) {
    int i = blockIdx.x * 256 + threadIdx.x;
    if (i < total) {
        int g = i >> 7, c = i & 127;
        float cnt = fmaxf(gcnt[g], 1.f);
        float mean = gsum[i] / cnt;
        float m2 = gsq[i] / cnt;
        float a = alpha[c];
        float var = m2 + mean * mean * (a * a - 2.f * a);
        gsum[i] = mean;
        gsq[i] = rsqrtf(fmaxf(var, 0.f) + EPSV);
    }
}

// ---------------- hidden matmul via MFMA: Q = half(dinv * (relu(norm(A16)) @ W2)) ----------------
__global__ __launch_bounds__(256) void mm_h_mfma(const __half* __restrict__ A16,
                                                 const float* __restrict__ gmean,
                                                 const float* __restrict__ gistd,
                                                 const float* __restrict__ alpha,
                                                 const float* __restrict__ w,
                                                 const float* __restrict__ bb,
                                                 const int* __restrict__ batch,
                                                 const __half* __restrict__ W2t,
                                                 const float* __restrict__ dinv,
                                                 __half* __restrict__ Q, int N) {
    __shared__ _Float16 XS[64][136];
    __shared__ _Float16 WT[HDIM][136];
    __shared__ float pA[HDIM], pW[HDIM], pB[HDIM];
    int t = threadIdx.x;
    for (int i = t; i < HDIM; i += 256) { pA[i] = alpha[i]; pW[i] = w[i]; pB[i] = bb[i]; }
    int n0 = blockIdx.x * 64;

    for (int i = t; i < HDIM * 16; i += 256) {
        int row = i >> 4;
        int kk = (i & 15) * 8;
        *(uint4*)&WT[row][kk] = *(const uint4*)(W2t + (size_t)row * HDIM + kk);
    }
    __syncthreads();

    for (int i = t; i < 64 * 16; i += 256) {
        int nn = i >> 4;
        int kk = (i & 15) * 8;
        int gn = n0 + nn;
        __half hv[8];
#pragma unroll
        for (int k = 0; k < 8; k++) hv[k] = __float2half(0.f);
        if (gn < N) {
            uint4 u = *(const uint4*)(A16 + (size_t)gn * HDIM + kk);
            int b = batch[gn];
            const float* mp = gmean + (size_t)b * HDIM + kk;
            const float* ip = gistd + (size_t)b * HDIM + kk;
            float2 f0 = __half22float2(*(__half2*)&u.x);
            float2 f1 = __half22float2(*(__half2*)&u.y);
            float2 f2 = __half22float2(*(__half2*)&u.z);
            float2 f3 = __half22float2(*(__half2*)&u.w);
            float f[8] = {f0.x, f0.y, f1.x, f1.y, f2.x, f2.y, f3.x, f3.y};
#pragma unroll
            for (int k = 0; k < 8; k++) {
                int c = kk + k;
                hv[k] = __float2half(fmaxf(pW[c] * (f[k] - pA[c] * mp[k]) * ip[k] + pB[c], 0.f));
            }
        }
        *(uint4*)&XS[nn][kk] = *(uint4*)hv;
    }
    __syncthreads();

    int wid = t >> 6, lane = t & 63;
    int m0 = wid * 16;
    int rlane = lane & 15;
    int kgrp = lane >> 4;
    f32x4 acc[8];
#pragma unroll
    for (int ct = 0; ct < 8; ct++) acc[ct] = (f32x4){0.f, 0.f, 0.f, 0.f};

#pragma unroll
    for (int kt = 0; kt < 4; ++kt) {
        int kbase = kt * 32 + kgrp * 8;
        f16x8 a = *(const f16x8*)&XS[m0 + rlane][kbase];
#pragma unroll
        for (int ct = 0; ct < 8; ++ct) {
            f16x8 bfr = *(const f16x8*)&WT[ct * 16 + rlane][kbase];
            acc[ct] = __builtin_amdgcn_mfma_f32_16x16x32_f16(a, bfr, acc[ct], 0, 0, 0);
        }
    }

    int rgrp = lane >> 4;
    float dv[4];
    int gnr[4];
#pragma unroll
    for (int r = 0; r < 4; r++) {
        gnr[r] = n0 + m0 + rgrp * 4 + r;
        dv[r] = (gnr[r] < N) ? dinv[gnr[r]] : 0.f;
    }
#pragma unroll
    for (int ct = 0; ct < 8; ++ct) {
#pragma unroll
        for (int r = 0; r < 4; ++r) {
            if (gnr[r] < N)
                Q[(size_t)gnr[r] * HDIM + ct * 16 + rlane] = __float2half(acc[ct][r] * dv[r]);
        }
    }
}

// ---------------- fp16 row load: 4 channels (8B) ----------------
__device__ __forceinline__ float4 qrow4(const __half* __restrict__ Q, int e, int c4) {
    uint2 u = *(const uint2*)(Q + (size_t)e * HDIM + c4);
    float2 f0 = __half22float2(*(__half2*)&u.x);
    float2 f1 = __half22float2(*(__half2*)&u.y);
    return make_float4(f0.x, f0.y, f1.x, f1.y);
}

// ---------------- layer-2 CSR gather: PURE (no stats/LDS/barrier) ----------------
__global__ __launch_bounds__(256) void node_agg2(const int* __restrict__ col,
                                                 const int* __restrict__ rowStart,
                                                 const __half* __restrict__ Q,
                                                 const float* __restrict__ dinv,
                                                 const float* __restrict__ bias,
                                                 __half* __restrict__ A2, int N) {
    int wib = threadIdx.x >> 6;
    int lane = threadIdx.x & 63;
    int half = lane >> 5;
    int l = lane & 31;
    int c4 = l * 4;
    int n = blockIdx.x * 4 + wib;
    if (n >= N) return;
    float4 acc = make_float4(0.f, 0.f, 0.f, 0.f);
    int rs = rowStart[n], re = rowStart[n + 1];
    if (half == 0) acc = qrow4(Q, n, c4);          // self term
    int j = rs + half;
    for (; j + 14 < re; j += 16) {
        int e0 = col[j],      e1 = col[j + 2],  e2 = col[j + 4],  e3 = col[j + 6];
        int e4 = col[j + 8],  e5 = col[j + 10], e6 = col[j + 12], e7 = col[j + 14];
        float4 r0 = qrow4(Q, e0, c4);
        float4 r1 = qrow4(Q, e1, c4);
        float4 r2 = qrow4(Q, e2, c4);
        float4 r3 = qrow4(Q, e3, c4);
        float4 r4 = qrow4(Q, e4, c4);
        float4 r5 = qrow4(Q, e5, c4);
        float4 r6 = qrow4(Q, e6, c4);
        float4 r7 = qrow4(Q, e7, c4);
        acc.x += ((r0.x + r1.x) + (r2.x + r3.x)) + ((r4.x + r5.x) + (r6.x + r7.x));
        acc.y += ((r0.y + r1.y) + (r2.y + r3.y)) + ((r4.y + r5.y) + (r6.y + r7.y));
        acc.z += ((r0.z + r1.z) + (r2.z + r3.z)) + ((r4.z + r5.z) + (r6.z + r7.z));
        acc.w += ((r0.w + r1.w) + (r2.w + r3.w)) + ((r4.w + r5.w) + (r6.w + r7.w));
    }
    for (; j + 6 < re; j += 8) {
        int e0 = col[j], e1 = col[j + 2], e2 = col[j + 4], e3 = col[j + 6];
        float4 r0 = qrow4(Q, e0, c4);
        float4 r1 = qrow4(Q, e1, c4);
        float4 r2 = qrow4(Q, e2, c4);
        float4 r3 = qrow4(Q, e3, c4);
        acc.x += (r0.x + r1.x) + (r2.x + r3.x);
        acc.y += (r0.y + r1.y) + (r2.y + r3.y);
        acc.z += (r0.z + r1.z) + (r2.z + r3.z);
        acc.w += (r0.w + r1.w) + (r2.w + r3.w);
    }
    for (; j < re; j += 2) {
        float4 r = qrow4(Q, col[j], c4);
        acc.x += r.x; acc.y += r.y; acc.z += r.z; acc.w += r.w;
    }
    acc.x += __shfl_xor(acc.x, 32);
    acc.y += __shfl_xor(acc.y, 32);
    acc.z += __shfl_xor(acc.z, 32);
    acc.w += __shfl_xor(acc.w, 32);
    if (half == 0) {
        float dv = dinv[n];
        acc.x = acc.x * dv + bias[c4];
        acc.y = acc.y * dv + bias[c4 + 1];
        acc.z = acc.z * dv + bias[c4 + 2];
        acc.w = acc.w * dv + bias[c4 + 3];
        __half2 o0 = __floats2half2_rn(acc.x, acc.y);
        __half2 o1 = __floats2half2_rn(acc.z, acc.w);
        uint2 u;
        u.x = *(unsigned int*)&o0;
        u.y = *(unsigned int*)&o1;
        *(uint2*)(A2 + (size_t)n * HDIM + c4) = u;
    }
}

// ---------------- layer-2 norm+relu+pool: coalesced, batch-run flush ----------------
__global__ __launch_bounds__(256) void node_norm_pool(const __half* __restrict__ A2,
                                                      const float* __restrict__ gmean,
                                                      const float* __restrict__ gistd,
                                                      const float* __restrict__ alpha,
                                                      const float* __restrict__ w,
                                                      const float* __restrict__ bb,
                                                      const int* __restrict__ batch,
                                                      float* __restrict__ gpool, int N) {
    int t = threadIdx.x;
    int c = t & 127;
    int half_ = t >> 7;
    int n0 = blockIdx.x * 32;
    float ac = alpha[c], wc = w[c], bc = bb[c];
    float s = 0.f, mc = 0.f, ic = 0.f;
    int cur = -1;
    for (int i = half_; i < 32; i += 2) {
        int n = n0 + i;
        if (n >= N) break;
        int b = batch[n];
        if (b != cur) {
            if (cur >= 0) unsafeAtomicAdd(&gpool[(size_t)cur * HDIM + c], s);
            cur = b; s = 0.f;
            mc = gmean[(size_t)b * HDIM + c];
            ic = gistd[(size_t)b * HDIM + c];
        }
        float v = __half2float(A2[(size_t)n * HDIM + c]);
        s += fmaxf(wc * (v - ac * mc) * ic + bc, 0.f);
    }
    if (cur >= 0) unsafeAtomicAdd(&gpool[(size_t)cur * HDIM + c], s);
}

// ---------------- head ----------------
__global__ __launch_bounds__(128) void head(const float* __restrict__ gpool,
                                            const float* __restrict__ gcnt,
                                            const float* __restrict__ H1,
                                            const float* __restrict__ hb1,
                                            const float* __restrict__ H2,
                                            const float* __restrict__ hb2,
                                            float* __restrict__ out, int G) {
    __shared__ float gv[HDIM];
    __shared__ float tv[HDIM];
    __shared__ float r0[HDIM], r1[HDIM];
    int g = blockIdx.x;
    int c = threadIdx.x;
    float cnt = fmaxf(gcnt[g], 1.0f);
    gv[c] = gpool[(long long)g * HDIM + c] / cnt;
    __syncthreads();
    float s = hb1[c];
    for (int k = 0; k < HDIM; k++) s += gv[k] * H1[k * HDIM + c];
    tv[c] = fmaxf(s, 0.f);
    __syncthreads();
    r0[c] = tv[c] * H2[c * 2 + 0];
    r1[c] = tv[c] * H2[c * 2 + 1];
    __syncthreads();
    for (int off = 64; off > 0; off >>= 1) {
        if (c < off) { r0[c] += r0[c + off]; r1[c] += r1[c + off]; }
        __syncthreads();
    }
    if (c == 0) {
        out[(long long)g * 2 + 0] = r0[0] + hb2[0];
        out[(long long)g * 2 + 1] = r1[0] + hb2[1];
    }
}

extern "C" void kernel_launch(void* const* d_in, const int* in_sizes, int n_in,
                              void* d_out, int out_size, void* d_ws, size_t ws_size,
                              hipStream_t stream) {
    const float* x    = (const float*)d_in[0];
    const int*   ei   = (const int*)d_in[1];
    const int*   batch= (const int*)d_in[2];
    const float* W1   = (const float*)d_in[4];
    const float* b1   = (const float*)d_in[5];
    const float* gn1w = (const float*)d_in[6];
    const float* gn1b = (const float*)d_in[7];
    const float* gn1a = (const float*)d_in[8];
    const float* W2   = (const float*)d_in[9];
    const float* b2   = (const float*)d_in[10];
    const float* gn2w = (const float*)d_in[11];
    const float* gn2b = (const float*)d_in[12];
    const float* gn2a = (const float*)d_in[13];
    const float* H1   = (const float*)d_in[14];
    const float* hb1  = (const float*)d_in[15];
    const float* H2   = (const float*)d_in[16];
    const float* hb2  = (const float*)d_in[17];

    int N = in_sizes[0] / 7;
    int E = in_sizes[1] / 2;
    int G = out_size / 2;
    const int* srcI = ei;
    const int* dstI = ei + E;

    int NB = (N + BKT_SIZE - 1) >> BKT_SHIFT;
    int NCHUNK = (E + CHK - 1) / CHK;

    // workspace layout
    __half* A16   = (__half*)d_ws;                   // N*128 half (layer1 pre-norm)
    __half* A2    = A16;                             // alias (layer2 pre-norm; A16 dead by then)
    __half* Q16   = A16 + (size_t)N * HDIM;          // N*128 half
    float*  xs    = (float*)(Q16 + (size_t)N * HDIM);// N*8
    float*  agg   = xs + (size_t)N * 8;              // N*8
    float*  gsum1 = agg + (size_t)N * 8;             // G*128
    float*  gsq1  = gsum1 + (size_t)G * HDIM;        // G*128
    float*  gsum2 = gsq1 + (size_t)G * HDIM;         // G*128
    float*  gsq2  = gsum2 + (size_t)G * HDIM;        // G*128
    float*  gpool = gsq2 + (size_t)G * HDIM;         // G*128
    float*  gcnt  = gpool + (size_t)G * HDIM;        // G
    float*  dinv  = gcnt + G;                        // N
    int* rowStart = (int*)(dinv + N);                // N+2
    unsigned int* EP = (unsigned int*)(rowStart + N + 2); // E
    int* col      = (int*)(EP + E);                  // E
    int* histG    = col + E;                         // NCHUNK*NB
    int* tot      = histG + (size_t)NCHUNK * NB;     // NB+2
    int* bucketBase = tot + NB + 2;                  // NB+2
    __half* W2t   = (__half*)(bucketBase + NB + 2);  // 128*128 half

    int gridNW = (N + 3) / 4;
    int gridGH = (G * HDIM + 255) / 256;
    int gridMM = (N + 63) / 64;
    int gridNS = (N + 31) / 32;

    // single upfront memset: gsum1,gsq1,gsum2,gsq2,gpool,gcnt
    hipMemsetAsync(gsum1, 0, ((size_t)G * HDIM * 5 + G) * 4, stream);

    // ---- CSR build ----
    hist_pass<<<NCHUNK, 256, 0, stream>>>(dstI, histG, E, NB);
    scan_chunks<<<NB, 512, 0, stream>>>(histG, tot, NCHUNK, NB);
    scan_tot_k<<<1, 512, 0, stream>>>(tot, bucketBase, rowStart, NB, N, E);
    add_base<<<((NCHUNK * NB) + 255) / 256, 256, 0, stream>>>(histG, bucketBase, NCHUNK * NB, NB);
    scatter_bkt<<<NCHUNK, 256, 0, stream>>>(srcI, dstI, histG, EP, E, NB);
    bucket_csr<<<NB, 512, 0, stream>>>(EP, bucketBase, rowStart, dinv, col, N);

    // ---- W2^T fp16 (once) ----
    prep_w2t<<<(HDIM * HDIM + 255) / 256, 256, 0, stream>>>(W2, W2t);

    // ---- block 1 (rank-7 aggregation) ----
    long long nx8 = (long long)N * 8;
    prep_xs<<<(int)((nx8 + 255) / 256), 256, 0, stream>>>(x, dinv, batch, xs, gcnt, nx8);
    agg7k<<<gridNW, 256, 0, stream>>>(col, rowStart, xs, agg, N);
    l1post<<<gridNW, 512, 0, stream>>>(agg, W1, b1, dinv, A16, N);
    stats2<<<gridNS, 256, 0, stream>>>(A16, batch, gsum1, gsq1, N);
    gstat<<<gridGH, 256, 0, stream>>>(gsum1, gsq1, gcnt, gn1a, G * HDIM);

    // ---- hidden matmul via MFMA, fused layer-1 norm+relu, fp16 in/out ----
    mm_h_mfma<<<gridMM, 256, 0, stream>>>(A16, gsum1, gsq1, gn1a, gn1w, gn1b, batch,
                                          W2t, dinv, Q16, N);

    // ---- block 2 (pure fp16 gather) ----
    node_agg2<<<gridNW, 256, 0, stream>>>(col, rowStart, Q16, dinv, b2, A2, N);
    stats2<<<gridNS, 256, 0, stream>>>(A2, batch, gsum2, gsq2, N);
    gstat<<<gridGH, 256, 0, stream>>>(gsum2, gsq2, gcnt, gn2a, G * HDIM);

    // ---- layer-2 norm + relu + pool ----
    node_norm_pool<<<gridNS, 256, 0, stream>>>(A2, gsum2, gsq2, gn2a, gn2w, gn2b, batch, gpool, N);

    // ---- head ----
    head<<<G, 128, 0, stream>>>(gpool, gcnt, H1, hb1, H2, hb2, (float*)d_out, G);
}

// Round 10
// 373.731 us; speedup vs baseline: 1.8015x; 1.2640x over previous
//
#include <hip/hip_runtime.h>
#include <hip/hip_fp16.h>

#define EPSV 1e-5f
#define HDIM 128
#define BKT_SHIFT 9
#define BKT_SIZE 512
#define CHK 8192

typedef _Float16 f16x8 __attribute__((ext_vector_type(8)));
typedef float f32x4 __attribute__((ext_vector_type(4)));

// ================= CSR build: bucketed counting sort =================

__global__ __launch_bounds__(256) void hist_pass(const int* __restrict__ dst,
                                                 int* __restrict__ histG, int E, int NB) {
    __shared__ int h[BKT_SIZE];
    int t = threadIdx.x;
    for (int i = t; i < NB; i += 256) h[i] = 0;
    __syncthreads();
    int base = blockIdx.x * CHK;
    int end = min(base + CHK, E);
    for (int e = base + t; e < end; e += 256) atomicAdd(&h[dst[e] >> BKT_SHIFT], 1);
    __syncthreads();
    for (int i = t; i < NB; i += 256) histG[(size_t)blockIdx.x * NB + i] = h[i];
}

__global__ __launch_bounds__(512) void scan_chunks(int* __restrict__ histG,
                                                   int* __restrict__ tot,
                                                   int NCHUNK, int NB) {
    __shared__ int tmp[512];
    int b = blockIdx.x, t = threadIdx.x;
    int v = (t < NCHUNK) ? histG[(size_t)t * NB + b] : 0;
    tmp[t] = v;
    __syncthreads();
    for (int off = 1; off < 512; off <<= 1) {
        int x = (t >= off) ? tmp[t - off] : 0;
        __syncthreads();
        tmp[t] += x;
        __syncthreads();
    }
    if (t < NCHUNK) histG[(size_t)t * NB + b] = tmp[t] - v;
    if (t == 511) tot[b] = tmp[511];
}

__global__ __launch_bounds__(512) void scan_tot_k(const int* __restrict__ tot,
                                                  int* __restrict__ bucketBase,
                                                  int* __restrict__ rowStart,
                                                  int NB, int N, int E) {
    __shared__ int tmp[512];
    int t = threadIdx.x;
    int v = (t < NB) ? tot[t] : 0;
    tmp[t] = v;
    __syncthreads();
    for (int off = 1; off < 512; off <<= 1) {
        int x = (t >= off) ? tmp[t - off] : 0;
        __syncthreads();
        tmp[t] += x;
        __syncthreads();
    }
    if (t < NB) bucketBase[t] = tmp[t] - v;
    if (t == NB - 1) {
        bucketBase[NB] = tmp[t];
        rowStart[N] = E;
    }
}

__global__ __launch_bounds__(256) void add_base(int* __restrict__ histG,
                                                const int* __restrict__ bucketBase,
                                                int total, int NB) {
    int i = blockIdx.x * 256 + threadIdx.x;
    if (i < total) histG[i] += bucketBase[i % NB];
}

__global__ __launch_bounds__(256) void scatter_bkt(const int* __restrict__ src,
                                                   const int* __restrict__ dst,
                                                   const int* __restrict__ chunkOff,
                                                   unsigned int* __restrict__ EP,
                                                   int E, int NB) {
    __shared__ int cur[BKT_SIZE];
    int t = threadIdx.x, c = blockIdx.x;
    for (int i = t; i < NB; i += 256) cur[i] = chunkOff[(size_t)c * NB + i];
    __syncthreads();
    int base = c * CHK, end = min(base + CHK, E);
    for (int e = base + t; e < end; e += 256) {
        int d = dst[e];
        int b = d >> BKT_SHIFT;
        int pos = atomicAdd(&cur[b], 1);
        EP[pos] = (unsigned int)src[e] | ((unsigned int)(d & (BKT_SIZE - 1)) << 23);
    }
}

__global__ __launch_bounds__(512) void bucket_csr(const unsigned int* __restrict__ EP,
                                                  const int* __restrict__ bucketBase,
                                                  int* __restrict__ rowStart,
                                                  float* __restrict__ dinv,
                                                  int* __restrict__ col, int N) {
    __shared__ int cnt[BKT_SIZE];
    __shared__ int tmp[BKT_SIZE];
    int b = blockIdx.x, t = threadIdx.x;
    int ebase = bucketBase[b], eend = bucketBase[b + 1];
    cnt[t] = 0;
    __syncthreads();
    for (int e = ebase + t; e < eend; e += 512)
        atomicAdd(&cnt[(EP[e] >> 23) & 511], 1);
    __syncthreads();
    int v = cnt[t];
    tmp[t] = v;
    __syncthreads();
    for (int off = 1; off < 512; off <<= 1) {
        int x = (t >= off) ? tmp[t - off] : 0;
        __syncthreads();
        tmp[t] += x;
        __syncthreads();
    }
    int excl = tmp[t] - v;
    int n = (b << BKT_SHIFT) + t;
    if (n < N) {
        rowStart[n] = ebase + excl;
        dinv[n] = rsqrtf((float)v + 1.0f);
    }
    __syncthreads();
    cnt[t] = ebase + excl;
    __syncthreads();
    for (int e = ebase + t; e < eend; e += 512) {
        unsigned int p = EP[e];
        int ld = (p >> 23) & 511;
        int pos = atomicAdd(&cnt[ld], 1);
        col[pos] = (int)(p & 0x7FFFFFu);
    }
}

// ---------------- per-graph node counts via binary search (batch is sorted) ----------------
__device__ __forceinline__ int lbound(const int* __restrict__ b, int N, int key) {
    int lo = 0, hi = N;
    while (lo < hi) {
        int mid = (lo + hi) >> 1;
        if (b[mid] < key) lo = mid + 1; else hi = mid;
    }
    return lo;
}

__global__ __launch_bounds__(256) void graph_counts(const int* __restrict__ batch,
                                                    float* __restrict__ gcnt, int N, int G) {
    int g = blockIdx.x * 256 + threadIdx.x;
    if (g < G)
        gcnt[g] = (float)(lbound(batch, N, g + 1) - lbound(batch, N, g));
}

// ---------------- W2^T in fp16 (once) ----------------
__global__ __launch_bounds__(256) void prep_w2t(const float* __restrict__ W2,
                                                __half* __restrict__ W2t) {
    int i = blockIdx.x * 256 + threadIdx.x;
    if (i < HDIM * HDIM) {
        int c = i >> 7, k = i & 127;
        W2t[c * HDIM + k] = __float2half(W2[k * HDIM + c]);
    }
}

// ---------------- xs = dinv * x, padded [N][8] (pure elementwise) ----------------
__global__ __launch_bounds__(256) void prep_xs(const float* __restrict__ x,
                                               const float* __restrict__ dinv,
                                               float* __restrict__ xs, long long total) {
    long long idx = (long long)blockIdx.x * 256 + threadIdx.x;
    if (idx >= total) return;
    int n = (int)(idx >> 3), k = (int)(idx & 7);
    xs[idx] = (k < 7) ? x[(long long)n * 7 + k] * dinv[n] : 0.f;
}

// ---------------- layer-1 aggregation: wave per node, 4 lanes/edge x 16 streams ----------------
__global__ __launch_bounds__(256) void agg7k(const int* __restrict__ col,
                                             const int* __restrict__ rowStart,
                                             const float* __restrict__ xs,
                                             float* __restrict__ agg, int N) {
    int wib = threadIdx.x >> 6, lane = threadIdx.x & 63;
    int stream = lane >> 2;
    int c2 = (lane & 3) * 2;
    int n = blockIdx.x * 4 + wib;
    if (n >= N) return;
    float2 acc = make_float2(0.f, 0.f);
    int rs = rowStart[n], re = rowStart[n + 1];
    if (stream == 0) acc = *(const float2*)(xs + (size_t)n * 8 + c2);
    int j = rs + stream;
    for (; j + 16 < re; j += 32) {
        int e0 = col[j], e1 = col[j + 16];
        float2 r0 = *(const float2*)(xs + (size_t)e0 * 8 + c2);
        float2 r1 = *(const float2*)(xs + (size_t)e1 * 8 + c2);
        acc.x += r0.x + r1.x;
        acc.y += r0.y + r1.y;
    }
    for (; j < re; j += 16) {
        float2 r = *(const float2*)(xs + (size_t)col[j] * 8 + c2);
        acc.x += r.x; acc.y += r.y;
    }
#pragma unroll
    for (int off = 4; off <= 32; off <<= 1) {
        acc.x += __shfl_xor(acc.x, off);
        acc.y += __shfl_xor(acc.y, off);
    }
    if (stream == 0) *(float2*)(agg + (size_t)n * 8 + c2) = acc;
}

// ---------------- layer-1 post: A16 = half(dinv*(agg@W1)+b1) ----------------
__global__ __launch_bounds__(512) void l1post(const float* __restrict__ agg,
                                              const float* __restrict__ W1,
                                              const float* __restrict__ b1,
                                              const float* __restrict__ dinv,
                                              __half* __restrict__ A16, int N) {
    __shared__ float w1s[7 * HDIM];
    int t = threadIdx.x;
    for (int i = t; i < 7 * HDIM; i += 512) w1s[i] = W1[i];
    int wib = t >> 7, c = t & 127;
    int n = blockIdx.x * 4 + wib;
    __syncthreads();
    if (n < N) {
        const float* ar = agg + (size_t)n * 8;
        float s = 0.f;
#pragma unroll
        for (int k = 0; k < 7; k++) s += ar[k] * w1s[k * HDIM + c];
        A16[(size_t)n * HDIM + c] = __float2half(s * dinv[n] + b1[c]);
    }
}

// ---------------- coalesced GraphNorm stats over fp16 matrix, batch-run flush ----------------
__global__ __launch_bounds__(256) void stats2(const __half* __restrict__ X,
                                              const int* __restrict__ batch,
                                              float* __restrict__ gsum,
                                              float* __restrict__ gsq, int N) {
    int t = threadIdx.x;
    int c = t & 127;
    int half_ = t >> 7;
    int n0 = blockIdx.x * 32;
    float s = 0.f, q = 0.f;
    int cur = -1;
    for (int i = half_; i < 32; i += 2) {
        int n = n0 + i;
        if (n >= N) break;
        int b = batch[n];
        if (b != cur) {
            if (cur >= 0) {
                unsafeAtomicAdd(&gsum[(size_t)cur * HDIM + c], s);
                unsafeAtomicAdd(&gsq[(size_t)cur * HDIM + c], q);
            }
            cur = b; s = 0.f; q = 0.f;
        }
        float v = __half2float(X[(size_t)n * HDIM + c]);
        s += v; q += v * v;
    }
    if (cur >= 0) {
        unsafeAtomicAdd(&gsum[(size_t)cur * HDIM + c], s);
        unsafeAtomicAdd(&gsq[(size_t)cur * HDIM + c], q);
    }
}

// ---------------- per-(graph,channel): sums -> mean, inv-std ----------------
__global__ __launch_bounds__(256) void gstat(float* __restrict__ gsum,
                                             float* __restrict__ gsq,
                                             const float* __restrict__ gcnt,
                                             const float* __restrict__ alpha, int total) {
    int i = blockIdx.x * 256 + threadIdx.x;
    if (i < total) {
        int g = i >> 7, c = i & 127;
        float cnt = fmaxf(gcnt[g], 1.f);
        float mean = gsum[i] / cnt;
        float m2 = gsq[i] / cnt;
        float a = alpha[c];
        float var = m2 + mean * mean * (a * a - 2.f * a);
        gsum[i] = mean;
        gsq[i] = rsqrtf(fmaxf(var, 0.f) + EPSV);
    }
}

// ---------------- hidden matmul via MFMA: Q = half(dinv * (relu(norm(A16)) @ W2)) ----------------
__global__ __launch_bounds__(256) void mm_h_mfma(const __half* __restrict__ A16,
                                                 const float* __restrict__ gmean,
                                                 const float* __restrict__ gistd,
                                                 const float* __restrict__ alpha,
                                                 const float* __restrict__ w,
                                                 const float* __restrict__ bb,
                                                 const int* __restrict__ batch,
                                                 const __half* __restrict__ W2t,
                                                 const float* __restrict__ dinv,
                                                 __half* __restrict__ Q, int N) {
    __shared__ _Float16 XS[64][136];
    __shared__ _Float16 WT[HDIM][136];
    __shared__ float pA[HDIM], pW[HDIM], pB[HDIM];
    int t = threadIdx.x;
    for (int i = t; i < HDIM; i += 256) { pA[i] = alpha[i]; pW[i] = w[i]; pB[i] = bb[i]; }
    int n0 = blockIdx.x * 64;

    for (int i = t; i < HDIM * 16; i += 256) {
        int row = i >> 4;
        int kk = (i & 15) * 8;
        *(uint4*)&WT[row][kk] = *(const uint4*)(W2t + (size_t)row * HDIM + kk);
    }
    __syncthreads();

    for (int i = t; i < 64 * 16; i += 256) {
        int nn = i >> 4;
        int kk = (i & 15) * 8;
        int gn = n0 + nn;
        __half hv[8];
#pragma unroll
        for (int k = 0; k < 8; k++) hv[k] = __float2half(0.f);
        if (gn < N) {
            uint4 u = *(const uint4*)(A16 + (size_t)gn * HDIM + kk);
            int b = batch[gn];
            const float* mp = gmean + (size_t)b * HDIM + kk;
            const float* ip = gistd + (size_t)b * HDIM + kk;
            float2 f0 = __half22float2(*(__half2*)&u.x);
            float2 f1 = __half22float2(*(__half2*)&u.y);
            float2 f2 = __half22float2(*(__half2*)&u.z);
            float2 f3 = __half22float2(*(__half2*)&u.w);
            float f[8] = {f0.x, f0.y, f1.x, f1.y, f2.x, f2.y, f3.x, f3.y};
#pragma unroll
            for (int k = 0; k < 8; k++) {
                int c = kk + k;
                hv[k] = __float2half(fmaxf(pW[c] * (f[k] - pA[c] * mp[k]) * ip[k] + pB[c], 0.f));
            }
        }
        *(uint4*)&XS[nn][kk] = *(uint4*)hv;
    }
    __syncthreads();

    int wid = t >> 6, lane = t & 63;
    int m0 = wid * 16;
    int rlane = lane & 15;
    int kgrp = lane >> 4;
    f32x4 acc[8];
#pragma unroll
    for (int ct = 0; ct < 8; ct++) acc[ct] = (f32x4){0.f, 0.f, 0.f, 0.f};

#pragma unroll
    for (int kt = 0; kt < 4; ++kt) {
        int kbase = kt * 32 + kgrp * 8;
        f16x8 a = *(const f16x8*)&XS[m0 + rlane][kbase];
#pragma unroll
        for (int ct = 0; ct < 8; ++ct) {
            f16x8 bfr = *(const f16x8*)&WT[ct * 16 + rlane][kbase];
            acc[ct] = __builtin_amdgcn_mfma_f32_16x16x32_f16(a, bfr, acc[ct], 0, 0, 0);
        }
    }

    int rgrp = lane >> 4;
    float dv[4];
    int gnr[4];
#pragma unroll
    for (int r = 0; r < 4; r++) {
        gnr[r] = n0 + m0 + rgrp * 4 + r;
        dv[r] = (gnr[r] < N) ? dinv[gnr[r]] : 0.f;
    }
#pragma unroll
    for (int ct = 0; ct < 8; ++ct) {
#pragma unroll
        for (int r = 0; r < 4; ++r) {
            if (gnr[r] < N)
                Q[(size_t)gnr[r] * HDIM + ct * 16 + rlane] = __float2half(acc[ct][r] * dv[r]);
        }
    }
}

// ---------------- fp16 row load: 4 channels (8B) ----------------
__device__ __forceinline__ float4 qrow4(const __half* __restrict__ Q, int e, int c4) {
    uint2 u = *(const uint2*)(Q + (size_t)e * HDIM + c4);
    float2 f0 = __half22float2(*(__half2*)&u.x);
    float2 f1 = __half22float2(*(__half2*)&u.y);
    return make_float4(f0.x, f0.y, f1.x, f1.y);
}

// ---------------- layer-2 CSR gather: PURE (no stats/LDS/barrier) ----------------
__global__ __launch_bounds__(256) void node_agg2(const int* __restrict__ col,
                                                 const int* __restrict__ rowStart,
                                                 const __half* __restrict__ Q,
                                                 const float* __restrict__ dinv,
                                                 const float* __restrict__ bias,
                                                 __half* __restrict__ A2, int N) {
    int wib = threadIdx.x >> 6;
    int lane = threadIdx.x & 63;
    int half = lane >> 5;
    int l = lane & 31;
    int c4 = l * 4;
    int n = blockIdx.x * 4 + wib;
    if (n >= N) return;
    float4 acc = make_float4(0.f, 0.f, 0.f, 0.f);
    int rs = rowStart[n], re = rowStart[n + 1];
    if (half == 0) acc = qrow4(Q, n, c4);          // self term
    int j = rs + half;
    for (; j + 14 < re; j += 16) {
        int e0 = col[j],      e1 = col[j + 2],  e2 = col[j + 4],  e3 = col[j + 6];
        int e4 = col[j + 8],  e5 = col[j + 10], e6 = col[j + 12], e7 = col[j + 14];
        float4 r0 = qrow4(Q, e0, c4);
        float4 r1 = qrow4(Q, e1, c4);
        float4 r2 = qrow4(Q, e2, c4);
        float4 r3 = qrow4(Q, e3, c4);
        float4 r4 = qrow4(Q, e4, c4);
        float4 r5 = qrow4(Q, e5, c4);
        float4 r6 = qrow4(Q, e6, c4);
        float4 r7 = qrow4(Q, e7, c4);
        acc.x += ((r0.x + r1.x) + (r2.x + r3.x)) + ((r4.x + r5.x) + (r6.x + r7.x));
        acc.y += ((r0.y + r1.y) + (r2.y + r3.y)) + ((r4.y + r5.y) + (r6.y + r7.y));
        acc.z += ((r0.z + r1.z) + (r2.z + r3.z)) + ((r4.z + r5.z) + (r6.z + r7.z));
        acc.w += ((r0.w + r1.w) + (r2.w + r3.w)) + ((r4.w + r5.w) + (r6.w + r7.w));
    }
    for (; j + 6 < re; j += 8) {
        int e0 = col[j], e1 = col[j + 2], e2 = col[j + 4], e3 = col[j + 6];
        float4 r0 = qrow4(Q, e0, c4);
        float4 r1 = qrow4(Q, e1, c4);
        float4 r2 = qrow4(Q, e2, c4);
        float4 r3 = qrow4(Q, e3, c4);
        acc.x += (r0.x + r1.x) + (r2.x + r3.x);
        acc.y += (r0.y + r1.y) + (r2.y + r3.y);
        acc.z += (r0.z + r1.z) + (r2.z + r3.z);
        acc.w += (r0.w + r1.w) + (r2.w + r3.w);
    }
    for (; j < re; j += 2) {
        float4 r = qrow4(Q, col[j], c4);
        acc.x += r.x; acc.y += r.y; acc.z += r.z; acc.w += r.w;
    }
    acc.x += __shfl_xor(acc.x, 32);
    acc.y += __shfl_xor(acc.y, 32);
    acc.z += __shfl_xor(acc.z, 32);
    acc.w += __shfl_xor(acc.w, 32);
    if (half == 0) {
        float dv = dinv[n];
        acc.x = acc.x * dv + bias[c4];
        acc.y = acc.y * dv + bias[c4 + 1];
        acc.z = acc.z * dv + bias[c4 + 2];
        acc.w = acc.w * dv + bias[c4 + 3];
        __half2 o0 = __floats2half2_rn(acc.x, acc.y);
        __half2 o1 = __floats2half2_rn(acc.z, acc.w);
        uint2 u;
        u.x = *(unsigned int*)&o0;
        u.y = *(unsigned int*)&o1;
        *(uint2*)(A2 + (size_t)n * HDIM + c4) = u;
    }
}

// ---------------- layer-2 norm+relu+pool: coalesced, batch-run flush ----------------
__global__ __launch_bounds__(256) void node_norm_pool(const __half* __restrict__ A2,
                                                      const float* __restrict__ gmean,
                                                      const float* __restrict__ gistd,
                                                      const float* __restrict__ alpha,
                                                      const float* __restrict__ w,
                                                      const float* __restrict__ bb,
                                                      const int* __restrict__ batch,
                                                      float* __restrict__ gpool, int N) {
    int t = threadIdx.x;
    int c = t & 127;
    int half_ = t >> 7;
    int n0 = blockIdx.x * 32;
    float ac = alpha[c], wc = w[c], bc = bb[c];
    float s = 0.f, mc = 0.f, ic = 0.f;
    int cur = -1;
    for (int i = half_; i < 32; i += 2) {
        int n = n0 + i;
        if (n >= N) break;
        int b = batch[n];
        if (b != cur) {
            if (cur >= 0) unsafeAtomicAdd(&gpool[(size_t)cur * HDIM + c], s);
            cur = b; s = 0.f;
            mc = gmean[(size_t)b * HDIM + c];
            ic = gistd[(size_t)b * HDIM + c];
        }
        float v = __half2float(A2[(size_t)n * HDIM + c]);
        s += fmaxf(wc * (v - ac * mc) * ic + bc, 0.f);
    }
    if (cur >= 0) unsafeAtomicAdd(&gpool[(size_t)cur * HDIM + c], s);
}

// ---------------- head ----------------
__global__ __launch_bounds__(128) void head(const float* __restrict__ gpool,
                                            const float* __restrict__ gcnt,
                                            const float* __restrict__ H1,
                                            const float* __restrict__ hb1,
                                            const float* __restrict__ H2,
                                            const float* __restrict__ hb2,
                                            float* __restrict__ out, int G) {
    __shared__ float gv[HDIM];
    __shared__ float tv[HDIM];
    __shared__ float r0[HDIM], r1[HDIM];
    int g = blockIdx.x;
    int c = threadIdx.x;
    float cnt = fmaxf(gcnt[g], 1.0f);
    gv[c] = gpool[(long long)g * HDIM + c] / cnt;
    __syncthreads();
    float s = hb1[c];
    for (int k = 0; k < HDIM; k++) s += gv[k] * H1[k * HDIM + c];
    tv[c] = fmaxf(s, 0.f);
    __syncthreads();
    r0[c] = tv[c] * H2[c * 2 + 0];
    r1[c] = tv[c] * H2[c * 2 + 1];
    __syncthreads();
    for (int off = 64; off > 0; off >>= 1) {
        if (c < off) { r0[c] += r0[c + off]; r1[c] += r1[c + off]; }
        __syncthreads();
    }
    if (c == 0) {
        out[(long long)g * 2 + 0] = r0[0] + hb2[0];
        out[(long long)g * 2 + 1] = r1[0] + hb2[1];
    }
}

extern "C" void kernel_launch(void* const* d_in, const int* in_sizes, int n_in,
                              void* d_out, int out_size, void* d_ws, size_t ws_size,
                              hipStream_t stream) {
    const float* x    = (const float*)d_in[0];
    const int*   ei   = (const int*)d_in[1];
    const int*   batch= (const int*)d_in[2];
    const float* W1   = (const float*)d_in[4];
    const float* b1   = (const float*)d_in[5];
    const float* gn1w = (const float*)d_in[6];
    const float* gn1b = (const float*)d_in[7];
    const float* gn1a = (const float*)d_in[8];
    const float* W2   = (const float*)d_in[9];
    const float* b2   = (const float*)d_in[10];
    const float* gn2w = (const float*)d_in[11];
    const float* gn2b = (const float*)d_in[12];
    const float* gn2a = (const float*)d_in[13];
    const float* H1   = (const float*)d_in[14];
    const float* hb1  = (const float*)d_in[15];
    const float* H2   = (const float*)d_in[16];
    const float* hb2  = (const float*)d_in[17];

    int N = in_sizes[0] / 7;
    int E = in_sizes[1] / 2;
    int G = out_size / 2;
    const int* srcI = ei;
    const int* dstI = ei + E;

    int NB = (N + BKT_SIZE - 1) >> BKT_SHIFT;
    int NCHUNK = (E + CHK - 1) / CHK;

    // workspace layout
    __half* A16   = (__half*)d_ws;                   // N*128 half (layer1 pre-norm)
    __half* A2    = A16;                             // alias (layer2 pre-norm; A16 dead by then)
    __half* Q16   = A16 + (size_t)N * HDIM;          // N*128 half
    float*  xs    = (float*)(Q16 + (size_t)N * HDIM);// N*8
    float*  agg   = xs + (size_t)N * 8;              // N*8
    float*  gsum1 = agg + (size_t)N * 8;             // G*128
    float*  gsq1  = gsum1 + (size_t)G * HDIM;        // G*128
    float*  gsum2 = gsq1 + (size_t)G * HDIM;         // G*128
    float*  gsq2  = gsum2 + (size_t)G * HDIM;        // G*128
    float*  gpool = gsq2 + (size_t)G * HDIM;         // G*128
    float*  gcnt  = gpool + (size_t)G * HDIM;        // G
    float*  dinv  = gcnt + G;                        // N
    int* rowStart = (int*)(dinv + N);                // N+2
    unsigned int* EP = (unsigned int*)(rowStart + N + 2); // E
    int* col      = (int*)(EP + E);                  // E
    int* histG    = col + E;                         // NCHUNK*NB
    int* tot      = histG + (size_t)NCHUNK * NB;     // NB+2
    int* bucketBase = tot + NB + 2;                  // NB+2
    __half* W2t   = (__half*)(bucketBase + NB + 2);  // 128*128 half

    int gridNW = (N + 3) / 4;
    int gridGH = (G * HDIM + 255) / 256;
    int gridMM = (N + 63) / 64;
    int gridNS = (N + 31) / 32;

    // single upfront memset: gsum1,gsq1,gsum2,gsq2,gpool
    hipMemsetAsync(gsum1, 0, (size_t)G * HDIM * 5 * 4, stream);

    // ---- CSR build ----
    hist_pass<<<NCHUNK, 256, 0, stream>>>(dstI, histG, E, NB);
    scan_chunks<<<NB, 512, 0, stream>>>(histG, tot, NCHUNK, NB);
    scan_tot_k<<<1, 512, 0, stream>>>(tot, bucketBase, rowStart, NB, N, E);
    add_base<<<((NCHUNK * NB) + 255) / 256, 256, 0, stream>>>(histG, bucketBase, NCHUNK * NB, NB);
    scatter_bkt<<<NCHUNK, 256, 0, stream>>>(srcI, dstI, histG, EP, E, NB);
    bucket_csr<<<NB, 512, 0, stream>>>(EP, bucketBase, rowStart, dinv, col, N);

    // ---- per-graph counts (sorted batch -> binary search, no atomics) ----
    graph_counts<<<(G + 255) / 256, 256, 0, stream>>>(batch, gcnt, N, G);

    // ---- W2^T fp16 (once) ----
    prep_w2t<<<(HDIM * HDIM + 255) / 256, 256, 0, stream>>>(W2, W2t);

    // ---- block 1 (rank-7 aggregation) ----
    long long nx8 = (long long)N * 8;
    prep_xs<<<(int)((nx8 + 255) / 256), 256, 0, stream>>>(x, dinv, xs, nx8);
    agg7k<<<gridNW, 256, 0, stream>>>(col, rowStart, xs, agg, N);
    l1post<<<gridNW, 512, 0, stream>>>(agg, W1, b1, dinv, A16, N);
    stats2<<<gridNS, 256, 0, stream>>>(A16, batch, gsum1, gsq1, N);
    gstat<<<gridGH, 256, 0, stream>>>(gsum1, gsq1, gcnt, gn1a, G * HDIM);

    // ---- hidden matmul via MFMA, fused layer-1 norm+relu, fp16 in/out ----
    mm_h_mfma<<<gridMM, 256, 0, stream>>>(A16, gsum1, gsq1, gn1a, gn1w, gn1b, batch,
                                          W2t, dinv, Q16, N);

    // ---- block 2 (pure fp16 gather) ----
    node_agg2<<<gridNW, 256, 0, stream>>>(col, rowStart, Q16, dinv, b2, A2, N);
    stats2<<<gridNS, 256, 0, stream>>>(A2, batch, gsum2, gsq2, N);
    gstat<<<gridGH, 256, 0, stream>>>(gsum2, gsq2, gcnt, gn2a, G * HDIM);

    // ---- layer-2 norm + relu + pool ----
    node_norm_pool<<<gridNS, 256, 0, stream>>>(A2, gsum2, gsq2, gn2a, gn2w, gn2b, batch, gpool, N);

    // ---- head ----
    head<<<G, 128, 0, stream>>>(gpool, gcnt, H1, hb1, H2, hb2, (float*)d_out, G);
}

// Round 11
// 354.391 us; speedup vs baseline: 1.8998x; 1.0546x over previous
//
#include <hip/hip_runtime.h>
#include <hip/hip_fp16.h>

#define EPSV 1e-5f
#define HDIM 128
#define BKT_SHIFT 8
#define BKT_SIZE 256
#define NBMAX 512
#define CHK 4096

typedef _Float16 f16x8 __attribute__((ext_vector_type(8)));
typedef float f32x4 __attribute__((ext_vector_type(4)));

// ================= CSR build: bucketed counting sort =================

__global__ __launch_bounds__(256) void hist_pass(const int* __restrict__ dst,
                                                 int* __restrict__ histG, int E, int NB) {
    __shared__ int h[NBMAX];
    int t = threadIdx.x;
    for (int i = t; i < NB; i += 256) h[i] = 0;
    __syncthreads();
    int base = blockIdx.x * CHK;
    int end = min(base + CHK, E);
    for (int e = base + t; e < end; e += 256) atomicAdd(&h[dst[e] >> BKT_SHIFT], 1);
    __syncthreads();
    for (int i = t; i < NB; i += 256) histG[(size_t)blockIdx.x * NB + i] = h[i];
}

__global__ __launch_bounds__(1024) void scan_chunks(int* __restrict__ histG,
                                                    int* __restrict__ tot,
                                                    int NCHUNK, int NB) {
    __shared__ int tmp[1024];
    int b = blockIdx.x, t = threadIdx.x;
    int v = (t < NCHUNK) ? histG[(size_t)t * NB + b] : 0;
    tmp[t] = v;
    __syncthreads();
    for (int off = 1; off < 1024; off <<= 1) {
        int x = (t >= off) ? tmp[t - off] : 0;
        __syncthreads();
        tmp[t] += x;
        __syncthreads();
    }
    if (t < NCHUNK) histG[(size_t)t * NB + b] = tmp[t] - v;
    if (t == 1023) tot[b] = tmp[1023];
}

__global__ __launch_bounds__(512) void scan_tot_k(const int* __restrict__ tot,
                                                  int* __restrict__ bucketBase,
                                                  int* __restrict__ rowStart,
                                                  int NB, int N, int E) {
    __shared__ int tmp[512];
    int t = threadIdx.x;
    int v = (t < NB) ? tot[t] : 0;
    tmp[t] = v;
    __syncthreads();
    for (int off = 1; off < 512; off <<= 1) {
        int x = (t >= off) ? tmp[t - off] : 0;
        __syncthreads();
        tmp[t] += x;
        __syncthreads();
    }
    if (t < NB) bucketBase[t] = tmp[t] - v;
    if (t == NB - 1) {
        bucketBase[NB] = tmp[t];
        rowStart[N] = E;
    }
}

__global__ __launch_bounds__(256) void add_base(int* __restrict__ histG,
                                                const int* __restrict__ bucketBase,
                                                int total, int NB) {
    int i = blockIdx.x * 256 + threadIdx.x;
    if (i < total) histG[i] += bucketBase[i % NB];
}

__global__ __launch_bounds__(256) void scatter_bkt(const int* __restrict__ src,
                                                   const int* __restrict__ dst,
                                                   const int* __restrict__ chunkOff,
                                                   unsigned int* __restrict__ EP,
                                                   int E, int NB) {
    __shared__ int cur[NBMAX];
    int t = threadIdx.x, c = blockIdx.x;
    for (int i = t; i < NB; i += 256) cur[i] = chunkOff[(size_t)c * NB + i];
    __syncthreads();
    int base = c * CHK, end = min(base + CHK, E);
    for (int e = base + t; e < end; e += 256) {
        int d = dst[e];
        int b = d >> BKT_SHIFT;
        int pos = atomicAdd(&cur[b], 1);
        EP[pos] = (unsigned int)src[e] | ((unsigned int)(d & (BKT_SIZE - 1)) << 23);
    }
}

// per-bucket exact counting sort (512 threads over 256-node buckets)
__global__ __launch_bounds__(512) void bucket_csr(const unsigned int* __restrict__ EP,
                                                  const int* __restrict__ bucketBase,
                                                  int* __restrict__ rowStart,
                                                  float* __restrict__ dinv,
                                                  int* __restrict__ col, int N) {
    __shared__ int cnt[BKT_SIZE];
    __shared__ int tmp[BKT_SIZE];
    int b = blockIdx.x, t = threadIdx.x;
    int ebase = bucketBase[b], eend = bucketBase[b + 1];
    if (t < BKT_SIZE) cnt[t] = 0;
    __syncthreads();
    for (int e = ebase + t; e < eend; e += 512)
        atomicAdd(&cnt[(EP[e] >> 23) & (BKT_SIZE - 1)], 1);
    __syncthreads();
    int v = (t < BKT_SIZE) ? cnt[t] : 0;
    if (t < BKT_SIZE) tmp[t] = v;
    __syncthreads();
    for (int off = 1; off < BKT_SIZE; off <<= 1) {
        int x = (t >= off && t < BKT_SIZE) ? tmp[t - off] : 0;
        __syncthreads();
        if (t < BKT_SIZE) tmp[t] += x;
        __syncthreads();
    }
    if (t < BKT_SIZE) {
        int excl = tmp[t] - v;
        int n = (b << BKT_SHIFT) + t;
        if (n < N) {
            rowStart[n] = ebase + excl;
            dinv[n] = rsqrtf((float)v + 1.0f);
        }
        cnt[t] = ebase + excl;   // reuse as cursor
    }
    __syncthreads();
    for (int e = ebase + t; e < eend; e += 512) {
        unsigned int p = EP[e];
        int pos = atomicAdd(&cnt[(p >> 23) & (BKT_SIZE - 1)], 1);
        col[pos] = (int)(p & 0x7FFFFFu);
    }
}

// ---------------- setup: W2^T fp16 + per-graph counts (sorted batch, binary search) ----------------
__device__ __forceinline__ int lbound(const int* __restrict__ b, int N, int key) {
    int lo = 0, hi = N;
    while (lo < hi) {
        int mid = (lo + hi) >> 1;
        if (b[mid] < key) lo = mid + 1; else hi = mid;
    }
    return lo;
}

__global__ __launch_bounds__(256) void setup_misc(const float* __restrict__ W2,
                                                  __half* __restrict__ W2t,
                                                  const int* __restrict__ batch,
                                                  float* __restrict__ gcnt, int N, int G) {
    int i = blockIdx.x * 256 + threadIdx.x;
    if (i < HDIM * HDIM) {
        int c = i >> 7, k = i & 127;
        W2t[c * HDIM + k] = __float2half(W2[k * HDIM + c]);
    } else if (i - HDIM * HDIM < G) {
        int g = i - HDIM * HDIM;
        gcnt[g] = (float)(lbound(batch, N, g + 1) - lbound(batch, N, g));
    }
}

// ---------------- xs = dinv * x, padded [N][8] ----------------
__global__ __launch_bounds__(256) void prep_xs(const float* __restrict__ x,
                                               const float* __restrict__ dinv,
                                               float* __restrict__ xs, long long total) {
    long long idx = (long long)blockIdx.x * 256 + threadIdx.x;
    if (idx >= total) return;
    int n = (int)(idx >> 3), k = (int)(idx & 7);
    xs[idx] = (k < 7) ? x[(long long)n * 7 + k] * dinv[n] : 0.f;
}

// ---------------- fused layer-1: gather (16 streams) + W1 matmul -> A16 ----------------
__global__ __launch_bounds__(256) void aggl1(const int* __restrict__ col,
                                             const int* __restrict__ rowStart,
                                             const float* __restrict__ xs,
                                             const float* __restrict__ W1,
                                             const float* __restrict__ b1,
                                             const float* __restrict__ dinv,
                                             __half* __restrict__ A16, int N) {
    __shared__ float w1s[7 * HDIM];
    __shared__ float aggs[4][8];
    int t = threadIdx.x;
    for (int i = t; i < 7 * HDIM; i += 256) w1s[i] = W1[i];
    int wib = t >> 6, lane = t & 63;
    int stream = lane >> 2;
    int c2 = (lane & 3) * 2;
    int n = blockIdx.x * 4 + wib;
    float2 acc = make_float2(0.f, 0.f);
    if (n < N) {
        int rs = rowStart[n], re = rowStart[n + 1];
        if (stream == 0) acc = *(const float2*)(xs + (size_t)n * 8 + c2);
        int j = rs + stream;
        for (; j + 16 < re; j += 32) {
            int e0 = col[j], e1 = col[j + 16];
            float2 r0 = *(const float2*)(xs + (size_t)e0 * 8 + c2);
            float2 r1 = *(const float2*)(xs + (size_t)e1 * 8 + c2);
            acc.x += r0.x + r1.x;
            acc.y += r0.y + r1.y;
        }
        for (; j < re; j += 16) {
            float2 r = *(const float2*)(xs + (size_t)col[j] * 8 + c2);
            acc.x += r.x; acc.y += r.y;
        }
#pragma unroll
        for (int off = 4; off <= 32; off <<= 1) {
            acc.x += __shfl_xor(acc.x, off);
            acc.y += __shfl_xor(acc.y, off);
        }
        if (stream == 0) { aggs[wib][c2] = acc.x; aggs[wib][c2 + 1] = acc.y; }
    }
    __syncthreads();
    if (n < N) {
        float ar[7];
#pragma unroll
        for (int k = 0; k < 7; k++) ar[k] = aggs[wib][k];
        float dv = dinv[n];
        int c = lane * 2;
        float s0 = 0.f, s1 = 0.f;
#pragma unroll
        for (int k = 0; k < 7; k++) {
            s0 += ar[k] * w1s[k * HDIM + c];
            s1 += ar[k] * w1s[k * HDIM + c + 1];
        }
        *(__half2*)(A16 + (size_t)n * HDIM + c) =
            __floats2half2_rn(s0 * dv + b1[c], s1 * dv + b1[c + 1]);
    }
}

// ---------------- coalesced GraphNorm stats over fp16 matrix, batch-run flush ----------------
__global__ __launch_bounds__(256) void stats2(const __half* __restrict__ X,
                                              const int* __restrict__ batch,
                                              float* __restrict__ gsum,
                                              float* __restrict__ gsq, int N) {
    int t = threadIdx.x;
    int c = t & 127;
    int half_ = t >> 7;
    int n0 = blockIdx.x * 32;
    float s = 0.f, q = 0.f;
    int cur = -1;
    for (int i = half_; i < 32; i += 2) {
        int n = n0 + i;
        if (n >= N) break;
        int b = batch[n];
        if (b != cur) {
            if (cur >= 0) {
                unsafeAtomicAdd(&gsum[(size_t)cur * HDIM + c], s);
                unsafeAtomicAdd(&gsq[(size_t)cur * HDIM + c], q);
            }
            cur = b; s = 0.f; q = 0.f;
        }
        float v = __half2float(X[(size_t)n * HDIM + c]);
        s += v; q += v * v;
    }
    if (cur >= 0) {
        unsafeAtomicAdd(&gsum[(size_t)cur * HDIM + c], s);
        unsafeAtomicAdd(&gsq[(size_t)cur * HDIM + c], q);
    }
}

// ---------------- per-(graph,channel): sums -> mean, inv-std ----------------
__global__ __launch_bounds__(256) void gstat(float* __restrict__ gsum,
                                             float* __restrict__ gsq,
                                             const float* __restrict__ gcnt,
                                             const float* __restrict__ alpha, int total) {
    int i = blockIdx.x * 256 + threadIdx.x;
    if (i < total) {
        int g = i >> 7, c = i & 127;
        float cnt = fmaxf(gcnt[g], 1.f);
        float mean = gsum[i] / cnt;
        float m2 = gsq[i] / cnt;
        float a = alpha[c];
        float var = m2 + mean * mean * (a * a - 2.f * a);
        gsum[i] = mean;
        gsq[i] = rsqrtf(fmaxf(var, 0.f) + EPSV);
    }
}

// ---------------- hidden matmul via MFMA: Q = half(dinv * (relu(norm(A16)) @ W2)) ----------------
__global__ __launch_bounds__(256) void mm_h_mfma(const __half* __restrict__ A16,
                                                 const float* __restrict__ gmean,
                                                 const float* __restrict__ gistd,
                                                 const float* __restrict__ alpha,
                                                 const float* __restrict__ w,
                                                 const float* __restrict__ bb,
                                                 const int* __restrict__ batch,
                                                 const __half* __restrict__ W2t,
                                                 const float* __restrict__ dinv,
                                                 __half* __restrict__ Q, int N) {
    __shared__ _Float16 XS[64][136];
    __shared__ _Float16 WT[HDIM][136];
    __shared__ float pA[HDIM], pW[HDIM], pB[HDIM];
    int t = threadIdx.x;
    for (int i = t; i < HDIM; i += 256) { pA[i] = alpha[i]; pW[i] = w[i]; pB[i] = bb[i]; }
    int n0 = blockIdx.x * 64;

    for (int i = t; i < HDIM * 16; i += 256) {
        int row = i >> 4;
        int kk = (i & 15) * 8;
        *(uint4*)&WT[row][kk] = *(const uint4*)(W2t + (size_t)row * HDIM + kk);
    }
    __syncthreads();

    for (int i = t; i < 64 * 16; i += 256) {
        int nn = i >> 4;
        int kk = (i & 15) * 8;
        int gn = n0 + nn;
        __half hv[8];
#pragma unroll
        for (int k = 0; k < 8; k++) hv[k] = __float2half(0.f);
        if (gn < N) {
            uint4 u = *(const uint4*)(A16 + (size_t)gn * HDIM + kk);
            int b = batch[gn];
            const float* mp = gmean + (size_t)b * HDIM + kk;
            const float* ip = gistd + (size_t)b * HDIM + kk;
            float2 f0 = __half22float2(*(__half2*)&u.x);
            float2 f1 = __half22float2(*(__half2*)&u.y);
            float2 f2 = __half22float2(*(__half2*)&u.z);
            float2 f3 = __half22float2(*(__half2*)&u.w);
            float f[8] = {f0.x, f0.y, f1.x, f1.y, f2.x, f2.y, f3.x, f3.y};
#pragma unroll
            for (int k = 0; k < 8; k++) {
                int c = kk + k;
                hv[k] = __float2half(fmaxf(pW[c] * (f[k] - pA[c] * mp[k]) * ip[k] + pB[c], 0.f));
            }
        }
        *(uint4*)&XS[nn][kk] = *(uint4*)hv;
    }
    __syncthreads();

    int wid = t >> 6, lane = t & 63;
    int m0 = wid * 16;
    int rlane = lane & 15;
    int kgrp = lane >> 4;
    f32x4 acc[8];
#pragma unroll
    for (int ct = 0; ct < 8; ct++) acc[ct] = (f32x4){0.f, 0.f, 0.f, 0.f};

#pragma unroll
    for (int kt = 0; kt < 4; ++kt) {
        int kbase = kt * 32 + kgrp * 8;
        f16x8 a = *(const f16x8*)&XS[m0 + rlane][kbase];
#pragma unroll
        for (int ct = 0; ct < 8; ++ct) {
            f16x8 bfr = *(const f16x8*)&WT[ct * 16 + rlane][kbase];
            acc[ct] = __builtin_amdgcn_mfma_f32_16x16x32_f16(a, bfr, acc[ct], 0, 0, 0);
        }
    }

    int rgrp = lane >> 4;
    float dv[4];
    int gnr[4];
#pragma unroll
    for (int r = 0; r < 4; r++) {
        gnr[r] = n0 + m0 + rgrp * 4 + r;
        dv[r] = (gnr[r] < N) ? dinv[gnr[r]] : 0.f;
    }
#pragma unroll
    for (int ct = 0; ct < 8; ++ct) {
#pragma unroll
        for (int r = 0; r < 4; ++r) {
            if (gnr[r] < N)
                Q[(size_t)gnr[r] * HDIM + ct * 16 + rlane] = __float2half(acc[ct][r] * dv[r]);
        }
    }
}

// ---------------- fp16 row load: 4 channels (8B) ----------------
__device__ __forceinline__ float4 qrow4(const __half* __restrict__ Q, int e, int c4) {
    uint2 u = *(const uint2*)(Q + (size_t)e * HDIM + c4);
    float2 f0 = __half22float2(*(__half2*)&u.x);
    float2 f1 = __half22float2(*(__half2*)&u.y);
    return make_float4(f0.x, f0.y, f1.x, f1.y);
}

// ---------------- layer-2 CSR gather: PURE (no stats/LDS/barrier) ----------------
__global__ __launch_bounds__(256) void node_agg2(const int* __restrict__ col,
                                                 const int* __restrict__ rowStart,
                                                 const __half* __restrict__ Q,
                                                 const float* __restrict__ dinv,
                                                 const float* __restrict__ bias,
                                                 __half* __restrict__ A2, int N) {
    int wib = threadIdx.x >> 6;
    int lane = threadIdx.x & 63;
    int half = lane >> 5;
    int l = lane & 31;
    int c4 = l * 4;
    int n = blockIdx.x * 4 + wib;
    if (n >= N) return;
    float4 acc = make_float4(0.f, 0.f, 0.f, 0.f);
    int rs = rowStart[n], re = rowStart[n + 1];
    if (half == 0) acc = qrow4(Q, n, c4);          // self term
    int j = rs + half;
    for (; j + 14 < re; j += 16) {
        int e0 = col[j],      e1 = col[j + 2],  e2 = col[j + 4],  e3 = col[j + 6];
        int e4 = col[j + 8],  e5 = col[j + 10], e6 = col[j + 12], e7 = col[j + 14];
        float4 r0 = qrow4(Q, e0, c4);
        float4 r1 = qrow4(Q, e1, c4);
        float4 r2 = qrow4(Q, e2, c4);
        float4 r3 = qrow4(Q, e3, c4);
        float4 r4 = qrow4(Q, e4, c4);
        float4 r5 = qrow4(Q, e5, c4);
        float4 r6 = qrow4(Q, e6, c4);
        float4 r7 = qrow4(Q, e7, c4);
        acc.x += ((r0.x + r1.x) + (r2.x + r3.x)) + ((r4.x + r5.x) + (r6.x + r7.x));
        acc.y += ((r0.y + r1.y) + (r2.y + r3.y)) + ((r4.y + r5.y) + (r6.y + r7.y));
        acc.z += ((r0.z + r1.z) + (r2.z + r3.z)) + ((r4.z + r5.z) + (r6.z + r7.z));
        acc.w += ((r0.w + r1.w) + (r2.w + r3.w)) + ((r4.w + r5.w) + (r6.w + r7.w));
    }
    for (; j + 6 < re; j += 8) {
        int e0 = col[j], e1 = col[j + 2], e2 = col[j + 4], e3 = col[j + 6];
        float4 r0 = qrow4(Q, e0, c4);
        float4 r1 = qrow4(Q, e1, c4);
        float4 r2 = qrow4(Q, e2, c4);
        float4 r3 = qrow4(Q, e3, c4);
        acc.x += (r0.x + r1.x) + (r2.x + r3.x);
        acc.y += (r0.y + r1.y) + (r2.y + r3.y);
        acc.z += (r0.z + r1.z) + (r2.z + r3.z);
        acc.w += (r0.w + r1.w) + (r2.w + r3.w);
    }
    for (; j < re; j += 2) {
        float4 r = qrow4(Q, col[j], c4);
        acc.x += r.x; acc.y += r.y; acc.z += r.z; acc.w += r.w;
    }
    acc.x += __shfl_xor(acc.x, 32);
    acc.y += __shfl_xor(acc.y, 32);
    acc.z += __shfl_xor(acc.z, 32);
    acc.w += __shfl_xor(acc.w, 32);
    if (half == 0) {
        float dv = dinv[n];
        acc.x = acc.x * dv + bias[c4];
        acc.y = acc.y * dv + bias[c4 + 1];
        acc.z = acc.z * dv + bias[c4 + 2];
        acc.w = acc.w * dv + bias[c4 + 3];
        __half2 o0 = __floats2half2_rn(acc.x, acc.y);
        __half2 o1 = __floats2half2_rn(acc.z, acc.w);
        uint2 u;
        u.x = *(unsigned int*)&o0;
        u.y = *(unsigned int*)&o1;
        *(uint2*)(A2 + (size_t)n * HDIM + c4) = u;
    }
}

// ---------------- layer-2 norm+relu+pool: coalesced, batch-run flush ----------------
__global__ __launch_bounds__(256) void node_norm_pool(const __half* __restrict__ A2,
                                                      const float* __restrict__ gmean,
                                                      const float* __restrict__ gistd,
                                                      const float* __restrict__ alpha,
                                                      const float* __restrict__ w,
                                                      const float* __restrict__ bb,
                                                      const int* __restrict__ batch,
                                                      float* __restrict__ gpool, int N) {
    int t = threadIdx.x;
    int c = t & 127;
    int half_ = t >> 7;
    int n0 = blockIdx.x * 32;
    float ac = alpha[c], wc = w[c], bc = bb[c];
    float s = 0.f, mc = 0.f, ic = 0.f;
    int cur = -1;
    for (int i = half_; i < 32; i += 2) {
        int n = n0 + i;
        if (n >= N) break;
        int b = batch[n];
        if (b != cur) {
            if (cur >= 0) unsafeAtomicAdd(&gpool[(size_t)cur * HDIM + c], s);
            cur = b; s = 0.f;
            mc = gmean[(size_t)b * HDIM + c];
            ic = gistd[(size_t)b * HDIM + c];
        }
        float v = __half2float(A2[(size_t)n * HDIM + c]);
        s += fmaxf(wc * (v - ac * mc) * ic + bc, 0.f);
    }
    if (cur >= 0) unsafeAtomicAdd(&gpool[(size_t)cur * HDIM + c], s);
}

// ---------------- head ----------------
__global__ __launch_bounds__(128) void head(const float* __restrict__ gpool,
                                            const float* __restrict__ gcnt,
                                            const float* __restrict__ H1,
                                            const float* __restrict__ hb1,
                                            const float* __restrict__ H2,
                                            const float* __restrict__ hb2,
                                            float* __restrict__ out, int G) {
    __shared__ float gv[HDIM];
    __shared__ float tv[HDIM];
    __shared__ float r0[HDIM], r1[HDIM];
    int g = blockIdx.x;
    int c = threadIdx.x;
    float cnt = fmaxf(gcnt[g], 1.0f);
    gv[c] = gpool[(long long)g * HDIM + c] / cnt;
    __syncthreads();
    float s = hb1[c];
    for (int k = 0; k < HDIM; k++) s += gv[k] * H1[k * HDIM + c];
    tv[c] = fmaxf(s, 0.f);
    __syncthreads();
    r0[c] = tv[c] * H2[c * 2 + 0];
    r1[c] = tv[c] * H2[c * 2 + 1];
    __syncthreads();
    for (int off = 64; off > 0; off >>= 1) {
        if (c < off) { r0[c] += r0[c + off]; r1[c] += r1[c + off]; }
        __syncthreads();
    }
    if (c == 0) {
        out[(long long)g * 2 + 0] = r0[0] + hb2[0];
        out[(long long)g * 2 + 1] = r1[0] + hb2[1];
    }
}

extern "C" void kernel_launch(void* const* d_in, const int* in_sizes, int n_in,
                              void* d_out, int out_size, void* d_ws, size_t ws_size,
                              hipStream_t stream) {
    const float* x    = (const float*)d_in[0];
    const int*   ei   = (const int*)d_in[1];
    const int*   batch= (const int*)d_in[2];
    const float* W1   = (const float*)d_in[4];
    const float* b1   = (const float*)d_in[5];
    const float* gn1w = (const float*)d_in[6];
    const float* gn1b = (const float*)d_in[7];
    const float* gn1a = (const float*)d_in[8];
    const float* W2   = (const float*)d_in[9];
    const float* b2   = (const float*)d_in[10];
    const float* gn2w = (const float*)d_in[11];
    const float* gn2b = (const float*)d_in[12];
    const float* gn2a = (const float*)d_in[13];
    const float* H1   = (const float*)d_in[14];
    const float* hb1  = (const float*)d_in[15];
    const float* H2   = (const float*)d_in[16];
    const float* hb2  = (const float*)d_in[17];

    int N = in_sizes[0] / 7;
    int E = in_sizes[1] / 2;
    int G = out_size / 2;
    const int* srcI = ei;
    const int* dstI = ei + E;

    int NB = (N + BKT_SIZE - 1) >> BKT_SHIFT;      // 391 buckets of 256 nodes
    int NCHUNK = (E + CHK - 1) / CHK;              // 782 chunks of 4096 edges

    // workspace layout
    __half* A16   = (__half*)d_ws;                   // N*128 half (layer1 pre-norm)
    __half* A2    = A16;                             // alias (layer2 pre-norm; A16 dead by then)
    __half* Q16   = A16 + (size_t)N * HDIM;          // N*128 half
    float*  xs    = (float*)(Q16 + (size_t)N * HDIM);// N*8
    float*  gsum1 = xs + (size_t)N * 8;              // G*128
    float*  gsq1  = gsum1 + (size_t)G * HDIM;        // G*128
    float*  gsum2 = gsq1 + (size_t)G * HDIM;         // G*128
    float*  gsq2  = gsum2 + (size_t)G * HDIM;        // G*128
    float*  gpool = gsq2 + (size_t)G * HDIM;         // G*128
    float*  gcnt  = gpool + (size_t)G * HDIM;        // G
    float*  dinv  = gcnt + G;                        // N
    int* rowStart = (int*)(dinv + N);                // N+2
    unsigned int* EP = (unsigned int*)(rowStart + N + 2); // E
    int* col      = (int*)(EP + E);                  // E
    int* histG    = col + E;                         // NCHUNK*NB
    int* tot      = histG + (size_t)NCHUNK * NB;     // NB+2
    int* bucketBase = tot + NB + 2;                  // NB+2
    __half* W2t   = (__half*)(bucketBase + NB + 2);  // 128*128 half

    int gridNW = (N + 3) / 4;
    int gridGH = (G * HDIM + 255) / 256;
    int gridMM = (N + 63) / 64;
    int gridNS = (N + 31) / 32;

    // single upfront memset: gsum1,gsq1,gsum2,gsq2,gpool
    hipMemsetAsync(gsum1, 0, (size_t)G * HDIM * 5 * 4, stream);

    // ---- CSR build (finer grids: ~3 waves/SIMD in each phase) ----
    hist_pass<<<NCHUNK, 256, 0, stream>>>(dstI, histG, E, NB);
    scan_chunks<<<NB, 1024, 0, stream>>>(histG, tot, NCHUNK, NB);
    scan_tot_k<<<1, 512, 0, stream>>>(tot, bucketBase, rowStart, NB, N, E);
    add_base<<<((NCHUNK * NB) + 255) / 256, 256, 0, stream>>>(histG, bucketBase, NCHUNK * NB, NB);
    scatter_bkt<<<NCHUNK, 256, 0, stream>>>(srcI, dstI, histG, EP, E, NB);
    bucket_csr<<<NB, 512, 0, stream>>>(EP, bucketBase, rowStart, dinv, col, N);

    // ---- setup: W2^T fp16 + per-graph counts ----
    setup_misc<<<(HDIM * HDIM + G + 255) / 256, 256, 0, stream>>>(W2, W2t, batch, gcnt, N, G);

    // ---- block 1: fused rank-7 aggregation + W1 matmul ----
    long long nx8 = (long long)N * 8;
    prep_xs<<<(int)((nx8 + 255) / 256), 256, 0, stream>>>(x, dinv, xs, nx8);
    aggl1<<<gridNW, 256, 0, stream>>>(col, rowStart, xs, W1, b1, dinv, A16, N);
    stats2<<<gridNS, 256, 0, stream>>>(A16, batch, gsum1, gsq1, N);
    gstat<<<gridGH, 256, 0, stream>>>(gsum1, gsq1, gcnt, gn1a, G * HDIM);

    // ---- hidden matmul via MFMA, fused layer-1 norm+relu, fp16 in/out ----
    mm_h_mfma<<<gridMM, 256, 0, stream>>>(A16, gsum1, gsq1, gn1a, gn1w, gn1b, batch,
                                          W2t, dinv, Q16, N);

    // ---- block 2 (pure fp16 gather) ----
    node_agg2<<<gridNW, 256, 0, stream>>>(col, rowStart, Q16, dinv, b2, A2, N);
    stats2<<<gridNS, 256, 0, stream>>>(A2, batch, gsum2, gsq2, N);
    gstat<<<gridGH, 256, 0, stream>>>(gsum2, gsq2, gcnt, gn2a, G * HDIM);

    // ---- layer-2 norm + relu + pool ----
    node_norm_pool<<<gridNS, 256, 0, stream>>>(A2, gsum2, gsq2, gn2a, gn2w, gn2b, batch, gpool, N);

    // ---- head ----
    head<<<G, 128, 0, stream>>>(gpool, gcnt, H1, hb1, H2, hb2, (float*)d_out, G);
}

// Round 12
// 351.862 us; speedup vs baseline: 1.9135x; 1.0072x over previous
//
#include <hip/hip_runtime.h>
#include <hip/hip_fp16.h>

#define EPSV 1e-5f
#define HDIM 128
#define BKT_SHIFT 8
#define BKT_SIZE 256
#define NBMAX 512
#define CHK 4096

typedef _Float16 f16x8 __attribute__((ext_vector_type(8)));
typedef float f32x4 __attribute__((ext_vector_type(4)));

// ================= CSR build: bucketed counting sort =================

__global__ __launch_bounds__(256) void hist_pass(const int* __restrict__ dst,
                                                 int* __restrict__ histG, int E, int NB) {
    __shared__ int h[NBMAX];
    int t = threadIdx.x;
    for (int i = t; i < NB; i += 256) h[i] = 0;
    __syncthreads();
    int base = blockIdx.x * CHK;
    int end = min(base + CHK, E);
    for (int e = base + t; e < end; e += 256) atomicAdd(&h[dst[e] >> BKT_SHIFT], 1);
    __syncthreads();
    for (int i = t; i < NB; i += 256) histG[(size_t)blockIdx.x * NB + i] = h[i];
}

// per-bucket exclusive scan over chunks via wave shfl scan (2 barriers)
__global__ __launch_bounds__(1024) void scan_chunks(int* __restrict__ histG,
                                                    int* __restrict__ tot,
                                                    int NCHUNK, int NB) {
    __shared__ int wsum[16];
    int b = blockIdx.x, t = threadIdx.x;
    int lane = t & 63, w = t >> 6;
    int v = (t < NCHUNK) ? histG[(size_t)t * NB + b] : 0;
    int iv = v;
#pragma unroll
    for (int off = 1; off < 64; off <<= 1) {
        int x = __shfl_up(iv, off);
        if (lane >= off) iv += x;
    }
    if (lane == 63) wsum[w] = iv;
    __syncthreads();
    int woff = 0;
    for (int i = 0; i < w; i++) woff += wsum[i];
    int incl = iv + woff;
    if (t < NCHUNK) histG[(size_t)t * NB + b] = incl - v;   // exclusive within bucket
    if (t == 1023) tot[b] = incl;
}

// exclusive scan over buckets via wave shfl scan
__global__ __launch_bounds__(512) void scan_tot_k(const int* __restrict__ tot,
                                                  int* __restrict__ bucketBase,
                                                  int* __restrict__ rowStart,
                                                  int NB, int N, int E) {
    __shared__ int wsum[8];
    int t = threadIdx.x, lane = t & 63, w = t >> 6;
    int v = (t < NB) ? tot[t] : 0;
    int iv = v;
#pragma unroll
    for (int off = 1; off < 64; off <<= 1) {
        int x = __shfl_up(iv, off);
        if (lane >= off) iv += x;
    }
    if (lane == 63) wsum[w] = iv;
    __syncthreads();
    int woff = 0;
    for (int i = 0; i < w; i++) woff += wsum[i];
    int incl = iv + woff;
    if (t < NB) bucketBase[t] = incl - v;
    if (t == NB - 1) {
        bucketBase[NB] = incl;
        rowStart[N] = E;
    }
}

// scatter with bucketBase folded into cursor init (add_base kernel eliminated)
__global__ __launch_bounds__(256) void scatter_bkt(const int* __restrict__ src,
                                                   const int* __restrict__ dst,
                                                   const int* __restrict__ chunkOff,
                                                   const int* __restrict__ bucketBase,
                                                   unsigned int* __restrict__ EP,
                                                   int E, int NB) {
    __shared__ int cur[NBMAX];
    int t = threadIdx.x, c = blockIdx.x;
    for (int i = t; i < NB; i += 256)
        cur[i] = chunkOff[(size_t)c * NB + i] + bucketBase[i];
    __syncthreads();
    int base = c * CHK, end = min(base + CHK, E);
    for (int e = base + t; e < end; e += 256) {
        int d = dst[e];
        int b = d >> BKT_SHIFT;
        int pos = atomicAdd(&cur[b], 1);
        EP[pos] = (unsigned int)src[e] | ((unsigned int)(d & (BKT_SIZE - 1)) << 23);
    }
}

// per-bucket exact counting sort; scan via wave shfl (3 barriers total)
__global__ __launch_bounds__(512) void bucket_csr(const unsigned int* __restrict__ EP,
                                                  const int* __restrict__ bucketBase,
                                                  int* __restrict__ rowStart,
                                                  float* __restrict__ dinv,
                                                  int* __restrict__ col, int N) {
    __shared__ int cnt[BKT_SIZE];
    __shared__ int wsum[4];
    int b = blockIdx.x, t = threadIdx.x;
    int ebase = bucketBase[b], eend = bucketBase[b + 1];
    if (t < BKT_SIZE) cnt[t] = 0;
    __syncthreads();
    for (int e = ebase + t; e < eend; e += 512)
        atomicAdd(&cnt[(EP[e] >> 23) & (BKT_SIZE - 1)], 1);
    __syncthreads();
    int v = 0, iv = 0;
    if (t < BKT_SIZE) {
        v = cnt[t];
        iv = v;
        int lane = t & 63;
#pragma unroll
        for (int off = 1; off < 64; off <<= 1) {
            int x = __shfl_up(iv, off);
            if (lane >= off) iv += x;
        }
        if (lane == 63) wsum[t >> 6] = iv;
    }
    __syncthreads();
    if (t < BKT_SIZE) {
        int w = t >> 6;
        int woff = 0;
        for (int i = 0; i < w; i++) woff += wsum[i];
        int excl = iv + woff - v;
        int n = (b << BKT_SHIFT) + t;
        if (n < N) {
            rowStart[n] = ebase + excl;
            dinv[n] = rsqrtf((float)v + 1.0f);
        }
        cnt[t] = ebase + excl;   // reuse as cursor
    }
    __syncthreads();
    for (int e = ebase + t; e < eend; e += 512) {
        unsigned int p = EP[e];
        int pos = atomicAdd(&cnt[(p >> 23) & (BKT_SIZE - 1)], 1);
        col[pos] = (int)(p & 0x7FFFFFu);
    }
}

// ---------------- setup: W2^T fp16 + per-graph counts (sorted batch, binary search) ----------------
__device__ __forceinline__ int lbound(const int* __restrict__ b, int N, int key) {
    int lo = 0, hi = N;
    while (lo < hi) {
        int mid = (lo + hi) >> 1;
        if (b[mid] < key) lo = mid + 1; else hi = mid;
    }
    return lo;
}

__global__ __launch_bounds__(256) void setup_misc(const float* __restrict__ W2,
                                                  __half* __restrict__ W2t,
                                                  const int* __restrict__ batch,
                                                  float* __restrict__ gcnt, int N, int G) {
    int i = blockIdx.x * 256 + threadIdx.x;
    if (i < HDIM * HDIM) {
        int c = i >> 7, k = i & 127;
        W2t[c * HDIM + k] = __float2half(W2[k * HDIM + c]);
    } else if (i - HDIM * HDIM < G) {
        int g = i - HDIM * HDIM;
        gcnt[g] = (float)(lbound(batch, N, g + 1) - lbound(batch, N, g));
    }
}

// ---------------- xs = dinv * x, padded [N][8] ----------------
__global__ __launch_bounds__(256) void prep_xs(const float* __restrict__ x,
                                               const float* __restrict__ dinv,
                                               float* __restrict__ xs, long long total) {
    long long idx = (long long)blockIdx.x * 256 + threadIdx.x;
    if (idx >= total) return;
    int n = (int)(idx >> 3), k = (int)(idx & 7);
    xs[idx] = (k < 7) ? x[(long long)n * 7 + k] * dinv[n] : 0.f;
}

// ---------------- fused layer-1: gather (16 streams) + W1 matmul -> A16 ----------------
__global__ __launch_bounds__(256) void aggl1(const int* __restrict__ col,
                                             const int* __restrict__ rowStart,
                                             const float* __restrict__ xs,
                                             const float* __restrict__ W1,
                                             const float* __restrict__ b1,
                                             const float* __restrict__ dinv,
                                             __half* __restrict__ A16, int N) {
    __shared__ float w1s[7 * HDIM];
    __shared__ float aggs[4][8];
    int t = threadIdx.x;
    for (int i = t; i < 7 * HDIM; i += 256) w1s[i] = W1[i];
    int wib = t >> 6, lane = t & 63;
    int stream = lane >> 2;
    int c2 = (lane & 3) * 2;
    int n = blockIdx.x * 4 + wib;
    float2 acc = make_float2(0.f, 0.f);
    if (n < N) {
        int rs = rowStart[n], re = rowStart[n + 1];
        if (stream == 0) acc = *(const float2*)(xs + (size_t)n * 8 + c2);
        int j = rs + stream;
        for (; j + 16 < re; j += 32) {
            int e0 = col[j], e1 = col[j + 16];
            float2 r0 = *(const float2*)(xs + (size_t)e0 * 8 + c2);
            float2 r1 = *(const float2*)(xs + (size_t)e1 * 8 + c2);
            acc.x += r0.x + r1.x;
            acc.y += r0.y + r1.y;
        }
        for (; j < re; j += 16) {
            float2 r = *(const float2*)(xs + (size_t)col[j] * 8 + c2);
            acc.x += r.x; acc.y += r.y;
        }
#pragma unroll
        for (int off = 4; off <= 32; off <<= 1) {
            acc.x += __shfl_xor(acc.x, off);
            acc.y += __shfl_xor(acc.y, off);
        }
        if (stream == 0) { aggs[wib][c2] = acc.x; aggs[wib][c2 + 1] = acc.y; }
    }
    __syncthreads();
    if (n < N) {
        float ar[7];
#pragma unroll
        for (int k = 0; k < 7; k++) ar[k] = aggs[wib][k];
        float dv = dinv[n];
        int c = lane * 2;
        float s0 = 0.f, s1 = 0.f;
#pragma unroll
        for (int k = 0; k < 7; k++) {
            s0 += ar[k] * w1s[k * HDIM + c];
            s1 += ar[k] * w1s[k * HDIM + c + 1];
        }
        *(__half2*)(A16 + (size_t)n * HDIM + c) =
            __floats2half2_rn(s0 * dv + b1[c], s1 * dv + b1[c + 1]);
    }
}

// ---------------- coalesced GraphNorm stats over fp16 matrix, batch-run flush ----------------
__global__ __launch_bounds__(256) void stats2(const __half* __restrict__ X,
                                              const int* __restrict__ batch,
                                              float* __restrict__ gsum,
                                              float* __restrict__ gsq, int N) {
    int t = threadIdx.x;
    int c = t & 127;
    int half_ = t >> 7;
    int n0 = blockIdx.x * 32;
    float s = 0.f, q = 0.f;
    int cur = -1;
    for (int i = half_; i < 32; i += 2) {
        int n = n0 + i;
        if (n >= N) break;
        int b = batch[n];
        if (b != cur) {
            if (cur >= 0) {
                unsafeAtomicAdd(&gsum[(size_t)cur * HDIM + c], s);
                unsafeAtomicAdd(&gsq[(size_t)cur * HDIM + c], q);
            }
            cur = b; s = 0.f; q = 0.f;
        }
        float v = __half2float(X[(size_t)n * HDIM + c]);
        s += v; q += v * v;
    }
    if (cur >= 0) {
        unsafeAtomicAdd(&gsum[(size_t)cur * HDIM + c], s);
        unsafeAtomicAdd(&gsq[(size_t)cur * HDIM + c], q);
    }
}

// ---------------- per-(graph,channel): sums -> mean, inv-std ----------------
__global__ __launch_bounds__(256) void gstat(float* __restrict__ gsum,
                                             float* __restrict__ gsq,
                                             const float* __restrict__ gcnt,
                                             const float* __restrict__ alpha, int total) {
    int i = blockIdx.x * 256 + threadIdx.x;
    if (i < total) {
        int g = i >> 7, c = i & 127;
        float cnt = fmaxf(gcnt[g], 1.f);
        float mean = gsum[i] / cnt;
        float m2 = gsq[i] / cnt;
        float a = alpha[c];
        float var = m2 + mean * mean * (a * a - 2.f * a);
        gsum[i] = mean;
        gsq[i] = rsqrtf(fmaxf(var, 0.f) + EPSV);
    }
}

// ---------------- hidden matmul via MFMA: Q = half(dinv * (relu(norm(A16)) @ W2)) ----------------
__global__ __launch_bounds__(256) void mm_h_mfma(const __half* __restrict__ A16,
                                                 const float* __restrict__ gmean,
                                                 const float* __restrict__ gistd,
                                                 const float* __restrict__ alpha,
                                                 const float* __restrict__ w,
                                                 const float* __restrict__ bb,
                                                 const int* __restrict__ batch,
                                                 const __half* __restrict__ W2t,
                                                 const float* __restrict__ dinv,
                                                 __half* __restrict__ Q, int N) {
    __shared__ _Float16 XS[64][136];
    __shared__ _Float16 WT[HDIM][136];
    __shared__ float pA[HDIM], pW[HDIM], pB[HDIM];
    int t = threadIdx.x;
    for (int i = t; i < HDIM; i += 256) { pA[i] = alpha[i]; pW[i] = w[i]; pB[i] = bb[i]; }
    int n0 = blockIdx.x * 64;

    for (int i = t; i < HDIM * 16; i += 256) {
        int row = i >> 4;
        int kk = (i & 15) * 8;
        *(uint4*)&WT[row][kk] = *(const uint4*)(W2t + (size_t)row * HDIM + kk);
    }
    __syncthreads();

    for (int i = t; i < 64 * 16; i += 256) {
        int nn = i >> 4;
        int kk = (i & 15) * 8;
        int gn = n0 + nn;
        __half hv[8];
#pragma unroll
        for (int k = 0; k < 8; k++) hv[k] = __float2half(0.f);
        if (gn < N) {
            uint4 u = *(const uint4*)(A16 + (size_t)gn * HDIM + kk);
            int b = batch[gn];
            const float* mp = gmean + (size_t)b * HDIM + kk;
            const float* ip = gistd + (size_t)b * HDIM + kk;
            float2 f0 = __half22float2(*(__half2*)&u.x);
            float2 f1 = __half22float2(*(__half2*)&u.y);
            float2 f2 = __half22float2(*(__half2*)&u.z);
            float2 f3 = __half22float2(*(__half2*)&u.w);
            float f[8] = {f0.x, f0.y, f1.x, f1.y, f2.x, f2.y, f3.x, f3.y};
#pragma unroll
            for (int k = 0; k < 8; k++) {
                int c = kk + k;
                hv[k] = __float2half(fmaxf(pW[c] * (f[k] - pA[c] * mp[k]) * ip[k] + pB[c], 0.f));
            }
        }
        *(uint4*)&XS[nn][kk] = *(uint4*)hv;
    }
    __syncthreads();

    int wid = t >> 6, lane = t & 63;
    int m0 = wid * 16;
    int rlane = lane & 15;
    int kgrp = lane >> 4;
    f32x4 acc[8];
#pragma unroll
    for (int ct = 0; ct < 8; ct++) acc[ct] = (f32x4){0.f, 0.f, 0.f, 0.f};

#pragma unroll
    for (int kt = 0; kt < 4; ++kt) {
        int kbase = kt * 32 + kgrp * 8;
        f16x8 a = *(const f16x8*)&XS[m0 + rlane][kbase];
#pragma unroll
        for (int ct = 0; ct < 8; ++ct) {
            f16x8 bfr = *(const f16x8*)&WT[ct * 16 + rlane][kbase];
            acc[ct] = __builtin_amdgcn_mfma_f32_16x16x32_f16(a, bfr, acc[ct], 0, 0, 0);
        }
    }

    int rgrp = lane >> 4;
    float dv[4];
    int gnr[4];
#pragma unroll
    for (int r = 0; r < 4; r++) {
        gnr[r] = n0 + m0 + rgrp * 4 + r;
        dv[r] = (gnr[r] < N) ? dinv[gnr[r]] : 0.f;
    }
#pragma unroll
    for (int ct = 0; ct < 8; ++ct) {
#pragma unroll
        for (int r = 0; r < 4; ++r) {
            if (gnr[r] < N)
                Q[(size_t)gnr[r] * HDIM + ct * 16 + rlane] = __float2half(acc[ct][r] * dv[r]);
        }
    }
}

// ---------------- fp16 row load: 4 channels (8B) ----------------
__device__ __forceinline__ float4 qrow4(const __half* __restrict__ Q, int e, int c4) {
    uint2 u = *(const uint2*)(Q + (size_t)e * HDIM + c4);
    float2 f0 = __half22float2(*(__half2*)&u.x);
    float2 f1 = __half22float2(*(__half2*)&u.y);
    return make_float4(f0.x, f0.y, f1.x, f1.y);
}

// ---------------- layer-2 CSR gather: PURE (no stats/LDS/barrier) ----------------
__global__ __launch_bounds__(256) void node_agg2(const int* __restrict__ col,
                                                 const int* __restrict__ rowStart,
                                                 const __half* __restrict__ Q,
                                                 const float* __restrict__ dinv,
                                                 const float* __restrict__ bias,
                                                 __half* __restrict__ A2, int N) {
    int wib = threadIdx.x >> 6;
    int lane = threadIdx.x & 63;
    int half = lane >> 5;
    int l = lane & 31;
    int c4 = l * 4;
    int n = blockIdx.x * 4 + wib;
    if (n >= N) return;
    float4 acc = make_float4(0.f, 0.f, 0.f, 0.f);
    int rs = rowStart[n], re = rowStart[n + 1];
    if (half == 0) acc = qrow4(Q, n, c4);          // self term
    int j = rs + half;
    for (; j + 14 < re; j += 16) {
        int e0 = col[j],      e1 = col[j + 2],  e2 = col[j + 4],  e3 = col[j + 6];
        int e4 = col[j + 8],  e5 = col[j + 10], e6 = col[j + 12], e7 = col[j + 14];
        float4 r0 = qrow4(Q, e0, c4);
        float4 r1 = qrow4(Q, e1, c4);
        float4 r2 = qrow4(Q, e2, c4);
        float4 r3 = qrow4(Q, e3, c4);
        float4 r4 = qrow4(Q, e4, c4);
        float4 r5 = qrow4(Q, e5, c4);
        float4 r6 = qrow4(Q, e6, c4);
        float4 r7 = qrow4(Q, e7, c4);
        acc.x += ((r0.x + r1.x) + (r2.x + r3.x)) + ((r4.x + r5.x) + (r6.x + r7.x));
        acc.y += ((r0.y + r1.y) + (r2.y + r3.y)) + ((r4.y + r5.y) + (r6.y + r7.y));
        acc.z += ((r0.z + r1.z) + (r2.z + r3.z)) + ((r4.z + r5.z) + (r6.z + r7.z));
        acc.w += ((r0.w + r1.w) + (r2.w + r3.w)) + ((r4.w + r5.w) + (r6.w + r7.w));
    }
    for (; j + 6 < re; j += 8) {
        int e0 = col[j], e1 = col[j + 2], e2 = col[j + 4], e3 = col[j + 6];
        float4 r0 = qrow4(Q, e0, c4);
        float4 r1 = qrow4(Q, e1, c4);
        float4 r2 = qrow4(Q, e2, c4);
        float4 r3 = qrow4(Q, e3, c4);
        acc.x += (r0.x + r1.x) + (r2.x + r3.x);
        acc.y += (r0.y + r1.y) + (r2.y + r3.y);
        acc.z += (r0.z + r1.z) + (r2.z + r3.z);
        acc.w += (r0.w + r1.w) + (r2.w + r3.w);
    }
    for (; j < re; j += 2) {
        float4 r = qrow4(Q, col[j], c4);
        acc.x += r.x; acc.y += r.y; acc.z += r.z; acc.w += r.w;
    }
    acc.x += __shfl_xor(acc.x, 32);
    acc.y += __shfl_xor(acc.y, 32);
    acc.z += __shfl_xor(acc.z, 32);
    acc.w += __shfl_xor(acc.w, 32);
    if (half == 0) {
        float dv = dinv[n];
        acc.x = acc.x * dv + bias[c4];
        acc.y = acc.y * dv + bias[c4 + 1];
        acc.z = acc.z * dv + bias[c4 + 2];
        acc.w = acc.w * dv + bias[c4 + 3];
        __half2 o0 = __floats2half2_rn(acc.x, acc.y);
        __half2 o1 = __floats2half2_rn(acc.z, acc.w);
        uint2 u;
        u.x = *(unsigned int*)&o0;
        u.y = *(unsigned int*)&o1;
        *(uint2*)(A2 + (size_t)n * HDIM + c4) = u;
    }
}

// ---------------- layer-2 norm+relu+pool: coalesced, batch-run flush ----------------
__global__ __launch_bounds__(256) void node_norm_pool(const __half* __restrict__ A2,
                                                      const float* __restrict__ gmean,
                                                      const float* __restrict__ gistd,
                                                      const float* __restrict__ alpha,
                                                      const float* __restrict__ w,
                                                      const float* __restrict__ bb,
                                                      const int* __restrict__ batch,
                                                      float* __restrict__ gpool, int N) {
    int t = threadIdx.x;
    int c = t & 127;
    int half_ = t >> 7;
    int n0 = blockIdx.x * 32;
    float ac = alpha[c], wc = w[c], bc = bb[c];
    float s = 0.f, mc = 0.f, ic = 0.f;
    int cur = -1;
    for (int i = half_; i < 32; i += 2) {
        int n = n0 + i;
        if (n >= N) break;
        int b = batch[n];
        if (b != cur) {
            if (cur >= 0) unsafeAtomicAdd(&gpool[(size_t)cur * HDIM + c], s);
            cur = b; s = 0.f;
            mc = gmean[(size_t)b * HDIM + c];
            ic = gistd[(size_t)b * HDIM + c];
        }
        float v = __half2float(A2[(size_t)n * HDIM + c]);
        s += fmaxf(wc * (v - ac * mc) * ic + bc, 0.f);
    }
    if (cur >= 0) unsafeAtomicAdd(&gpool[(size_t)cur * HDIM + c], s);
}

// ---------------- head ----------------
__global__ __launch_bounds__(128) void head(const float* __restrict__ gpool,
                                            const float* __restrict__ gcnt,
                                            const float* __restrict__ H1,
                                            const float* __restrict__ hb1,
                                            const float* __restrict__ H2,
                                            const float* __restrict__ hb2,
                                            float* __restrict__ out, int G) {
    __shared__ float gv[HDIM];
    __shared__ float tv[HDIM];
    __shared__ float r0[HDIM], r1[HDIM];
    int g = blockIdx.x;
    int c = threadIdx.x;
    float cnt = fmaxf(gcnt[g], 1.0f);
    gv[c] = gpool[(long long)g * HDIM + c] / cnt;
    __syncthreads();
    float s = hb1[c];
    for (int k = 0; k < HDIM; k++) s += gv[k] * H1[k * HDIM + c];
    tv[c] = fmaxf(s, 0.f);
    __syncthreads();
    r0[c] = tv[c] * H2[c * 2 + 0];
    r1[c] = tv[c] * H2[c * 2 + 1];
    __syncthreads();
    for (int off = 64; off > 0; off >>= 1) {
        if (c < off) { r0[c] += r0[c + off]; r1[c] += r1[c + off]; }
        __syncthreads();
    }
    if (c == 0) {
        out[(long long)g * 2 + 0] = r0[0] + hb2[0];
        out[(long long)g * 2 + 1] = r1[0] + hb2[1];
    }
}

extern "C" void kernel_launch(void* const* d_in, const int* in_sizes, int n_in,
                              void* d_out, int out_size, void* d_ws, size_t ws_size,
                              hipStream_t stream) {
    const float* x    = (const float*)d_in[0];
    const int*   ei   = (const int*)d_in[1];
    const int*   batch= (const int*)d_in[2];
    const float* W1   = (const float*)d_in[4];
    const float* b1   = (const float*)d_in[5];
    const float* gn1w = (const float*)d_in[6];
    const float* gn1b = (const float*)d_in[7];
    const float* gn1a = (const float*)d_in[8];
    const float* W2   = (const float*)d_in[9];
    const float* b2   = (const float*)d_in[10];
    const float* gn2w = (const float*)d_in[11];
    const float* gn2b = (const float*)d_in[12];
    const float* gn2a = (const float*)d_in[13];
    const float* H1   = (const float*)d_in[14];
    const float* hb1  = (const float*)d_in[15];
    const float* H2   = (const float*)d_in[16];
    const float* hb2  = (const float*)d_in[17];

    int N = in_sizes[0] / 7;
    int E = in_sizes[1] / 2;
    int G = out_size / 2;
    const int* srcI = ei;
    const int* dstI = ei + E;

    int NB = (N + BKT_SIZE - 1) >> BKT_SHIFT;      // 391 buckets of 256 nodes
    int NCHUNK = (E + CHK - 1) / CHK;              // 782 chunks of 4096 edges

    // workspace layout
    __half* A16   = (__half*)d_ws;                   // N*128 half (layer1 pre-norm)
    __half* A2    = A16;                             // alias (layer2 pre-norm; A16 dead by then)
    __half* Q16   = A16 + (size_t)N * HDIM;          // N*128 half
    float*  xs    = (float*)(Q16 + (size_t)N * HDIM);// N*8
    float*  gsum1 = xs + (size_t)N * 8;              // G*128
    float*  gsq1  = gsum1 + (size_t)G * HDIM;        // G*128
    float*  gsum2 = gsq1 + (size_t)G * HDIM;         // G*128
    float*  gsq2  = gsum2 + (size_t)G * HDIM;        // G*128
    float*  gpool = gsq2 + (size_t)G * HDIM;         // G*128
    float*  gcnt  = gpool + (size_t)G * HDIM;        // G
    float*  dinv  = gcnt + G;                        // N
    int* rowStart = (int*)(dinv + N);                // N+2
    unsigned int* EP = (unsigned int*)(rowStart + N + 2); // E
    int* col      = (int*)(EP + E);                  // E
    int* histG    = col + E;                         // NCHUNK*NB
    int* tot      = histG + (size_t)NCHUNK * NB;     // NB+2
    int* bucketBase = tot + NB + 2;                  // NB+2
    __half* W2t   = (__half*)(bucketBase + NB + 2);  // 128*128 half

    int gridNW = (N + 3) / 4;
    int gridGH = (G * HDIM + 255) / 256;
    int gridMM = (N + 63) / 64;
    int gridNS = (N + 31) / 32;

    // single upfront memset: gsum1,gsq1,gsum2,gsq2,gpool
    hipMemsetAsync(gsum1, 0, (size_t)G * HDIM * 5 * 4, stream);

    // ---- CSR build ----
    hist_pass<<<NCHUNK, 256, 0, stream>>>(dstI, histG, E, NB);
    scan_chunks<<<NB, 1024, 0, stream>>>(histG, tot, NCHUNK, NB);
    scan_tot_k<<<1, 512, 0, stream>>>(tot, bucketBase, rowStart, NB, N, E);
    scatter_bkt<<<NCHUNK, 256, 0, stream>>>(srcI, dstI, histG, bucketBase, EP, E, NB);
    bucket_csr<<<NB, 512, 0, stream>>>(EP, bucketBase, rowStart, dinv, col, N);

    // ---- setup: W2^T fp16 + per-graph counts ----
    setup_misc<<<(HDIM * HDIM + G + 255) / 256, 256, 0, stream>>>(W2, W2t, batch, gcnt, N, G);

    // ---- block 1: fused rank-7 aggregation + W1 matmul ----
    long long nx8 = (long long)N * 8;
    prep_xs<<<(int)((nx8 + 255) / 256), 256, 0, stream>>>(x, dinv, xs, nx8);
    aggl1<<<gridNW, 256, 0, stream>>>(col, rowStart, xs, W1, b1, dinv, A16, N);
    stats2<<<gridNS, 256, 0, stream>>>(A16, batch, gsum1, gsq1, N);
    gstat<<<gridGH, 256, 0, stream>>>(gsum1, gsq1, gcnt, gn1a, G * HDIM);

    // ---- hidden matmul via MFMA, fused layer-1 norm+relu, fp16 in/out ----
    mm_h_mfma<<<gridMM, 256, 0, stream>>>(A16, gsum1, gsq1, gn1a, gn1w, gn1b, batch,
                                          W2t, dinv, Q16, N);

    // ---- block 2 (pure fp16 gather) ----
    node_agg2<<<gridNW, 256, 0, stream>>>(col, rowStart, Q16, dinv, b2, A2, N);
    stats2<<<gridNS, 256, 0, stream>>>(A2, batch, gsum2, gsq2, N);
    gstat<<<gridGH, 256, 0, stream>>>(gsum2, gsq2, gcnt, gn2a, G * HDIM);

    // ---- layer-2 norm + relu + pool ----
    node_norm_pool<<<gridNS, 256, 0, stream>>>(A2, gsum2, gsq2, gn2a, gn2w, gn2b, batch, gpool, N);

    // ---- head ----
    head<<<G, 128, 0, stream>>>(gpool, gcnt, H1, hb1, H2, hb2, (float*)d_out, G);
}

// Round 13
// 349.441 us; speedup vs baseline: 1.9267x; 1.0069x over previous
//
#include <hip/hip_runtime.h>
#include <hip/hip_fp16.h>

#define EPSV 1e-5f
#define HDIM 128
#define BKT_SHIFT 8
#define BKT_SIZE 256
#define NBMAX 512
#define CHK 4096
#define EPLDS 12288   // LDS-cached edges per bucket (48 KB); mean ~8184, 4-sigma ~8550

typedef _Float16 f16x8 __attribute__((ext_vector_type(8)));
typedef float f32x4 __attribute__((ext_vector_type(4)));

// ================= CSR build: bucketed counting sort =================

__global__ __launch_bounds__(256) void hist_pass(const int* __restrict__ dst,
                                                 int* __restrict__ histG, int E, int NB) {
    __shared__ int h[NBMAX];
    int t = threadIdx.x;
    for (int i = t; i < NB; i += 256) h[i] = 0;
    __syncthreads();
    int base = blockIdx.x * CHK;
    int end = min(base + CHK, E);
    for (int e = base + t; e < end; e += 256) atomicAdd(&h[dst[e] >> BKT_SHIFT], 1);
    __syncthreads();
    for (int i = t; i < NB; i += 256) histG[(size_t)blockIdx.x * NB + i] = h[i];
}

// per-bucket exclusive scan over chunks via wave shfl scan
__global__ __launch_bounds__(1024) void scan_chunks(int* __restrict__ histG,
                                                    int* __restrict__ tot,
                                                    int NCHUNK, int NB) {
    __shared__ int wsum[16];
    int b = blockIdx.x, t = threadIdx.x;
    int lane = t & 63, w = t >> 6;
    int v = (t < NCHUNK) ? histG[(size_t)t * NB + b] : 0;
    int iv = v;
#pragma unroll
    for (int off = 1; off < 64; off <<= 1) {
        int x = __shfl_up(iv, off);
        if (lane >= off) iv += x;
    }
    if (lane == 63) wsum[w] = iv;
    __syncthreads();
    int woff = 0;
    for (int i = 0; i < w; i++) woff += wsum[i];
    int incl = iv + woff;
    if (t < NCHUNK) histG[(size_t)t * NB + b] = incl - v;
    if (t == 1023) tot[b] = incl;
}

// exclusive scan over buckets via wave shfl scan
__global__ __launch_bounds__(512) void scan_tot_k(const int* __restrict__ tot,
                                                  int* __restrict__ bucketBase,
                                                  int* __restrict__ rowStart,
                                                  int NB, int N, int E) {
    __shared__ int wsum[8];
    int t = threadIdx.x, lane = t & 63, w = t >> 6;
    int v = (t < NB) ? tot[t] : 0;
    int iv = v;
#pragma unroll
    for (int off = 1; off < 64; off <<= 1) {
        int x = __shfl_up(iv, off);
        if (lane >= off) iv += x;
    }
    if (lane == 63) wsum[w] = iv;
    __syncthreads();
    int woff = 0;
    for (int i = 0; i < w; i++) woff += wsum[i];
    int incl = iv + woff;
    if (t < NB) bucketBase[t] = incl - v;
    if (t == NB - 1) {
        bucketBase[NB] = incl;
        rowStart[N] = E;
    }
}

// scatter with bucketBase folded into cursor init
__global__ __launch_bounds__(256) void scatter_bkt(const int* __restrict__ src,
                                                   const int* __restrict__ dst,
                                                   const int* __restrict__ chunkOff,
                                                   const int* __restrict__ bucketBase,
                                                   unsigned int* __restrict__ EP,
                                                   int E, int NB) {
    __shared__ int cur[NBMAX];
    int t = threadIdx.x, c = blockIdx.x;
    for (int i = t; i < NB; i += 256)
        cur[i] = chunkOff[(size_t)c * NB + i] + bucketBase[i];
    __syncthreads();
    int base = c * CHK, end = min(base + CHK, E);
    for (int e = base + t; e < end; e += 256) {
        int d = dst[e];
        int b = d >> BKT_SHIFT;
        int pos = atomicAdd(&cur[b], 1);
        EP[pos] = (unsigned int)src[e] | ((unsigned int)(d & (BKT_SIZE - 1)) << 23);
    }
}

// per-bucket exact counting sort with LDS-cached EP slice; also emits dinv + xs rows
__global__ __launch_bounds__(512) void bucket_csr(const unsigned int* __restrict__ EP,
                                                  const int* __restrict__ bucketBase,
                                                  const float* __restrict__ x,
                                                  int* __restrict__ rowStart,
                                                  float* __restrict__ dinv,
                                                  float* __restrict__ xs,
                                                  int* __restrict__ col, int N) {
    __shared__ unsigned int eph[EPLDS];
    __shared__ int cnt[BKT_SIZE];
    __shared__ int wsum[4];
    int b = blockIdx.x, t = threadIdx.x;
    int ebase = bucketBase[b], eend = bucketBase[b + 1];
    int m = eend - ebase;
    int ml = min(m, EPLDS);
    for (int e = t; e < ml; e += 512) eph[e] = EP[ebase + e];
    if (t < BKT_SIZE) cnt[t] = 0;
    __syncthreads();
    for (int e = t; e < m; e += 512) {
        unsigned int p = (e < ml) ? eph[e] : EP[ebase + e];
        atomicAdd(&cnt[(p >> 23) & (BKT_SIZE - 1)], 1);
    }
    __syncthreads();
    int v = 0, iv = 0;
    if (t < BKT_SIZE) {
        v = cnt[t];
        iv = v;
        int lane = t & 63;
#pragma unroll
        for (int off = 1; off < 64; off <<= 1) {
            int xsh = __shfl_up(iv, off);
            if (lane >= off) iv += xsh;
        }
        if (lane == 63) wsum[t >> 6] = iv;
    }
    __syncthreads();
    if (t < BKT_SIZE) {
        int w = t >> 6;
        int woff = 0;
        for (int i = 0; i < w; i++) woff += wsum[i];
        int excl = iv + woff - v;
        int n = (b << BKT_SHIFT) + t;
        if (n < N) {
            rowStart[n] = ebase + excl;
            float dv = rsqrtf((float)v + 1.0f);
            dinv[n] = dv;
            const float* xr = x + (size_t)n * 7;
            float* xo = xs + (size_t)n * 8;
#pragma unroll
            for (int k = 0; k < 7; k++) xo[k] = xr[k] * dv;
            xo[7] = 0.f;
        }
        cnt[t] = ebase + excl;   // reuse as cursor
    }
    __syncthreads();
    for (int e = t; e < m; e += 512) {
        unsigned int p = (e < ml) ? eph[e] : EP[ebase + e];
        int pos = atomicAdd(&cnt[(p >> 23) & (BKT_SIZE - 1)], 1);
        col[pos] = (int)(p & 0x7FFFFFu);
    }
}

// ---------------- setup: W2^T fp16 + per-graph counts (sorted batch, binary search) ----------------
__device__ __forceinline__ int lbound(const int* __restrict__ b, int N, int key) {
    int lo = 0, hi = N;
    while (lo < hi) {
        int mid = (lo + hi) >> 1;
        if (b[mid] < key) lo = mid + 1; else hi = mid;
    }
    return lo;
}

__global__ __launch_bounds__(256) void setup_misc(const float* __restrict__ W2,
                                                  __half* __restrict__ W2t,
                                                  const int* __restrict__ batch,
                                                  float* __restrict__ gcnt, int N, int G) {
    int i = blockIdx.x * 256 + threadIdx.x;
    if (i < HDIM * HDIM) {
        int c = i >> 7, k = i & 127;
        W2t[c * HDIM + k] = __float2half(W2[k * HDIM + c]);
    } else if (i - HDIM * HDIM < G) {
        int g = i - HDIM * HDIM;
        gcnt[g] = (float)(lbound(batch, N, g + 1) - lbound(batch, N, g));
    }
}

// ---------------- fused layer-1: gather (32 streams x float4) + W1 matmul -> A16 ----------------
__global__ __launch_bounds__(256) void aggl1(const int* __restrict__ col,
                                             const int* __restrict__ rowStart,
                                             const float* __restrict__ xs,
                                             const float* __restrict__ W1,
                                             const float* __restrict__ b1,
                                             const float* __restrict__ dinv,
                                             __half* __restrict__ A16, int N) {
    __shared__ float w1s[7 * HDIM];
    __shared__ float aggs[4][8];
    int t = threadIdx.x;
    for (int i = t; i < 7 * HDIM; i += 256) w1s[i] = W1[i];
    int wib = t >> 6, lane = t & 63;
    int stream = lane >> 1;          // 0..31
    int c4 = (lane & 1) * 4;         // channel quad
    int n = blockIdx.x * 4 + wib;
    float4 acc = make_float4(0.f, 0.f, 0.f, 0.f);
    if (n < N) {
        int rs = rowStart[n], re = rowStart[n + 1];
        if (stream == 0) acc = *(const float4*)(xs + (size_t)n * 8 + c4);   // self
        int j = rs + stream;
        for (; j + 32 < re; j += 64) {
            int e0 = col[j], e1 = col[j + 32];
            float4 r0 = *(const float4*)(xs + (size_t)e0 * 8 + c4);
            float4 r1 = *(const float4*)(xs + (size_t)e1 * 8 + c4);
            acc.x += r0.x + r1.x;
            acc.y += r0.y + r1.y;
            acc.z += r0.z + r1.z;
            acc.w += r0.w + r1.w;
        }
        for (; j < re; j += 32) {
            float4 r = *(const float4*)(xs + (size_t)col[j] * 8 + c4);
            acc.x += r.x; acc.y += r.y; acc.z += r.z; acc.w += r.w;
        }
#pragma unroll
        for (int off = 2; off <= 32; off <<= 1) {
            acc.x += __shfl_xor(acc.x, off);
            acc.y += __shfl_xor(acc.y, off);
            acc.z += __shfl_xor(acc.z, off);
            acc.w += __shfl_xor(acc.w, off);
        }
        if (stream == 0) *(float4*)&aggs[wib][c4] = acc;
    }
    __syncthreads();
    if (n < N) {
        float ar[7];
#pragma unroll
        for (int k = 0; k < 7; k++) ar[k] = aggs[wib][k];
        float dv = dinv[n];
        int c = lane * 2;
        float s0 = 0.f, s1 = 0.f;
#pragma unroll
        for (int k = 0; k < 7; k++) {
            s0 += ar[k] * w1s[k * HDIM + c];
            s1 += ar[k] * w1s[k * HDIM + c + 1];
        }
        *(__half2*)(A16 + (size_t)n * HDIM + c) =
            __floats2half2_rn(s0 * dv + b1[c], s1 * dv + b1[c + 1]);
    }
}

// ---------------- coalesced GraphNorm stats over fp16 matrix, batch-run flush ----------------
__global__ __launch_bounds__(256) void stats2(const __half* __restrict__ X,
                                              const int* __restrict__ batch,
                                              float* __restrict__ gsum,
                                              float* __restrict__ gsq, int N) {
    int t = threadIdx.x;
    int c = t & 127;
    int half_ = t >> 7;
    int n0 = blockIdx.x * 32;
    float s = 0.f, q = 0.f;
    int cur = -1;
    for (int i = half_; i < 32; i += 2) {
        int n = n0 + i;
        if (n >= N) break;
        int b = batch[n];
        if (b != cur) {
            if (cur >= 0) {
                unsafeAtomicAdd(&gsum[(size_t)cur * HDIM + c], s);
                unsafeAtomicAdd(&gsq[(size_t)cur * HDIM + c], q);
            }
            cur = b; s = 0.f; q = 0.f;
        }
        float v = __half2float(X[(size_t)n * HDIM + c]);
        s += v; q += v * v;
    }
    if (cur >= 0) {
        unsafeAtomicAdd(&gsum[(size_t)cur * HDIM + c], s);
        unsafeAtomicAdd(&gsq[(size_t)cur * HDIM + c], q);
    }
}

// ---------------- per-(graph,channel): sums -> mean, inv-std ----------------
__global__ __launch_bounds__(256) void gstat(float* __restrict__ gsum,
                                             float* __restrict__ gsq,
                                             const float* __restrict__ gcnt,
                                             const float* __restrict__ alpha, int total) {
    int i = blockIdx.x * 256 + threadIdx.x;
    if (i < total) {
        int g = i >> 7, c = i & 127;
        float cnt = fmaxf(gcnt[g], 1.f);
        float mean = gsum[i] / cnt;
        float m2 = gsq[i] / cnt;
        float a = alpha[c];
        float var = m2 + mean * mean * (a * a - 2.f * a);
        gsum[i] = mean;
        gsq[i] = rsqrtf(fmaxf(var, 0.f) + EPSV);
    }
}

// ---------------- hidden matmul via MFMA: Q = half(dinv * (relu(norm(A16)) @ W2)) ----------------
__global__ __launch_bounds__(256) void mm_h_mfma(const __half* __restrict__ A16,
                                                 const float* __restrict__ gmean,
                                                 const float* __restrict__ gistd,
                                                 const float* __restrict__ alpha,
                                                 const float* __restrict__ w,
                                                 const float* __restrict__ bb,
                                                 const int* __restrict__ batch,
                                                 const __half* __restrict__ W2t,
                                                 const float* __restrict__ dinv,
                                                 __half* __restrict__ Q, int N) {
    __shared__ _Float16 XS[64][136];
    __shared__ _Float16 WT[HDIM][136];
    __shared__ float pA[HDIM], pW[HDIM], pB[HDIM];
    int t = threadIdx.x;
    for (int i = t; i < HDIM; i += 256) { pA[i] = alpha[i]; pW[i] = w[i]; pB[i] = bb[i]; }
    int n0 = blockIdx.x * 64;

    for (int i = t; i < HDIM * 16; i += 256) {
        int row = i >> 4;
        int kk = (i & 15) * 8;
        *(uint4*)&WT[row][kk] = *(const uint4*)(W2t + (size_t)row * HDIM + kk);
    }
    __syncthreads();

    for (int i = t; i < 64 * 16; i += 256) {
        int nn = i >> 4;
        int kk = (i & 15) * 8;
        int gn = n0 + nn;
        __half hv[8];
#pragma unroll
        for (int k = 0; k < 8; k++) hv[k] = __float2half(0.f);
        if (gn < N) {
            uint4 u = *(const uint4*)(A16 + (size_t)gn * HDIM + kk);
            int b = batch[gn];
            const float* mp = gmean + (size_t)b * HDIM + kk;
            const float* ip = gistd + (size_t)b * HDIM + kk;
            float2 f0 = __half22float2(*(__half2*)&u.x);
            float2 f1 = __half22float2(*(__half2*)&u.y);
            float2 f2 = __half22float2(*(__half2*)&u.z);
            float2 f3 = __half22float2(*(__half2*)&u.w);
            float f[8] = {f0.x, f0.y, f1.x, f1.y, f2.x, f2.y, f3.x, f3.y};
#pragma unroll
            for (int k = 0; k < 8; k++) {
                int c = kk + k;
                hv[k] = __float2half(fmaxf(pW[c] * (f[k] - pA[c] * mp[k]) * ip[k] + pB[c], 0.f));
            }
        }
        *(uint4*)&XS[nn][kk] = *(uint4*)hv;
    }
    __syncthreads();

    int wid = t >> 6, lane = t & 63;
    int m0 = wid * 16;
    int rlane = lane & 15;
    int kgrp = lane >> 4;
    f32x4 acc[8];
#pragma unroll
    for (int ct = 0; ct < 8; ct++) acc[ct] = (f32x4){0.f, 0.f, 0.f, 0.f};

#pragma unroll
    for (int kt = 0; kt < 4; ++kt) {
        int kbase = kt * 32 + kgrp * 8;
        f16x8 a = *(const f16x8*)&XS[m0 + rlane][kbase];
#pragma unroll
        for (int ct = 0; ct < 8; ++ct) {
            f16x8 bfr = *(const f16x8*)&WT[ct * 16 + rlane][kbase];
            acc[ct] = __builtin_amdgcn_mfma_f32_16x16x32_f16(a, bfr, acc[ct], 0, 0, 0);
        }
    }

    int rgrp = lane >> 4;
    float dv[4];
    int gnr[4];
#pragma unroll
    for (int r = 0; r < 4; r++) {
        gnr[r] = n0 + m0 + rgrp * 4 + r;
        dv[r] = (gnr[r] < N) ? dinv[gnr[r]] : 0.f;
    }
#pragma unroll
    for (int ct = 0; ct < 8; ++ct) {
#pragma unroll
        for (int r = 0; r < 4; ++r) {
            if (gnr[r] < N)
                Q[(size_t)gnr[r] * HDIM + ct * 16 + rlane] = __float2half(acc[ct][r] * dv[r]);
        }
    }
}

// ---------------- fp16 row load: 4 channels (8B) ----------------
__device__ __forceinline__ float4 qrow4(const __half* __restrict__ Q, int e, int c4) {
    uint2 u = *(const uint2*)(Q + (size_t)e * HDIM + c4);
    float2 f0 = __half22float2(*(__half2*)&u.x);
    float2 f1 = __half22float2(*(__half2*)&u.y);
    return make_float4(f0.x, f0.y, f1.x, f1.y);
}

// ---------------- layer-2 CSR gather: PURE (no stats/LDS/barrier) ----------------
__global__ __launch_bounds__(256) void node_agg2(const int* __restrict__ col,
                                                 const int* __restrict__ rowStart,
                                                 const __half* __restrict__ Q,
                                                 const float* __restrict__ dinv,
                                                 const float* __restrict__ bias,
                                                 __half* __restrict__ A2, int N) {
    int wib = threadIdx.x >> 6;
    int lane = threadIdx.x & 63;
    int half = lane >> 5;
    int l = lane & 31;
    int c4 = l * 4;
    int n = blockIdx.x * 4 + wib;
    if (n >= N) return;
    float4 acc = make_float4(0.f, 0.f, 0.f, 0.f);
    int rs = rowStart[n], re = rowStart[n + 1];
    if (half == 0) acc = qrow4(Q, n, c4);          // self term
    int j = rs + half;
    for (; j + 14 < re; j += 16) {
        int e0 = col[j],      e1 = col[j + 2],  e2 = col[j + 4],  e3 = col[j + 6];
        int e4 = col[j + 8],  e5 = col[j + 10], e6 = col[j + 12], e7 = col[j + 14];
        float4 r0 = qrow4(Q, e0, c4);
        float4 r1 = qrow4(Q, e1, c4);
        float4 r2 = qrow4(Q, e2, c4);
        float4 r3 = qrow4(Q, e3, c4);
        float4 r4 = qrow4(Q, e4, c4);
        float4 r5 = qrow4(Q, e5, c4);
        float4 r6 = qrow4(Q, e6, c4);
        float4 r7 = qrow4(Q, e7, c4);
        acc.x += ((r0.x + r1.x) + (r2.x + r3.x)) + ((r4.x + r5.x) + (r6.x + r7.x));
        acc.y += ((r0.y + r1.y) + (r2.y + r3.y)) + ((r4.y + r5.y) + (r6.y + r7.y));
        acc.z += ((r0.z + r1.z) + (r2.z + r3.z)) + ((r4.z + r5.z) + (r6.z + r7.z));
        acc.w += ((r0.w + r1.w) + (r2.w + r3.w)) + ((r4.w + r5.w) + (r6.w + r7.w));
    }
    for (; j + 6 < re; j += 8) {
        int e0 = col[j], e1 = col[j + 2], e2 = col[j + 4], e3 = col[j + 6];
        float4 r0 = qrow4(Q, e0, c4);
        float4 r1 = qrow4(Q, e1, c4);
        float4 r2 = qrow4(Q, e2, c4);
        float4 r3 = qrow4(Q, e3, c4);
        acc.x += (r0.x + r1.x) + (r2.x + r3.x);
        acc.y += (r0.y + r1.y) + (r2.y + r3.y);
        acc.z += (r0.z + r1.z) + (r2.z + r3.z);
        acc.w += (r0.w + r1.w) + (r2.w + r3.w);
    }
    for (; j < re; j += 2) {
        float4 r = qrow4(Q, col[j], c4);
        acc.x += r.x; acc.y += r.y; acc.z += r.z; acc.w += r.w;
    }
    acc.x += __shfl_xor(acc.x, 32);
    acc.y += __shfl_xor(acc.y, 32);
    acc.z += __shfl_xor(acc.z, 32);
    acc.w += __shfl_xor(acc.w, 32);
    if (half == 0) {
        float dv = dinv[n];
        acc.x = acc.x * dv + bias[c4];
        acc.y = acc.y * dv + bias[c4 + 1];
        acc.z = acc.z * dv + bias[c4 + 2];
        acc.w = acc.w * dv + bias[c4 + 3];
        __half2 o0 = __floats2half2_rn(acc.x, acc.y);
        __half2 o1 = __floats2half2_rn(acc.z, acc.w);
        uint2 u;
        u.x = *(unsigned int*)&o0;
        u.y = *(unsigned int*)&o1;
        *(uint2*)(A2 + (size_t)n * HDIM + c4) = u;
    }
}

// ---------------- layer-2 norm+relu+pool: coalesced, batch-run flush ----------------
__global__ __launch_bounds__(256) void node_norm_pool(const __half* __restrict__ A2,
                                                      const float* __restrict__ gmean,
                                                      const float* __restrict__ gistd,
                                                      const float* __restrict__ alpha,
                                                      const float* __restrict__ w,
                                                      const float* __restrict__ bb,
                                                      const int* __restrict__ batch,
                                                      float* __restrict__ gpool, int N) {
    int t = threadIdx.x;
    int c = t & 127;
    int half_ = t >> 7;
    int n0 = blockIdx.x * 32;
    float ac = alpha[c], wc = w[c], bc = bb[c];
    float s = 0.f, mc = 0.f, ic = 0.f;
    int cur = -1;
    for (int i = half_; i < 32; i += 2) {
        int n = n0 + i;
        if (n >= N) break;
        int b = batch[n];
        if (b != cur) {
            if (cur >= 0) unsafeAtomicAdd(&gpool[(size_t)cur * HDIM + c], s);
            cur = b; s = 0.f;
            mc = gmean[(size_t)b * HDIM + c];
            ic = gistd[(size_t)b * HDIM + c];
        }
        float v = __half2float(A2[(size_t)n * HDIM + c]);
        s += fmaxf(wc * (v - ac * mc) * ic + bc, 0.f);
    }
    if (cur >= 0) unsafeAtomicAdd(&gpool[(size_t)cur * HDIM + c], s);
}

// ---------------- head ----------------
__global__ __launch_bounds__(128) void head(const float* __restrict__ gpool,
                                            const float* __restrict__ gcnt,
                                            const float* __restrict__ H1,
                                            const float* __restrict__ hb1,
                                            const float* __restrict__ H2,
                                            const float* __restrict__ hb2,
                                            float* __restrict__ out, int G) {
    __shared__ float gv[HDIM];
    __shared__ float tv[HDIM];
    __shared__ float r0[HDIM], r1[HDIM];
    int g = blockIdx.x;
    int c = threadIdx.x;
    float cnt = fmaxf(gcnt[g], 1.0f);
    gv[c] = gpool[(long long)g * HDIM + c] / cnt;
    __syncthreads();
    float s = hb1[c];
    for (int k = 0; k < HDIM; k++) s += gv[k] * H1[k * HDIM + c];
    tv[c] = fmaxf(s, 0.f);
    __syncthreads();
    r0[c] = tv[c] * H2[c * 2 + 0];
    r1[c] = tv[c] * H2[c * 2 + 1];
    __syncthreads();
    for (int off = 64; off > 0; off >>= 1) {
        if (c < off) { r0[c] += r0[c + off]; r1[c] += r1[c + off]; }
        __syncthreads();
    }
    if (c == 0) {
        out[(long long)g * 2 + 0] = r0[0] + hb2[0];
        out[(long long)g * 2 + 1] = r1[0] + hb2[1];
    }
}

extern "C" void kernel_launch(void* const* d_in, const int* in_sizes, int n_in,
                              void* d_out, int out_size, void* d_ws, size_t ws_size,
                              hipStream_t stream) {
    const float* x    = (const float*)d_in[0];
    const int*   ei   = (const int*)d_in[1];
    const int*   batch= (const int*)d_in[2];
    const float* W1   = (const float*)d_in[4];
    const float* b1   = (const float*)d_in[5];
    const float* gn1w = (const float*)d_in[6];
    const float* gn1b = (const float*)d_in[7];
    const float* gn1a = (const float*)d_in[8];
    const float* W2   = (const float*)d_in[9];
    const float* b2   = (const float*)d_in[10];
    const float* gn2w = (const float*)d_in[11];
    const float* gn2b = (const float*)d_in[12];
    const float* gn2a = (const float*)d_in[13];
    const float* H1   = (const float*)d_in[14];
    const float* hb1  = (const float*)d_in[15];
    const float* H2   = (const float*)d_in[16];
    const float* hb2  = (const float*)d_in[17];

    int N = in_sizes[0] / 7;
    int E = in_sizes[1] / 2;
    int G = out_size / 2;
    const int* srcI = ei;
    const int* dstI = ei + E;

    int NB = (N + BKT_SIZE - 1) >> BKT_SHIFT;      // 391 buckets of 256 nodes
    int NCHUNK = (E + CHK - 1) / CHK;              // 782 chunks of 4096 edges

    // workspace layout
    __half* A16   = (__half*)d_ws;                   // N*128 half (layer1 pre-norm)
    __half* A2    = A16;                             // alias (layer2 pre-norm; A16 dead by then)
    __half* Q16   = A16 + (size_t)N * HDIM;          // N*128 half
    float*  xs    = (float*)(Q16 + (size_t)N * HDIM);// N*8
    float*  gsum1 = xs + (size_t)N * 8;              // G*128
    float*  gsq1  = gsum1 + (size_t)G * HDIM;        // G*128
    float*  gsum2 = gsq1 + (size_t)G * HDIM;         // G*128
    float*  gsq2  = gsum2 + (size_t)G * HDIM;        // G*128
    float*  gpool = gsq2 + (size_t)G * HDIM;         // G*128
    float*  gcnt  = gpool + (size_t)G * HDIM;        // G
    float*  dinv  = gcnt + G;                        // N
    int* rowStart = (int*)(dinv + N);                // N+2
    unsigned int* EP = (unsigned int*)(rowStart + N + 2); // E
    int* col      = (int*)(EP + E);                  // E
    int* histG    = col + E;                         // NCHUNK*NB
    int* tot      = histG + (size_t)NCHUNK * NB;     // NB+2
    int* bucketBase = tot + NB + 2;                  // NB+2
    __half* W2t   = (__half*)(bucketBase + NB + 2);  // 128*128 half

    int gridNW = (N + 3) / 4;
    int gridGH = (G * HDIM + 255) / 256;
    int gridMM = (N + 63) / 64;
    int gridNS = (N + 31) / 32;

    // single upfront memset: gsum1,gsq1,gsum2,gsq2,gpool
    hipMemsetAsync(gsum1, 0, (size_t)G * HDIM * 5 * 4, stream);

    // ---- CSR build ----
    hist_pass<<<NCHUNK, 256, 0, stream>>>(dstI, histG, E, NB);
    scan_chunks<<<NB, 1024, 0, stream>>>(histG, tot, NCHUNK, NB);
    scan_tot_k<<<1, 512, 0, stream>>>(tot, bucketBase, rowStart, NB, N, E);
    scatter_bkt<<<NCHUNK, 256, 0, stream>>>(srcI, dstI, histG, bucketBase, EP, E, NB);
    bucket_csr<<<NB, 512, 0, stream>>>(EP, bucketBase, x, rowStart, dinv, xs, col, N);

    // ---- setup: W2^T fp16 + per-graph counts ----
    setup_misc<<<(HDIM * HDIM + G + 255) / 256, 256, 0, stream>>>(W2, W2t, batch, gcnt, N, G);

    // ---- block 1: fused rank-7 aggregation + W1 matmul ----
    aggl1<<<gridNW, 256, 0, stream>>>(col, rowStart, xs, W1, b1, dinv, A16, N);
    stats2<<<gridNS, 256, 0, stream>>>(A16, batch, gsum1, gsq1, N);
    gstat<<<gridGH, 256, 0, stream>>>(gsum1, gsq1, gcnt, gn1a, G * HDIM);

    // ---- hidden matmul via MFMA, fused layer-1 norm+relu, fp16 in/out ----
    mm_h_mfma<<<gridMM, 256, 0, stream>>>(A16, gsum1, gsq1, gn1a, gn1w, gn1b, batch,
                                          W2t, dinv, Q16, N);

    // ---- block 2 (pure fp16 gather) ----
    node_agg2<<<gridNW, 256, 0, stream>>>(col, rowStart, Q16, dinv, b2, A2, N);
    stats2<<<gridNS, 256, 0, stream>>>(A2, batch, gsum2, gsq2, N);
    gstat<<<gridGH, 256, 0, stream>>>(gsum2, gsq2, gcnt, gn2a, G * HDIM);

    // ---- layer-2 norm + relu + pool ----
    node_norm_pool<<<gridNS, 256, 0, stream>>>(A2, gsum2, gsq2, gn2a, gn2w, gn2b, batch, gpool, N);

    // ---- head ----
    head<<<G, 128, 0, stream>>>(gpool, gcnt, H1, hb1, H2, hb2, (float*)d_out, G);
}

// Round 14
// 341.133 us; speedup vs baseline: 1.9737x; 1.0244x over previous
//
#include <hip/hip_runtime.h>
#include <hip/hip_fp16.h>

#define EPSV 1e-5f
#define HDIM 128
#define BKT_SHIFT 8
#define BKT_SIZE 256
#define NBMAX 512
#define CHK 4096
#define EPCAP 12288   // padded slab per bucket; mean 8184, sigma ~90 -> 45-sigma margin
#define EPLDS 12288

typedef _Float16 f16x8 __attribute__((ext_vector_type(8)));
typedef float f32x4 __attribute__((ext_vector_type(4)));

// ---------------- binary search helper ----------------
__device__ __forceinline__ int lbound(const int* __restrict__ b, int N, int key) {
    int lo = 0, hi = N;
    while (lo < hi) {
        int mid = (lo + hi) >> 1;
        if (b[mid] < key) lo = mid + 1; else hi = mid;
    }
    return lo;
}

// ================= CSR build: direct bucket scatter (padded slabs) =================
// blocks [0, NCHUNK): scatter edges into EP[b*EPCAP + ...] via global range reservation
// blocks [NCHUNK, ...): setup work (W2^T fp16, per-graph counts)
__global__ __launch_bounds__(256) void scatter_direct(const int* __restrict__ src,
                                                      const int* __restrict__ dst,
                                                      int* __restrict__ gcur,
                                                      unsigned int* __restrict__ EP,
                                                      const float* __restrict__ W2,
                                                      __half* __restrict__ W2t,
                                                      const int* __restrict__ batch,
                                                      float* __restrict__ gcnt,
                                                      int E, int NB, int NCHUNK, int N, int G) {
    int blk = blockIdx.x;
    int t = threadIdx.x;
    if (blk >= NCHUNK) {
        int i = (blk - NCHUNK) * 256 + t;
        if (i < HDIM * HDIM) {
            int c = i >> 7, k = i & 127;
            W2t[c * HDIM + k] = __float2half(W2[k * HDIM + c]);
        } else if (i - HDIM * HDIM < G) {
            int g = i - HDIM * HDIM;
            gcnt[g] = (float)(lbound(batch, N, g + 1) - lbound(batch, N, g));
        }
        return;
    }
    __shared__ int h[NBMAX];
    __shared__ int dsh[CHK];
    for (int i = t; i < NB; i += 256) h[i] = 0;
    __syncthreads();
    int base = blk * CHK;
    int m = min(CHK, E - base);
    for (int e = t; e < m; e += 256) {
        int d = dst[base + e];
        dsh[e] = d;
        atomicAdd(&h[d >> BKT_SHIFT], 1);
    }
    __syncthreads();
    for (int i = t; i < NB; i += 256) {
        int c = h[i];
        h[i] = c ? atomicAdd(&gcur[i], c) : 0;   // reserve range; h becomes cursor
    }
    __syncthreads();
    for (int e = t; e < m; e += 256) {
        int d = dsh[e];
        int b = d >> BKT_SHIFT;
        int pos = atomicAdd(&h[b], 1);
        EP[(size_t)b * EPCAP + pos] =
            (unsigned int)src[base + e] | ((unsigned int)(d & (BKT_SIZE - 1)) << 23);
    }
}

// exclusive scan over bucket counts via wave shfl scan
__global__ __launch_bounds__(512) void scan_tot_k(const int* __restrict__ gcur,
                                                  int* __restrict__ bucketBase,
                                                  int* __restrict__ rowStart,
                                                  int NB, int N, int E) {
    __shared__ int wsum[8];
    int t = threadIdx.x, lane = t & 63, w = t >> 6;
    int v = (t < NB) ? gcur[t] : 0;
    int iv = v;
#pragma unroll
    for (int off = 1; off < 64; off <<= 1) {
        int x = __shfl_up(iv, off);
        if (lane >= off) iv += x;
    }
    if (lane == 63) wsum[w] = iv;
    __syncthreads();
    int woff = 0;
    for (int i = 0; i < w; i++) woff += wsum[i];
    int incl = iv + woff;
    if (t < NB) bucketBase[t] = incl - v;
    if (t == NB - 1) {
        bucketBase[NB] = incl;
        rowStart[N] = E;
    }
}

// per-bucket exact counting sort with LDS-cached EP slab; emits rowStart, dinv, xs, col
__global__ __launch_bounds__(512) void bucket_csr(const unsigned int* __restrict__ EP,
                                                  const int* __restrict__ bucketBase,
                                                  const float* __restrict__ x,
                                                  int* __restrict__ rowStart,
                                                  float* __restrict__ dinv,
                                                  float* __restrict__ xs,
                                                  int* __restrict__ col, int N) {
    __shared__ unsigned int eph[EPLDS];
    __shared__ int cnt[BKT_SIZE];
    __shared__ int wsum[4];
    int b = blockIdx.x, t = threadIdx.x;
    int ebase = bucketBase[b];
    int m = bucketBase[b + 1] - ebase;
    int ml = min(m, EPLDS);
    const unsigned int* eps = EP + (size_t)b * EPCAP;
    for (int e = t; e < ml; e += 512) eph[e] = eps[e];
    if (t < BKT_SIZE) cnt[t] = 0;
    __syncthreads();
    for (int e = t; e < m; e += 512) {
        unsigned int p = (e < ml) ? eph[e] : eps[e];
        atomicAdd(&cnt[(p >> 23) & (BKT_SIZE - 1)], 1);
    }
    __syncthreads();
    int v = 0, iv = 0;
    if (t < BKT_SIZE) {
        v = cnt[t];
        iv = v;
        int lane = t & 63;
#pragma unroll
        for (int off = 1; off < 64; off <<= 1) {
            int xsh = __shfl_up(iv, off);
            if (lane >= off) iv += xsh;
        }
        if (lane == 63) wsum[t >> 6] = iv;
    }
    __syncthreads();
    if (t < BKT_SIZE) {
        int w = t >> 6;
        int woff = 0;
        for (int i = 0; i < w; i++) woff += wsum[i];
        int excl = iv + woff - v;
        int n = (b << BKT_SHIFT) + t;
        if (n < N) {
            rowStart[n] = ebase + excl;
            float dv = rsqrtf((float)v + 1.0f);
            dinv[n] = dv;
            const float* xr = x + (size_t)n * 7;
            float* xo = xs + (size_t)n * 8;
#pragma unroll
            for (int k = 0; k < 7; k++) xo[k] = xr[k] * dv;
            xo[7] = 0.f;
        }
        cnt[t] = ebase + excl;   // reuse as cursor
    }
    __syncthreads();
    for (int e = t; e < m; e += 512) {
        unsigned int p = (e < ml) ? eph[e] : eps[e];
        int pos = atomicAdd(&cnt[(p >> 23) & (BKT_SIZE - 1)], 1);
        col[pos] = (int)(p & 0x7FFFFFu);
    }
}

// ---------------- fused layer-1: gather (32 streams x float4) + W1 matmul -> A16 ----------------
__global__ __launch_bounds__(256) void aggl1(const int* __restrict__ col,
                                             const int* __restrict__ rowStart,
                                             const float* __restrict__ xs,
                                             const float* __restrict__ W1,
                                             const float* __restrict__ b1,
                                             const float* __restrict__ dinv,
                                             __half* __restrict__ A16, int N) {
    __shared__ float w1s[7 * HDIM];
    __shared__ float aggs[4][8];
    int t = threadIdx.x;
    for (int i = t; i < 7 * HDIM; i += 256) w1s[i] = W1[i];
    int wib = t >> 6, lane = t & 63;
    int stream = lane >> 1;          // 0..31
    int c4 = (lane & 1) * 4;         // channel quad
    int n = blockIdx.x * 4 + wib;
    float4 acc = make_float4(0.f, 0.f, 0.f, 0.f);
    if (n < N) {
        int rs = rowStart[n], re = rowStart[n + 1];
        if (stream == 0) acc = *(const float4*)(xs + (size_t)n * 8 + c4);   // self
        int j = rs + stream;
        for (; j + 32 < re; j += 64) {
            int e0 = col[j], e1 = col[j + 32];
            float4 r0 = *(const float4*)(xs + (size_t)e0 * 8 + c4);
            float4 r1 = *(const float4*)(xs + (size_t)e1 * 8 + c4);
            acc.x += r0.x + r1.x;
            acc.y += r0.y + r1.y;
            acc.z += r0.z + r1.z;
            acc.w += r0.w + r1.w;
        }
        for (; j < re; j += 32) {
            float4 r = *(const float4*)(xs + (size_t)col[j] * 8 + c4);
            acc.x += r.x; acc.y += r.y; acc.z += r.z; acc.w += r.w;
        }
#pragma unroll
        for (int off = 2; off <= 32; off <<= 1) {
            acc.x += __shfl_xor(acc.x, off);
            acc.y += __shfl_xor(acc.y, off);
            acc.z += __shfl_xor(acc.z, off);
            acc.w += __shfl_xor(acc.w, off);
        }
        if (stream == 0) *(float4*)&aggs[wib][c4] = acc;
    }
    __syncthreads();
    if (n < N) {
        float ar[7];
#pragma unroll
        for (int k = 0; k < 7; k++) ar[k] = aggs[wib][k];
        float dv = dinv[n];
        int c = lane * 2;
        float s0 = 0.f, s1 = 0.f;
#pragma unroll
        for (int k = 0; k < 7; k++) {
            s0 += ar[k] * w1s[k * HDIM + c];
            s1 += ar[k] * w1s[k * HDIM + c + 1];
        }
        *(__half2*)(A16 + (size_t)n * HDIM + c) =
            __floats2half2_rn(s0 * dv + b1[c], s1 * dv + b1[c + 1]);
    }
}

// ---------------- coalesced GraphNorm stats over fp16 matrix, batch-run flush ----------------
__global__ __launch_bounds__(256) void stats2(const __half* __restrict__ X,
                                              const int* __restrict__ batch,
                                              float* __restrict__ gsum,
                                              float* __restrict__ gsq, int N) {
    int t = threadIdx.x;
    int c = t & 127;
    int half_ = t >> 7;
    int n0 = blockIdx.x * 32;
    float s = 0.f, q = 0.f;
    int cur = -1;
    for (int i = half_; i < 32; i += 2) {
        int n = n0 + i;
        if (n >= N) break;
        int b = batch[n];
        if (b != cur) {
            if (cur >= 0) {
                unsafeAtomicAdd(&gsum[(size_t)cur * HDIM + c], s);
                unsafeAtomicAdd(&gsq[(size_t)cur * HDIM + c], q);
            }
            cur = b; s = 0.f; q = 0.f;
        }
        float v = __half2float(X[(size_t)n * HDIM + c]);
        s += v; q += v * v;
    }
    if (cur >= 0) {
        unsafeAtomicAdd(&gsum[(size_t)cur * HDIM + c], s);
        unsafeAtomicAdd(&gsq[(size_t)cur * HDIM + c], q);
    }
}

// ---------------- hidden matmul via MFMA with INLINE gstat (raw sums -> mean/istd) ----------------
__global__ __launch_bounds__(256) void mm_h_mfma(const __half* __restrict__ A16,
                                                 const float* __restrict__ gsum,
                                                 const float* __restrict__ gsq,
                                                 const float* __restrict__ gcnt,
                                                 const float* __restrict__ alpha,
                                                 const float* __restrict__ w,
                                                 const float* __restrict__ bb,
                                                 const int* __restrict__ batch,
                                                 const __half* __restrict__ W2t,
                                                 const float* __restrict__ dinv,
                                                 __half* __restrict__ Q, int N) {
    __shared__ _Float16 XS[64][136];
    __shared__ _Float16 WT[HDIM][136];
    __shared__ float pA[HDIM], pW[HDIM], pB[HDIM];
    int t = threadIdx.x;
    for (int i = t; i < HDIM; i += 256) { pA[i] = alpha[i]; pW[i] = w[i]; pB[i] = bb[i]; }
    int n0 = blockIdx.x * 64;

    for (int i = t; i < HDIM * 16; i += 256) {
        int row = i >> 4;
        int kk = (i & 15) * 8;
        *(uint4*)&WT[row][kk] = *(const uint4*)(W2t + (size_t)row * HDIM + kk);
    }
    __syncthreads();

    for (int i = t; i < 64 * 16; i += 256) {
        int nn = i >> 4;
        int kk = (i & 15) * 8;
        int gn = n0 + nn;
        __half hv[8];
#pragma unroll
        for (int k = 0; k < 8; k++) hv[k] = __float2half(0.f);
        if (gn < N) {
            uint4 u = *(const uint4*)(A16 + (size_t)gn * HDIM + kk);
            int b = batch[gn];
            float invc = 1.f / fmaxf(gcnt[b], 1.f);
            const float* sp = gsum + (size_t)b * HDIM + kk;
            const float* qp = gsq + (size_t)b * HDIM + kk;
            float2 f0 = __half22float2(*(__half2*)&u.x);
            float2 f1 = __half22float2(*(__half2*)&u.y);
            float2 f2 = __half22float2(*(__half2*)&u.z);
            float2 f3 = __half22float2(*(__half2*)&u.w);
            float f[8] = {f0.x, f0.y, f1.x, f1.y, f2.x, f2.y, f3.x, f3.y};
#pragma unroll
            for (int k = 0; k < 8; k++) {
                int c = kk + k;
                float a = pA[c];
                float mean = sp[k] * invc;
                float m2 = qp[k] * invc;
                float var = m2 + mean * mean * (a * a - 2.f * a);
                float istd = rsqrtf(fmaxf(var, 0.f) + EPSV);
                hv[k] = __float2half(fmaxf(pW[c] * (f[k] - a * mean) * istd + pB[c], 0.f));
            }
        }
        *(uint4*)&XS[nn][kk] = *(uint4*)hv;
    }
    __syncthreads();

    int wid = t >> 6, lane = t & 63;
    int m0 = wid * 16;
    int rlane = lane & 15;
    int kgrp = lane >> 4;
    f32x4 acc[8];
#pragma unroll
    for (int ct = 0; ct < 8; ct++) acc[ct] = (f32x4){0.f, 0.f, 0.f, 0.f};

#pragma unroll
    for (int kt = 0; kt < 4; ++kt) {
        int kbase = kt * 32 + kgrp * 8;
        f16x8 a = *(const f16x8*)&XS[m0 + rlane][kbase];
#pragma unroll
        for (int ct = 0; ct < 8; ++ct) {
            f16x8 bfr = *(const f16x8*)&WT[ct * 16 + rlane][kbase];
            acc[ct] = __builtin_amdgcn_mfma_f32_16x16x32_f16(a, bfr, acc[ct], 0, 0, 0);
        }
    }

    int rgrp = lane >> 4;
    float dv[4];
    int gnr[4];
#pragma unroll
    for (int r = 0; r < 4; r++) {
        gnr[r] = n0 + m0 + rgrp * 4 + r;
        dv[r] = (gnr[r] < N) ? dinv[gnr[r]] : 0.f;
    }
#pragma unroll
    for (int ct = 0; ct < 8; ++ct) {
#pragma unroll
        for (int r = 0; r < 4; ++r) {
            if (gnr[r] < N)
                Q[(size_t)gnr[r] * HDIM + ct * 16 + rlane] = __float2half(acc[ct][r] * dv[r]);
        }
    }
}

// ---------------- fp16 row load: 4 channels (8B) ----------------
__device__ __forceinline__ float4 qrow4(const __half* __restrict__ Q, int e, int c4) {
    uint2 u = *(const uint2*)(Q + (size_t)e * HDIM + c4);
    float2 f0 = __half22float2(*(__half2*)&u.x);
    float2 f1 = __half22float2(*(__half2*)&u.y);
    return make_float4(f0.x, f0.y, f1.x, f1.y);
}

// ---------------- layer-2 CSR gather: PURE (no stats/LDS/barrier) ----------------
__global__ __launch_bounds__(256) void node_agg2(const int* __restrict__ col,
                                                 const int* __restrict__ rowStart,
                                                 const __half* __restrict__ Q,
                                                 const float* __restrict__ dinv,
                                                 const float* __restrict__ bias,
                                                 __half* __restrict__ A2, int N) {
    int wib = threadIdx.x >> 6;
    int lane = threadIdx.x & 63;
    int half = lane >> 5;
    int l = lane & 31;
    int c4 = l * 4;
    int n = blockIdx.x * 4 + wib;
    if (n >= N) return;
    float4 acc = make_float4(0.f, 0.f, 0.f, 0.f);
    int rs = rowStart[n], re = rowStart[n + 1];
    if (half == 0) acc = qrow4(Q, n, c4);          // self term
    int j = rs + half;
    for (; j + 14 < re; j += 16) {
        int e0 = col[j],      e1 = col[j + 2],  e2 = col[j + 4],  e3 = col[j + 6];
        int e4 = col[j + 8],  e5 = col[j + 10], e6 = col[j + 12], e7 = col[j + 14];
        float4 r0 = qrow4(Q, e0, c4);
        float4 r1 = qrow4(Q, e1, c4);
        float4 r2 = qrow4(Q, e2, c4);
        float4 r3 = qrow4(Q, e3, c4);
        float4 r4 = qrow4(Q, e4, c4);
        float4 r5 = qrow4(Q, e5, c4);
        float4 r6 = qrow4(Q, e6, c4);
        float4 r7 = qrow4(Q, e7, c4);
        acc.x += ((r0.x + r1.x) + (r2.x + r3.x)) + ((r4.x + r5.x) + (r6.x + r7.x));
        acc.y += ((r0.y + r1.y) + (r2.y + r3.y)) + ((r4.y + r5.y) + (r6.y + r7.y));
        acc.z += ((r0.z + r1.z) + (r2.z + r3.z)) + ((r4.z + r5.z) + (r6.z + r7.z));
        acc.w += ((r0.w + r1.w) + (r2.w + r3.w)) + ((r4.w + r5.w) + (r6.w + r7.w));
    }
    for (; j + 6 < re; j += 8) {
        int e0 = col[j], e1 = col[j + 2], e2 = col[j + 4], e3 = col[j + 6];
        float4 r0 = qrow4(Q, e0, c4);
        float4 r1 = qrow4(Q, e1, c4);
        float4 r2 = qrow4(Q, e2, c4);
        float4 r3 = qrow4(Q, e3, c4);
        acc.x += (r0.x + r1.x) + (r2.x + r3.x);
        acc.y += (r0.y + r1.y) + (r2.y + r3.y);
        acc.z += (r0.z + r1.z) + (r2.z + r3.z);
        acc.w += (r0.w + r1.w) + (r2.w + r3.w);
    }
    for (; j < re; j += 2) {
        float4 r = qrow4(Q, col[j], c4);
        acc.x += r.x; acc.y += r.y; acc.z += r.z; acc.w += r.w;
    }
    acc.x += __shfl_xor(acc.x, 32);
    acc.y += __shfl_xor(acc.y, 32);
    acc.z += __shfl_xor(acc.z, 32);
    acc.w += __shfl_xor(acc.w, 32);
    if (half == 0) {
        float dv = dinv[n];
        acc.x = acc.x * dv + bias[c4];
        acc.y = acc.y * dv + bias[c4 + 1];
        acc.z = acc.z * dv + bias[c4 + 2];
        acc.w = acc.w * dv + bias[c4 + 3];
        __half2 o0 = __floats2half2_rn(acc.x, acc.y);
        __half2 o1 = __floats2half2_rn(acc.z, acc.w);
        uint2 u;
        u.x = *(unsigned int*)&o0;
        u.y = *(unsigned int*)&o1;
        *(uint2*)(A2 + (size_t)n * HDIM + c4) = u;
    }
}

// ---------------- layer-2 norm+relu+pool with INLINE gstat, batch-run flush ----------------
__global__ __launch_bounds__(256) void node_norm_pool(const __half* __restrict__ A2,
                                                      const float* __restrict__ gsum,
                                                      const float* __restrict__ gsq,
                                                      const float* __restrict__ gcnt,
                                                      const float* __restrict__ alpha,
                                                      const float* __restrict__ w,
                                                      const float* __restrict__ bb,
                                                      const int* __restrict__ batch,
                                                      float* __restrict__ gpool, int N) {
    int t = threadIdx.x;
    int c = t & 127;
    int half_ = t >> 7;
    int n0 = blockIdx.x * 32;
    float ac = alpha[c], wc = w[c], bc = bb[c];
    float s = 0.f, mc = 0.f, ic = 0.f;
    int cur = -1;
    for (int i = half_; i < 32; i += 2) {
        int n = n0 + i;
        if (n >= N) break;
        int b = batch[n];
        if (b != cur) {
            if (cur >= 0) unsafeAtomicAdd(&gpool[(size_t)cur * HDIM + c], s);
            cur = b; s = 0.f;
            float invc = 1.f / fmaxf(gcnt[b], 1.f);
            float mean = gsum[(size_t)b * HDIM + c] * invc;
            float m2 = gsq[(size_t)b * HDIM + c] * invc;
            float var = m2 + mean * mean * (ac * ac - 2.f * ac);
            mc = mean;
            ic = rsqrtf(fmaxf(var, 0.f) + EPSV);
        }
        float v = __half2float(A2[(size_t)n * HDIM + c]);
        s += fmaxf(wc * (v - ac * mc) * ic + bc, 0.f);
    }
    if (cur >= 0) unsafeAtomicAdd(&gpool[(size_t)cur * HDIM + c], s);
}

// ---------------- head ----------------
__global__ __launch_bounds__(128) void head(const float* __restrict__ gpool,
                                            const float* __restrict__ gcnt,
                                            const float* __restrict__ H1,
                                            const float* __restrict__ hb1,
                                            const float* __restrict__ H2,
                                            const float* __restrict__ hb2,
                                            float* __restrict__ out, int G) {
    __shared__ float gv[HDIM];
    __shared__ float tv[HDIM];
    __shared__ float r0[HDIM], r1[HDIM];
    int g = blockIdx.x;
    int c = threadIdx.x;
    float cnt = fmaxf(gcnt[g], 1.0f);
    gv[c] = gpool[(long long)g * HDIM + c] / cnt;
    __syncthreads();
    float s = hb1[c];
    for (int k = 0; k < HDIM; k++) s += gv[k] * H1[k * HDIM + c];
    tv[c] = fmaxf(s, 0.f);
    __syncthreads();
    r0[c] = tv[c] * H2[c * 2 + 0];
    r1[c] = tv[c] * H2[c * 2 + 1];
    __syncthreads();
    for (int off = 64; off > 0; off >>= 1) {
        if (c < off) { r0[c] += r0[c + off]; r1[c] += r1[c + off]; }
        __syncthreads();
    }
    if (c == 0) {
        out[(long long)g * 2 + 0] = r0[0] + hb2[0];
        out[(long long)g * 2 + 1] = r1[0] + hb2[1];
    }
}

extern "C" void kernel_launch(void* const* d_in, const int* in_sizes, int n_in,
                              void* d_out, int out_size, void* d_ws, size_t ws_size,
                              hipStream_t stream) {
    const float* x    = (const float*)d_in[0];
    const int*   ei   = (const int*)d_in[1];
    const int*   batch= (const int*)d_in[2];
    const float* W1   = (const float*)d_in[4];
    const float* b1   = (const float*)d_in[5];
    const float* gn1w = (const float*)d_in[6];
    const float* gn1b = (const float*)d_in[7];
    const float* gn1a = (const float*)d_in[8];
    const float* W2   = (const float*)d_in[9];
    const float* b2   = (const float*)d_in[10];
    const float* gn2w = (const float*)d_in[11];
    const float* gn2b = (const float*)d_in[12];
    const float* gn2a = (const float*)d_in[13];
    const float* H1   = (const float*)d_in[14];
    const float* hb1  = (const float*)d_in[15];
    const float* H2   = (const float*)d_in[16];
    const float* hb2  = (const float*)d_in[17];

    int N = in_sizes[0] / 7;
    int E = in_sizes[1] / 2;
    int G = out_size / 2;
    const int* srcI = ei;
    const int* dstI = ei + E;

    int NB = (N + BKT_SIZE - 1) >> BKT_SHIFT;      // 391 buckets of 256 nodes
    int NCHUNK = (E + CHK - 1) / CHK;              // 782 chunks of 4096 edges

    // workspace layout
    __half* A16   = (__half*)d_ws;                   // N*128 half
    __half* A2    = A16;                             // alias
    __half* Q16   = A16 + (size_t)N * HDIM;          // N*128 half
    float*  xs    = (float*)(Q16 + (size_t)N * HDIM);// N*8
    float*  gsum1 = xs + (size_t)N * 8;              // G*128  --- zeroed region start
    float*  gsq1  = gsum1 + (size_t)G * HDIM;        // G*128
    float*  gsum2 = gsq1 + (size_t)G * HDIM;         // G*128
    float*  gsq2  = gsum2 + (size_t)G * HDIM;        // G*128
    float*  gpool = gsq2 + (size_t)G * HDIM;         // G*128
    int*    gcur  = (int*)(gpool + (size_t)G * HDIM);// NB+2  --- zeroed region end
    float*  gcnt  = (float*)(gcur + NB + 2);         // G
    float*  dinv  = gcnt + G;                        // N
    int* rowStart = (int*)(dinv + N);                // N+2
    unsigned int* EP = (unsigned int*)(rowStart + N + 2); // NB*EPCAP (~19.2 MB)
    int* col      = (int*)(EP + (size_t)NB * EPCAP); // E
    int* bucketBase = col + E;                       // NB+2
    __half* W2t   = (__half*)(bucketBase + NB + 2);  // 128*128 half

    int gridNW = (N + 3) / 4;
    int gridMM = (N + 63) / 64;
    int gridNS = (N + 31) / 32;
    int setupBlocks = (HDIM * HDIM + G + 255) / 256;

    // single upfront memset: gsum1..gpool + gcur
    hipMemsetAsync(gsum1, 0, ((size_t)G * HDIM * 5 + NB + 2) * 4, stream);

    // ---- CSR build: direct scatter into padded bucket slabs (+setup riding along) ----
    scatter_direct<<<NCHUNK + setupBlocks, 256, 0, stream>>>(srcI, dstI, gcur, EP,
                                                             W2, W2t, batch, gcnt,
                                                             E, NB, NCHUNK, N, G);
    scan_tot_k<<<1, 512, 0, stream>>>(gcur, bucketBase, rowStart, NB, N, E);
    bucket_csr<<<NB, 512, 0, stream>>>(EP, bucketBase, x, rowStart, dinv, xs, col, N);

    // ---- block 1: fused rank-7 aggregation + W1 matmul ----
    aggl1<<<gridNW, 256, 0, stream>>>(col, rowStart, xs, W1, b1, dinv, A16, N);
    stats2<<<gridNS, 256, 0, stream>>>(A16, batch, gsum1, gsq1, N);

    // ---- hidden matmul via MFMA (inline gstat), fp16 in/out ----
    mm_h_mfma<<<gridMM, 256, 0, stream>>>(A16, gsum1, gsq1, gcnt, gn1a, gn1w, gn1b,
                                          batch, W2t, dinv, Q16, N);

    // ---- block 2 (pure fp16 gather) ----
    node_agg2<<<gridNW, 256, 0, stream>>>(col, rowStart, Q16, dinv, b2, A2, N);
    stats2<<<gridNS, 256, 0, stream>>>(A2, batch, gsum2, gsq2, N);

    // ---- layer-2 norm + relu + pool (inline gstat) ----
    node_norm_pool<<<gridNS, 256, 0, stream>>>(A2, gsum2, gsq2, gcnt, gn2a, gn2w, gn2b,
                                               batch, gpool, N);

    // ---- head ----
    head<<<G, 128, 0, stream>>>(gpool, gcnt, H1, hb1, H2, hb2, (float*)d_out, G);
}

// Round 15
// 335.699 us; speedup vs baseline: 2.0056x; 1.0162x over previous
//
#include <hip/hip_runtime.h>
#include <hip/hip_fp16.h>

#define EPSV 1e-5f
#define HDIM 128
#define BKT_SHIFT 8
#define BKT_SIZE 256
#define NBMAX 512
#define CHK 4096
#define EPCAP 12288
#define EPLDS 12288

typedef _Float16 f16x8 __attribute__((ext_vector_type(8)));
typedef float f32x4 __attribute__((ext_vector_type(4)));

// ---------------- binary search helper ----------------
__device__ __forceinline__ int lbound(const int* __restrict__ b, int N, int key) {
    int lo = 0, hi = N;
    while (lo < hi) {
        int mid = (lo + hi) >> 1;
        if (b[mid] < key) lo = mid + 1; else hi = mid;
    }
    return lo;
}

// ================= CSR build: direct bucket scatter (padded slabs) =================
// blocks [0, NCHUNK): scatter edges; [NCHUNK, NCHUNK+setup): W2^T + gcnt;
// [NCHUNK+setup, ...): zero the stats region (not consumed until stats2).
__global__ __launch_bounds__(256) void scatter_direct(const int* __restrict__ src,
                                                      const int* __restrict__ dst,
                                                      int* __restrict__ gcur,
                                                      unsigned int* __restrict__ EP,
                                                      const float* __restrict__ W2,
                                                      __half* __restrict__ W2t,
                                                      const int* __restrict__ batch,
                                                      float* __restrict__ gcnt,
                                                      float* __restrict__ zeroRegion,
                                                      long long zeroCount,
                                                      int E, int NB, int NCHUNK,
                                                      int SETUPB, int N, int G) {
    int blk = blockIdx.x;
    int t = threadIdx.x;
    if (blk >= NCHUNK + SETUPB) {
        long long i = (long long)(blk - NCHUNK - SETUPB) * 256 + t;
        if (i < zeroCount) zeroRegion[i] = 0.f;
        return;
    }
    if (blk >= NCHUNK) {
        int i = (blk - NCHUNK) * 256 + t;
        if (i < HDIM * HDIM) {
            int c = i >> 7, k = i & 127;
            W2t[c * HDIM + k] = __float2half(W2[k * HDIM + c]);
        } else if (i - HDIM * HDIM < G) {
            int g = i - HDIM * HDIM;
            gcnt[g] = (float)(lbound(batch, N, g + 1) - lbound(batch, N, g));
        }
        return;
    }
    __shared__ int h[NBMAX];
    __shared__ int dsh[CHK];
    for (int i = t; i < NB; i += 256) h[i] = 0;
    __syncthreads();
    int base = blk * CHK;
    int m = min(CHK, E - base);
    for (int e = t; e < m; e += 256) {
        int d = dst[base + e];
        dsh[e] = d;
        atomicAdd(&h[d >> BKT_SHIFT], 1);
    }
    __syncthreads();
    for (int i = t; i < NB; i += 256) {
        int c = h[i];
        h[i] = c ? atomicAdd(&gcur[i], c) : 0;
    }
    __syncthreads();
    for (int e = t; e < m; e += 256) {
        int d = dsh[e];
        int b = d >> BKT_SHIFT;
        int pos = atomicAdd(&h[b], 1);
        EP[(size_t)b * EPCAP + pos] =
            (unsigned int)src[base + e] | ((unsigned int)(d & (BKT_SIZE - 1)) << 23);
    }
}

// exclusive scan over bucket counts via wave shfl scan
__global__ __launch_bounds__(512) void scan_tot_k(const int* __restrict__ gcur,
                                                  int* __restrict__ bucketBase,
                                                  int* __restrict__ rowStart,
                                                  int NB, int N, int E) {
    __shared__ int wsum[8];
    int t = threadIdx.x, lane = t & 63, w = t >> 6;
    int v = (t < NB) ? gcur[t] : 0;
    int iv = v;
#pragma unroll
    for (int off = 1; off < 64; off <<= 1) {
        int x = __shfl_up(iv, off);
        if (lane >= off) iv += x;
    }
    if (lane == 63) wsum[w] = iv;
    __syncthreads();
    int woff = 0;
    for (int i = 0; i < w; i++) woff += wsum[i];
    int incl = iv + woff;
    if (t < NB) bucketBase[t] = incl - v;
    if (t == NB - 1) {
        bucketBase[NB] = incl;
        rowStart[N] = E;
    }
}

// per-bucket exact counting sort with LDS-cached EP slab; emits rowStart, dinv, xs, col
__global__ __launch_bounds__(512) void bucket_csr(const unsigned int* __restrict__ EP,
                                                  const int* __restrict__ bucketBase,
                                                  const float* __restrict__ x,
                                                  int* __restrict__ rowStart,
                                                  float* __restrict__ dinv,
                                                  float* __restrict__ xs,
                                                  int* __restrict__ col, int N) {
    __shared__ unsigned int eph[EPLDS];
    __shared__ int cnt[BKT_SIZE];
    __shared__ int wsum[4];
    int b = blockIdx.x, t = threadIdx.x;
    int ebase = bucketBase[b];
    int m = bucketBase[b + 1] - ebase;
    int ml = min(m, EPLDS);
    const unsigned int* eps = EP + (size_t)b * EPCAP;
    for (int e = t; e < ml; e += 512) eph[e] = eps[e];
    if (t < BKT_SIZE) cnt[t] = 0;
    __syncthreads();
    for (int e = t; e < m; e += 512) {
        unsigned int p = (e < ml) ? eph[e] : eps[e];
        atomicAdd(&cnt[(p >> 23) & (BKT_SIZE - 1)], 1);
    }
    __syncthreads();
    int v = 0, iv = 0;
    if (t < BKT_SIZE) {
        v = cnt[t];
        iv = v;
        int lane = t & 63;
#pragma unroll
        for (int off = 1; off < 64; off <<= 1) {
            int xsh = __shfl_up(iv, off);
            if (lane >= off) iv += xsh;
        }
        if (lane == 63) wsum[t >> 6] = iv;
    }
    __syncthreads();
    if (t < BKT_SIZE) {
        int w = t >> 6;
        int woff = 0;
        for (int i = 0; i < w; i++) woff += wsum[i];
        int excl = iv + woff - v;
        int n = (b << BKT_SHIFT) + t;
        if (n < N) {
            rowStart[n] = ebase + excl;
            float dv = rsqrtf((float)v + 1.0f);
            dinv[n] = dv;
            const float* xr = x + (size_t)n * 7;
            float* xo = xs + (size_t)n * 8;
#pragma unroll
            for (int k = 0; k < 7; k++) xo[k] = xr[k] * dv;
            xo[7] = 0.f;
        }
        cnt[t] = ebase + excl;
    }
    __syncthreads();
    for (int e = t; e < m; e += 512) {
        unsigned int p = (e < ml) ? eph[e] : eps[e];
        int pos = atomicAdd(&cnt[(p >> 23) & (BKT_SIZE - 1)], 1);
        col[pos] = (int)(p & 0x7FFFFFu);
    }
}

// ---------------- fused layer-1: gather (32 streams x float4) + W1 matmul, 2 nodes/wave ----------------
__global__ __launch_bounds__(256) void aggl1(const int* __restrict__ col,
                                             const int* __restrict__ rowStart,
                                             const float* __restrict__ xs,
                                             const float* __restrict__ W1,
                                             const float* __restrict__ b1,
                                             const float* __restrict__ dinv,
                                             __half* __restrict__ A16, int N) {
    __shared__ float w1s[7 * HDIM];
    __shared__ float aggs[8][8];
    int t = threadIdx.x;
    for (int i = t; i < 7 * HDIM; i += 256) w1s[i] = W1[i];
    int wib = t >> 6, lane = t & 63;
    int stream = lane >> 1;          // 0..31
    int c4 = (lane & 1) * 4;         // channel quad
#pragma unroll
    for (int ni = 0; ni < 2; ni++) {
        int n = blockIdx.x * 8 + wib * 2 + ni;
        float4 acc = make_float4(0.f, 0.f, 0.f, 0.f);
        if (n < N) {
            int rs = rowStart[n], re = rowStart[n + 1];
            if (stream == 0) acc = *(const float4*)(xs + (size_t)n * 8 + c4);   // self
            int j = rs + stream;
            for (; j + 32 < re; j += 64) {
                int e0 = col[j], e1 = col[j + 32];
                float4 r0 = *(const float4*)(xs + (size_t)e0 * 8 + c4);
                float4 r1 = *(const float4*)(xs + (size_t)e1 * 8 + c4);
                acc.x += r0.x + r1.x;
                acc.y += r0.y + r1.y;
                acc.z += r0.z + r1.z;
                acc.w += r0.w + r1.w;
            }
            for (; j < re; j += 32) {
                float4 r = *(const float4*)(xs + (size_t)col[j] * 8 + c4);
                acc.x += r.x; acc.y += r.y; acc.z += r.z; acc.w += r.w;
            }
#pragma unroll
            for (int off = 2; off <= 32; off <<= 1) {
                acc.x += __shfl_xor(acc.x, off);
                acc.y += __shfl_xor(acc.y, off);
                acc.z += __shfl_xor(acc.z, off);
                acc.w += __shfl_xor(acc.w, off);
            }
            if (stream == 0) *(float4*)&aggs[wib * 2 + ni][c4] = acc;
        }
    }
    __syncthreads();
#pragma unroll
    for (int ni = 0; ni < 2; ni++) {
        int n = blockIdx.x * 8 + wib * 2 + ni;
        if (n < N) {
            float ar[7];
#pragma unroll
            for (int k = 0; k < 7; k++) ar[k] = aggs[wib * 2 + ni][k];
            float dv = dinv[n];
            int c = lane * 2;
            float s0 = 0.f, s1 = 0.f;
#pragma unroll
            for (int k = 0; k < 7; k++) {
                s0 += ar[k] * w1s[k * HDIM + c];
                s1 += ar[k] * w1s[k * HDIM + c + 1];
            }
            *(__half2*)(A16 + (size_t)n * HDIM + c) =
                __floats2half2_rn(s0 * dv + b1[c], s1 * dv + b1[c + 1]);
        }
    }
}

// ---------------- coalesced GraphNorm stats over fp16 matrix, batch-run flush ----------------
__global__ __launch_bounds__(256) void stats2(const __half* __restrict__ X,
                                              const int* __restrict__ batch,
                                              float* __restrict__ gsum,
                                              float* __restrict__ gsq, int N) {
    int t = threadIdx.x;
    int c = t & 127;
    int half_ = t >> 7;
    int n0 = blockIdx.x * 32;
    float s = 0.f, q = 0.f;
    int cur = -1;
    for (int i = half_; i < 32; i += 2) {
        int n = n0 + i;
        if (n >= N) break;
        int b = batch[n];
        if (b != cur) {
            if (cur >= 0) {
                unsafeAtomicAdd(&gsum[(size_t)cur * HDIM + c], s);
                unsafeAtomicAdd(&gsq[(size_t)cur * HDIM + c], q);
            }
            cur = b; s = 0.f; q = 0.f;
        }
        float v = __half2float(X[(size_t)n * HDIM + c]);
        s += v; q += v * v;
    }
    if (cur >= 0) {
        unsafeAtomicAdd(&gsum[(size_t)cur * HDIM + c], s);
        unsafeAtomicAdd(&gsq[(size_t)cur * HDIM + c], q);
    }
}

// ---------------- hidden matmul via MFMA with INLINE gstat ----------------
__global__ __launch_bounds__(256) void mm_h_mfma(const __half* __restrict__ A16,
                                                 const float* __restrict__ gsum,
                                                 const float* __restrict__ gsq,
                                                 const float* __restrict__ gcnt,
                                                 const float* __restrict__ alpha,
                                                 const float* __restrict__ w,
                                                 const float* __restrict__ bb,
                                                 const int* __restrict__ batch,
                                                 const __half* __restrict__ W2t,
                                                 const float* __restrict__ dinv,
                                                 __half* __restrict__ Q, int N) {
    __shared__ _Float16 XS[64][136];
    __shared__ _Float16 WT[HDIM][136];
    __shared__ float pA[HDIM], pW[HDIM], pB[HDIM];
    int t = threadIdx.x;
    for (int i = t; i < HDIM; i += 256) { pA[i] = alpha[i]; pW[i] = w[i]; pB[i] = bb[i]; }
    int n0 = blockIdx.x * 64;

    for (int i = t; i < HDIM * 16; i += 256) {
        int row = i >> 4;
        int kk = (i & 15) * 8;
        *(uint4*)&WT[row][kk] = *(const uint4*)(W2t + (size_t)row * HDIM + kk);
    }
    __syncthreads();

    for (int i = t; i < 64 * 16; i += 256) {
        int nn = i >> 4;
        int kk = (i & 15) * 8;
        int gn = n0 + nn;
        __half hv[8];
#pragma unroll
        for (int k = 0; k < 8; k++) hv[k] = __float2half(0.f);
        if (gn < N) {
            uint4 u = *(const uint4*)(A16 + (size_t)gn * HDIM + kk);
            int b = batch[gn];
            float invc = 1.f / fmaxf(gcnt[b], 1.f);
            const float* sp = gsum + (size_t)b * HDIM + kk;
            const float* qp = gsq + (size_t)b * HDIM + kk;
            float2 f0 = __half22float2(*(__half2*)&u.x);
            float2 f1 = __half22float2(*(__half2*)&u.y);
            float2 f2 = __half22float2(*(__half2*)&u.z);
            float2 f3 = __half22float2(*(__half2*)&u.w);
            float f[8] = {f0.x, f0.y, f1.x, f1.y, f2.x, f2.y, f3.x, f3.y};
#pragma unroll
            for (int k = 0; k < 8; k++) {
                int c = kk + k;
                float a = pA[c];
                float mean = sp[k] * invc;
                float m2 = qp[k] * invc;
                float var = m2 + mean * mean * (a * a - 2.f * a);
                float istd = rsqrtf(fmaxf(var, 0.f) + EPSV);
                hv[k] = __float2half(fmaxf(pW[c] * (f[k] - a * mean) * istd + pB[c], 0.f));
            }
        }
        *(uint4*)&XS[nn][kk] = *(uint4*)hv;
    }
    __syncthreads();

    int wid = t >> 6, lane = t & 63;
    int m0 = wid * 16;
    int rlane = lane & 15;
    int kgrp = lane >> 4;
    f32x4 acc[8];
#pragma unroll
    for (int ct = 0; ct < 8; ct++) acc[ct] = (f32x4){0.f, 0.f, 0.f, 0.f};

#pragma unroll
    for (int kt = 0; kt < 4; ++kt) {
        int kbase = kt * 32 + kgrp * 8;
        f16x8 a = *(const f16x8*)&XS[m0 + rlane][kbase];
#pragma unroll
        for (int ct = 0; ct < 8; ++ct) {
            f16x8 bfr = *(const f16x8*)&WT[ct * 16 + rlane][kbase];
            acc[ct] = __builtin_amdgcn_mfma_f32_16x16x32_f16(a, bfr, acc[ct], 0, 0, 0);
        }
    }

    int rgrp = lane >> 4;
    float dv[4];
    int gnr[4];
#pragma unroll
    for (int r = 0; r < 4; r++) {
        gnr[r] = n0 + m0 + rgrp * 4 + r;
        dv[r] = (gnr[r] < N) ? dinv[gnr[r]] : 0.f;
    }
#pragma unroll
    for (int ct = 0; ct < 8; ++ct) {
#pragma unroll
        for (int r = 0; r < 4; ++r) {
            if (gnr[r] < N)
                Q[(size_t)gnr[r] * HDIM + ct * 16 + rlane] = __float2half(acc[ct][r] * dv[r]);
        }
    }
}

// ---------------- fp16 row load: 4 channels (8B) ----------------
__device__ __forceinline__ float4 qrow4(const __half* __restrict__ Q, int e, int c4) {
    uint2 u = *(const uint2*)(Q + (size_t)e * HDIM + c4);
    float2 f0 = __half22float2(*(__half2*)&u.x);
    float2 f1 = __half22float2(*(__half2*)&u.y);
    return make_float4(f0.x, f0.y, f1.x, f1.y);
}

// ---------------- layer-2 CSR gather: PURE ----------------
__global__ __launch_bounds__(256) void node_agg2(const int* __restrict__ col,
                                                 const int* __restrict__ rowStart,
                                                 const __half* __restrict__ Q,
                                                 const float* __restrict__ dinv,
                                                 const float* __restrict__ bias,
                                                 __half* __restrict__ A2, int N) {
    int wib = threadIdx.x >> 6;
    int lane = threadIdx.x & 63;
    int half = lane >> 5;
    int l = lane & 31;
    int c4 = l * 4;
    int n = blockIdx.x * 4 + wib;
    if (n >= N) return;
    float4 acc = make_float4(0.f, 0.f, 0.f, 0.f);
    int rs = rowStart[n], re = rowStart[n + 1];
    if (half == 0) acc = qrow4(Q, n, c4);          // self term
    int j = rs + half;
    for (; j + 14 < re; j += 16) {
        int e0 = col[j],      e1 = col[j + 2],  e2 = col[j + 4],  e3 = col[j + 6];
        int e4 = col[j + 8],  e5 = col[j + 10], e6 = col[j + 12], e7 = col[j + 14];
        float4 r0 = qrow4(Q, e0, c4);
        float4 r1 = qrow4(Q, e1, c4);
        float4 r2 = qrow4(Q, e2, c4);
        float4 r3 = qrow4(Q, e3, c4);
        float4 r4 = qrow4(Q, e4, c4);
        float4 r5 = qrow4(Q, e5, c4);
        float4 r6 = qrow4(Q, e6, c4);
        float4 r7 = qrow4(Q, e7, c4);
        acc.x += ((r0.x + r1.x) + (r2.x + r3.x)) + ((r4.x + r5.x) + (r6.x + r7.x));
        acc.y += ((r0.y + r1.y) + (r2.y + r3.y)) + ((r4.y + r5.y) + (r6.y + r7.y));
        acc.z += ((r0.z + r1.z) + (r2.z + r3.z)) + ((r4.z + r5.z) + (r6.z + r7.z));
        acc.w += ((r0.w + r1.w) + (r2.w + r3.w)) + ((r4.w + r5.w) + (r6.w + r7.w));
    }
    for (; j + 6 < re; j += 8) {
        int e0 = col[j], e1 = col[j + 2], e2 = col[j + 4], e3 = col[j + 6];
        float4 r0 = qrow4(Q, e0, c4);
        float4 r1 = qrow4(Q, e1, c4);
        float4 r2 = qrow4(Q, e2, c4);
        float4 r3 = qrow4(Q, e3, c4);
        acc.x += (r0.x + r1.x) + (r2.x + r3.x);
        acc.y += (r0.y + r1.y) + (r2.y + r3.y);
        acc.z += (r0.z + r1.z) + (r2.z + r3.z);
        acc.w += (r0.w + r1.w) + (r2.w + r3.w);
    }
    for (; j < re; j += 2) {
        float4 r = qrow4(Q, col[j], c4);
        acc.x += r.x; acc.y += r.y; acc.z += r.z; acc.w += r.w;
    }
    acc.x += __shfl_xor(acc.x, 32);
    acc.y += __shfl_xor(acc.y, 32);
    acc.z += __shfl_xor(acc.z, 32);
    acc.w += __shfl_xor(acc.w, 32);
    if (half == 0) {
        float dv = dinv[n];
        acc.x = acc.x * dv + bias[c4];
        acc.y = acc.y * dv + bias[c4 + 1];
        acc.z = acc.z * dv + bias[c4 + 2];
        acc.w = acc.w * dv + bias[c4 + 3];
        __half2 o0 = __floats2half2_rn(acc.x, acc.y);
        __half2 o1 = __floats2half2_rn(acc.z, acc.w);
        uint2 u;
        u.x = *(unsigned int*)&o0;
        u.y = *(unsigned int*)&o1;
        *(uint2*)(A2 + (size_t)n * HDIM + c4) = u;
    }
}

// ---------------- layer-2 norm+relu+pool with INLINE gstat, batch-run flush ----------------
__global__ __launch_bounds__(256) void node_norm_pool(const __half* __restrict__ A2,
                                                      const float* __restrict__ gsum,
                                                      const float* __restrict__ gsq,
                                                      const float* __restrict__ gcnt,
                                                      const float* __restrict__ alpha,
                                                      const float* __restrict__ w,
                                                      const float* __restrict__ bb,
                                                      const int* __restrict__ batch,
                                                      float* __restrict__ gpool, int N) {
    int t = threadIdx.x;
    int c = t & 127;
    int half_ = t >> 7;
    int n0 = blockIdx.x * 32;
    float ac = alpha[c], wc = w[c], bc = bb[c];
    float s = 0.f, mc = 0.f, ic = 0.f;
    int cur = -1;
    for (int i = half_; i < 32; i += 2) {
        int n = n0 + i;
        if (n >= N) break;
        int b = batch[n];
        if (b != cur) {
            if (cur >= 0) unsafeAtomicAdd(&gpool[(size_t)cur * HDIM + c], s);
            cur = b; s = 0.f;
            float invc = 1.f / fmaxf(gcnt[b], 1.f);
            float mean = gsum[(size_t)b * HDIM + c] * invc;
            float m2 = gsq[(size_t)b * HDIM + c] * invc;
            float var = m2 + mean * mean * (ac * ac - 2.f * ac);
            mc = mean;
            ic = rsqrtf(fmaxf(var, 0.f) + EPSV);
        }
        float v = __half2float(A2[(size_t)n * HDIM + c]);
        s += fmaxf(wc * (v - ac * mc) * ic + bc, 0.f);
    }
    if (cur >= 0) unsafeAtomicAdd(&gpool[(size_t)cur * HDIM + c], s);
}

// ---------------- head ----------------
__global__ __launch_bounds__(128) void head(const float* __restrict__ gpool,
                                            const float* __restrict__ gcnt,
                                            const float* __restrict__ H1,
                                            const float* __restrict__ hb1,
                                            const float* __restrict__ H2,
                                            const float* __restrict__ hb2,
                                            float* __restrict__ out, int G) {
    __shared__ float gv[HDIM];
    __shared__ float tv[HDIM];
    __shared__ float r0[HDIM], r1[HDIM];
    int g = blockIdx.x;
    int c = threadIdx.x;
    float cnt = fmaxf(gcnt[g], 1.0f);
    gv[c] = gpool[(long long)g * HDIM + c] / cnt;
    __syncthreads();
    float s = hb1[c];
    for (int k = 0; k < HDIM; k++) s += gv[k] * H1[k * HDIM + c];
    tv[c] = fmaxf(s, 0.f);
    __syncthreads();
    r0[c] = tv[c] * H2[c * 2 + 0];
    r1[c] = tv[c] * H2[c * 2 + 1];
    __syncthreads();
    for (int off = 64; off > 0; off >>= 1) {
        if (c < off) { r0[c] += r0[c + off]; r1[c] += r1[c + off]; }
        __syncthreads();
    }
    if (c == 0) {
        out[(long long)g * 2 + 0] = r0[0] + hb2[0];
        out[(long long)g * 2 + 1] = r1[0] + hb2[1];
    }
}

extern "C" void kernel_launch(void* const* d_in, const int* in_sizes, int n_in,
                              void* d_out, int out_size, void* d_ws, size_t ws_size,
                              hipStream_t stream) {
    const float* x    = (const float*)d_in[0];
    const int*   ei   = (const int*)d_in[1];
    const int*   batch= (const int*)d_in[2];
    const float* W1   = (const float*)d_in[4];
    const float* b1   = (const float*)d_in[5];
    const float* gn1w = (const float*)d_in[6];
    const float* gn1b = (const float*)d_in[7];
    const float* gn1a = (const float*)d_in[8];
    const float* W2   = (const float*)d_in[9];
    const float* b2   = (const float*)d_in[10];
    const float* gn2w = (const float*)d_in[11];
    const float* gn2b = (const float*)d_in[12];
    const float* gn2a = (const float*)d_in[13];
    const float* H1   = (const float*)d_in[14];
    const float* hb1  = (const float*)d_in[15];
    const float* H2   = (const float*)d_in[16];
    const float* hb2  = (const float*)d_in[17];

    int N = in_sizes[0] / 7;
    int E = in_sizes[1] / 2;
    int G = out_size / 2;
    const int* srcI = ei;
    const int* dstI = ei + E;

    int NB = (N + BKT_SIZE - 1) >> BKT_SHIFT;
    int NCHUNK = (E + CHK - 1) / CHK;

    // workspace layout
    __half* A16   = (__half*)d_ws;                   // N*128 half
    __half* A2    = A16;                             // alias
    __half* Q16   = A16 + (size_t)N * HDIM;          // N*128 half
    float*  xs    = (float*)(Q16 + (size_t)N * HDIM);// N*8
    float*  gsum1 = xs + (size_t)N * 8;              // G*128  --- zero-rider region start
    float*  gsq1  = gsum1 + (size_t)G * HDIM;        // G*128
    float*  gsum2 = gsq1 + (size_t)G * HDIM;         // G*128
    float*  gsq2  = gsum2 + (size_t)G * HDIM;        // G*128
    float*  gpool = gsq2 + (size_t)G * HDIM;         // G*128  --- zero-rider region end
    int*    gcur  = (int*)(gpool + (size_t)G * HDIM);// NB+2 (memset)
    float*  gcnt  = (float*)(gcur + NB + 2);         // G
    float*  dinv  = gcnt + G;                        // N
    int* rowStart = (int*)(dinv + N);                // N+2
    unsigned int* EP = (unsigned int*)(rowStart + N + 2); // NB*EPCAP
    int* col      = (int*)(EP + (size_t)NB * EPCAP); // E
    int* bucketBase = col + E;                       // NB+2
    __half* W2t   = (__half*)(bucketBase + NB + 2);  // 128*128 half

    int gridNW = (N + 3) / 4;
    int gridA1 = (N + 7) / 8;
    int gridMM = (N + 63) / 64;
    int gridNS = (N + 31) / 32;
    int setupBlocks = (HDIM * HDIM + G + 255) / 256;
    long long zeroCount = (long long)G * HDIM * 5;
    int zeroBlocks = (int)((zeroCount + 255) / 256);

    // tiny memset: just gcur
    hipMemsetAsync(gcur, 0, (size_t)(NB + 2) * 4, stream);

    // ---- CSR build: direct scatter + setup + stats-zero riders ----
    scatter_direct<<<NCHUNK + setupBlocks + zeroBlocks, 256, 0, stream>>>(
        srcI, dstI, gcur, EP, W2, W2t, batch, gcnt, gsum1, zeroCount,
        E, NB, NCHUNK, setupBlocks, N, G);
    scan_tot_k<<<1, 512, 0, stream>>>(gcur, bucketBase, rowStart, NB, N, E);
    bucket_csr<<<NB, 512, 0, stream>>>(EP, bucketBase, x, rowStart, dinv, xs, col, N);

    // ---- block 1: fused rank-7 aggregation + W1 matmul (2 nodes/wave) ----
    aggl1<<<gridA1, 256, 0, stream>>>(col, rowStart, xs, W1, b1, dinv, A16, N);
    stats2<<<gridNS, 256, 0, stream>>>(A16, batch, gsum1, gsq1, N);

    // ---- hidden matmul via MFMA (inline gstat) ----
    mm_h_mfma<<<gridMM, 256, 0, stream>>>(A16, gsum1, gsq1, gcnt, gn1a, gn1w, gn1b,
                                          batch, W2t, dinv, Q16, N);

    // ---- block 2 (pure fp16 gather) ----
    node_agg2<<<gridNW, 256, 0, stream>>>(col, rowStart, Q16, dinv, b2, A2, N);
    stats2<<<gridNS, 256, 0, stream>>>(A2, batch, gsum2, gsq2, N);

    // ---- layer-2 norm + relu + pool (inline gstat) ----
    node_norm_pool<<<gridNS, 256, 0, stream>>>(A2, gsum2, gsq2, gcnt, gn2a, gn2w, gn2b,
                                               batch, gpool, N);

    // ---- head ----
    head<<<G, 128, 0, stream>>>(gpool, gcnt, H1, hb1, H2, hb2, (float*)d_out, G);
}